// Round 6
// baseline (2814.140 us; speedup 1.0000x reference)
//
#include <hip/hip_runtime.h>
#include <hip/hip_bf16.h>

typedef unsigned short ushort_t;
typedef unsigned int uint_t;

#define NN    10000
#define NE    320000
#define NL    4
#define EBLK  64        // edges per block (4 threads per edge)
#define NEBLK 5000      // NE / EBLK exactly
#define NPB   64        // nodes per block in node_kernel (4 threads per node)
#define NNODEBLK 157    // ceil(NN / NPB)

// ---- workspace float offsets -------------------------------------------------
// coord lives directly in d_out (fp32, 30000 elems, fully initialized by node_init)
#define OFF_FIELD 0        // 30000
#define OFF_HH    30000    // 640000
#define OFF_CSUM  670000   // 30000  (contiguous with MAGG for one memset)
#define OFF_MAGG  700000   // 640000 -> float end 1340000
// ---- int region (starts at float offset 1340000) ----------------------------
#define IOFF_CNTI   0        // 10000
#define IOFF_OFF    10000    // 10001
#define IOFF_CURSOR 20001    // 10000
#define IOFF_PERM   30001    // 320000 -> int end 350001 (total ws ~6.76 MB)

// fast silu: v_rcp_f32 instead of IEEE divide (~1e-7 rel err, VALU-bound paths)
__device__ __forceinline__ float silu(float x) {
    return x * __builtin_amdgcn_rcpf(1.0f + __expf(-x));
}
// fp32 -> bf16 round-to-nearest-even
__device__ __forceinline__ ushort_t f2bf(float f) {
    union { float f; uint_t u; } v; v.f = f;
    const uint_t r = (v.u + 0x7FFFu + ((v.u >> 16) & 1u)) >> 16;
    return (ushort_t)r;
}
__device__ __forceinline__ void unpack2(uint_t p, float& lo, float& hi) {
    union { uint_t u; float f; } a, b;
    a.u = p << 16; b.u = p & 0xffff0000u;
    lo = a.f; hi = b.f;
}

// ---- CSR build: per-row int counts ------------------------------------------
__global__ __launch_bounds__(256) void counti_kernel(const int* __restrict__ rows,
                                                     int* __restrict__ cnti) {
    const int e = blockIdx.x * 256 + threadIdx.x;
    if (e < NE) {
        int r = rows[e];
        r = ((uint_t)r < (uint_t)NN) ? r : 0;
        atomicAdd(&cnti[r], 1);
    }
}

// ---- CSR build: exclusive scan over 10000 counts (single block) --------------
__global__ __launch_bounds__(1024) void scan_kernel(const int* __restrict__ cnti,
                                                    int* __restrict__ off,
                                                    int* __restrict__ cursor) {
    __shared__ int part[1024];
    const int t = threadIdx.x;
    const int base = t * 10;
    int loc[10];
    int s = 0;
    #pragma unroll
    for (int i = 0; i < 10; i++) {
        const int idx = base + i;
        const int v = (idx < NN) ? cnti[idx] : 0;
        loc[i] = s; s += v;
    }
    part[t] = s;
    __syncthreads();
    const int own = s;
    for (int d = 1; d < 1024; d <<= 1) {
        const int v = (t >= d) ? part[t - d] : 0;
        __syncthreads();
        part[t] += v;
        __syncthreads();
    }
    const int excl = part[t] - own;
    #pragma unroll
    for (int i = 0; i < 10; i++) {
        const int idx = base + i;
        if (idx < NN) { const int o = excl + loc[i]; off[idx] = o; cursor[idx] = o; }
    }
    if (t == 0) off[NN] = NE;
}

// ---- CSR build: scatter edge ids into row-sorted order -----------------------
__global__ __launch_bounds__(256) void scatter_kernel(const int* __restrict__ rows,
                                                      int* __restrict__ cursor,
                                                      int* __restrict__ perm) {
    const int e = blockIdx.x * 256 + threadIdx.x;
    if (e < NE) {
        int r = rows[e];
        r = ((uint_t)r < (uint_t)NN) ? r : 0;
        const int pos = atomicAdd(&cursor[r], 1);
        if ((uint_t)pos < (uint_t)NE) perm[pos] = e;
    }
}

// ---- field network + node embedding + coord init (once per call) ------------
__global__ __launch_bounds__(256) void node_init(
    const float* __restrict__ hsrc, const float* __restrict__ xsrc,
    const float* __restrict__ vsrc, const int* __restrict__ charges,
    const float* __restrict__ cls,
    const float* __restrict__ fW1, const float* __restrict__ fb1,
    const float* __restrict__ fW2, const float* __restrict__ fb2,
    const float* __restrict__ fW3, const float* __restrict__ fb3,
    const float* __restrict__ embW, const float* __restrict__ embb,
    float* __restrict__ coord, float* __restrict__ field, float* __restrict__ hh)
{
    __shared__ float sFW1[704], sFW2[1024], sFW3[96];
    __shared__ float sFB1[32], sFB2[32], sFB3[3], sCLS[32], sEW[64], sEB[64];
    const int t = threadIdx.x;
    for (int i = t; i < 704; i += 256) sFW1[i] = fW1[i];
    for (int i = t; i < 1024; i += 256) sFW2[i] = fW2[i];
    if (t < 96) sFW3[t] = fW3[t];
    if (t < 32) { sFB1[t] = fb1[t]; sFB2[t] = fb2[t]; sCLS[t] = cls[t]; }
    if (t < 3)  sFB3[t] = fb3[t];
    if (t < 64) { sEW[t] = embW[t]; sEB[t] = embb[t]; }
    __syncthreads();

    const int n = blockIdx.x * 256 + t;
    if (n >= NN) return;

    float fin[22];
    #pragma unroll
    for (int d = 0; d < 3; d++) {
        fin[d]     = xsrc[3 * n + d];
        fin[3 + d] = vsrc[3 * n + d];
        coord[3 * n + d] = fin[d];
    }
    int ci = charges[n];
    ci = ((uint_t)ci < 2u) ? ci : 0;
    const int cix = ci * 16;
    #pragma unroll
    for (int k = 0; k < 16; k++) fin[6 + k] = sCLS[cix + k];

    float h1[32];
    #pragma unroll
    for (int j = 0; j < 32; j++) h1[j] = sFB1[j];
    #pragma unroll
    for (int k = 0; k < 22; k++) {
        const float v = fin[k];
        #pragma unroll
        for (int j = 0; j < 32; j++) h1[j] += v * sFW1[k * 32 + j];
    }
    #pragma unroll
    for (int j = 0; j < 32; j++) h1[j] = silu(h1[j]);

    float h2[32];
    #pragma unroll
    for (int j = 0; j < 32; j++) h2[j] = sFB2[j];
    #pragma unroll
    for (int k = 0; k < 32; k++) {
        const float v = h1[k];
        #pragma unroll
        for (int j = 0; j < 32; j++) h2[j] += v * sFW2[k * 32 + j];
    }
    #pragma unroll
    for (int j = 0; j < 32; j++) h2[j] = silu(h2[j]);

    #pragma unroll
    for (int d = 0; d < 3; d++) {
        float s = sFB3[d];
        #pragma unroll
        for (int j = 0; j < 32; j++) s += h2[j] * sFW3[j * 3 + d];
        field[3 * n + d] = s;
    }

    const float hv = hsrc[n];
    #pragma unroll
    for (int j = 0; j < 64; j++) hh[(size_t)n * 64 + j] = hv * sEW[j] + sEB[j];
}

// ---- per-layer edge kernel: 4 threads per edge, 16 channels per thread -------
// Round-5 changes vs round-3/4 structure (which passed at 335us, VGPR 88):
//  * sW2 / sCW1 no longer staged in LDS: W2 and cW1 GEMMs read fp32 weights
//    straight from global as 4-address broadcast loads (pattern validated by
//    round-4 node_kernel). Kills 1024 unpack ops (cW1 was bf16) and frees 24KB.
//  * LDS 60.4 -> ~34.4 KB  => 4 blocks/CU (launch_bounds(256,4)), occupancy
//    8 -> 16 waves/CU to hide LDS/VMEM latency.
//  * segment scan done by wave 0 via shfl_up: 14 block barriers -> 2.
__global__ __launch_bounds__(256, 4) void edge_kernel(
    const int* __restrict__ rows, const int* __restrict__ cols,
    const int* __restrict__ perm,
    const float* __restrict__ coord, const float* __restrict__ hh,
    const float* __restrict__ eattr,
    const float* __restrict__ gEW1, const float* __restrict__ gEB1,
    const float* __restrict__ gEW2, const float* __restrict__ gEB2,
    const float* __restrict__ gCW1, const float* __restrict__ gCB1,
    const float* __restrict__ gCW2,
    float* __restrict__ csum, float* __restrict__ magg)
{
    __shared__ __align__(16) ushort_t sW1[131 * 64];   // bf16 edge-MLP W1 (16768 B)
    __shared__ float sB1[64], sB2[64], sCB1[64], sCW2v[64];
    __shared__ __align__(16) float tile[EBLK * 64];    // activation exchange + reduce
    __shared__ int   sr[EBLK], sc[EBLK], se[EBLK];
    __shared__ int   segstart[EBLK + 1];
    __shared__ int   snseg;

    const int t = threadIdx.x;
    // ---- stage W1 (bf16) + biases ----
    for (int i = t; i < 2096; i += 256) {          // 131*64 = 8384 = 2096 float4
        const float4 v = ((const float4*)gEW1)[i];
        sW1[4 * i + 0] = f2bf(v.x); sW1[4 * i + 1] = f2bf(v.y);
        sW1[4 * i + 2] = f2bf(v.z); sW1[4 * i + 3] = f2bf(v.w);
    }
    if (t < 64) { sB1[t] = gEB1[t]; sB2[t] = gEB2[t];
                  sCB1[t] = gCB1[t]; sCW2v[t] = gCW2[t]; }

    // ---- load this block's 64 edges (sorted by row via perm) ----
    if (t < EBLK) {
        int e = perm[blockIdx.x * EBLK + t];
        e = ((uint_t)e < (uint_t)NE) ? e : 0;
        int r = rows[e], c = cols[e];
        r = ((uint_t)r < (uint_t)NN) ? r : 0;
        c = ((uint_t)c < (uint_t)NN) ? c : 0;
        se[t] = e; sr[t] = r; sc[t] = c;
    }
    __syncthreads();

    // ---- segment boundaries over the 64 sorted rows: wave-0 shfl scan ----
    if (t < EBLK) {                     // exactly wave 0 (256-thread block)
        const int flag = (t == 0) ? 1 : ((sr[t] != sr[t - 1]) ? 1 : 0);
        int isc = flag;
        #pragma unroll
        for (int d = 1; d < EBLK; d <<= 1) {
            const int up = __shfl_up(isc, d);
            if (t >= d) isc += up;
        }
        if (flag) segstart[isc - 1] = t;
        if (t == EBLK - 1) { snseg = isc; segstart[isc] = EBLK; }
    }
    __syncthreads();
    const int nseg = snseg;

    // ---- per-thread edge/chunk identity ----
    const int ei = t >> 2;          // edge in block
    const int q  = t & 3;           // channel chunk (16 ch)
    const int sw = ei & 7;          // tile swizzle key
    const int r = sr[ei], c = sc[ei], e = se[ei];

    const float dx = coord[3 * r + 0] - coord[3 * c + 0];
    const float dy = coord[3 * r + 1] - coord[3 * c + 1];
    const float dz = coord[3 * r + 2] - coord[3 * c + 2];
    const float radial = dx * dx + dy * dy + dz * dz;
    const float2 ea = ((const float2*)eattr)[e];

    const float4* hr4 = (const float4*)(hh + (size_t)r * 64);
    const float4* hc4 = (const float4*)(hh + (size_t)c * 64);
    const uint_t* sW1u = (const uint_t*)sW1;
    float4* tile4 = (float4*)tile;

    // ---- hidden layer: acc16 = silu(in131 @ W1[:, q*16..+16]) ----
    float acc16[16];
    #pragma unroll
    for (int j = 0; j < 16; j++) acc16[j] = sB1[q * 16 + j];

    #pragma unroll 2
    for (int kk = 0; kk < 16; kk++) {
        const float4 a = hr4[kk];
        const float av[4] = {a.x, a.y, a.z, a.w};
        #pragma unroll
        for (int u = 0; u < 4; u++) {
            const float v = av[u];
            const uint_t* w = sW1u + (kk * 4 + u) * 32 + q * 8;
            #pragma unroll
            for (int jj = 0; jj < 8; jj++) {
                float lo, hi; unpack2(w[jj], lo, hi);
                acc16[2 * jj]     += v * lo;
                acc16[2 * jj + 1] += v * hi;
            }
        }
    }
    #pragma unroll 2
    for (int kk = 0; kk < 16; kk++) {
        const float4 a = hc4[kk];
        const float av[4] = {a.x, a.y, a.z, a.w};
        #pragma unroll
        for (int u = 0; u < 4; u++) {
            const float v = av[u];
            const uint_t* w = sW1u + (64 + kk * 4 + u) * 32 + q * 8;
            #pragma unroll
            for (int jj = 0; jj < 8; jj++) {
                float lo, hi; unpack2(w[jj], lo, hi);
                acc16[2 * jj]     += v * lo;
                acc16[2 * jj + 1] += v * hi;
            }
        }
    }
    {
        const float ext[3] = {radial, ea.x, ea.y};
        #pragma unroll
        for (int x = 0; x < 3; x++) {
            const float v = ext[x];
            const uint_t* w = sW1u + (128 + x) * 32 + q * 8;
            #pragma unroll
            for (int jj = 0; jj < 8; jj++) {
                float lo, hi; unpack2(w[jj], lo, hi);
                acc16[2 * jj]     += v * lo;
                acc16[2 * jj + 1] += v * hi;
            }
        }
    }
    #pragma unroll
    for (int j = 0; j < 16; j++) acc16[j] = silu(acc16[j]);

    // stage hidden to tile (swizzled)
    #pragma unroll
    for (int j = 0; j < 4; j++) {
        float4 v; v.x = acc16[4 * j]; v.y = acc16[4 * j + 1];
        v.z = acc16[4 * j + 2]; v.w = acc16[4 * j + 3];
        tile4[ei * 16 + ((q * 4 + j) ^ sw)] = v;
    }
    __syncthreads();

    // ---- layer 2: m16 = silu(hid64 @ W2[:, q*16..+16] + b2), W2 from global --
    float m16[16];
    #pragma unroll
    for (int j = 0; j < 16; j++) m16[j] = sB2[q * 16 + j];
    #pragma unroll 4
    for (int kk = 0; kk < 16; kk++) {
        const float4 h4 = tile4[ei * 16 + (kk ^ sw)];
        const float hv[4] = {h4.x, h4.y, h4.z, h4.w};
        #pragma unroll
        for (int u = 0; u < 4; u++) {
            const float v = hv[u];
            const float4* w4 = (const float4*)(gEW2 + (kk * 4 + u) * 64 + q * 16);
            #pragma unroll
            for (int j4 = 0; j4 < 4; j4++) {
                const float4 w = w4[j4];
                m16[4 * j4 + 0] += v * w.x; m16[4 * j4 + 1] += v * w.y;
                m16[4 * j4 + 2] += v * w.z; m16[4 * j4 + 3] += v * w.w;
            }
        }
    }
    #pragma unroll
    for (int j = 0; j < 16; j++) m16[j] = silu(m16[j]);

    __syncthreads();                 // everyone done reading hid
    #pragma unroll
    for (int j = 0; j < 4; j++) {
        float4 v; v.x = m16[4 * j]; v.y = m16[4 * j + 1];
        v.z = m16[4 * j + 2]; v.w = m16[4 * j + 3];
        tile4[ei * 16 + ((q * 4 + j) ^ sw)] = v;
    }
    __syncthreads();                 // tile now holds m for all edges

    // ---- cw = silu(m @ cW1 + cb1) @ cW2, cW1 fp32 from global ----
    float ch16[16];
    #pragma unroll
    for (int j = 0; j < 16; j++) ch16[j] = sCB1[q * 16 + j];
    #pragma unroll 4
    for (int kk = 0; kk < 16; kk++) {
        const float4 m4 = tile4[ei * 16 + (kk ^ sw)];
        const float mv[4] = {m4.x, m4.y, m4.z, m4.w};
        #pragma unroll
        for (int u = 0; u < 4; u++) {
            const float v = mv[u];
            const float4* w4 = (const float4*)(gCW1 + (kk * 4 + u) * 64 + q * 16);
            #pragma unroll
            for (int j4 = 0; j4 < 4; j4++) {
                const float4 w = w4[j4];
                ch16[4 * j4 + 0] += v * w.x; ch16[4 * j4 + 1] += v * w.y;
                ch16[4 * j4 + 2] += v * w.z; ch16[4 * j4 + 3] += v * w.w;
            }
        }
    }
    float part = 0.f;
    #pragma unroll
    for (int j = 0; j < 16; j++) part += silu(ch16[j]) * sCW2v[q * 16 + j];
    part += __shfl_xor(part, 1);
    part += __shfl_xor(part, 2);
    const float cw = part;

    // ---- segmented reduction: magg (all 64 channels from tile-m) ----
    for (int w = t; w < nseg * 64; w += 256) {
        const int lr2 = w >> 6, cc = w & 63;
        const int p0 = segstart[lr2], p1 = segstart[lr2 + 1];
        float s = 0.f;
        for (int p = p0; p < p1; p++)
            s += tile[p * 64 + ((((cc >> 2) ^ (p & 7)) << 2) | (cc & 3))];
        atomicAdd(&magg[(size_t)sr[p0] * 64 + cc], s);
    }
    __syncthreads();

    // ---- segmented reduction: csum (3 coords; stage in tile[0..255]) ----
    if (q < 3) tile[ei * 4 + q] = (q == 0 ? dx : (q == 1 ? dy : dz)) * cw;
    __syncthreads();
    for (int w = t; w < nseg * 3; w += 256) {
        const int lr2 = w / 3, cc = w - 3 * lr2;
        const int p0 = segstart[lr2], p1 = segstart[lr2 + 1];
        float s = 0.f;
        for (int p = p0; p < p1; p++) s += tile[p * 4 + cc];
        atomicAdd(&csum[3 * sr[p0] + cc], s);
    }
}

// ---- per-layer node kernel: 4 threads per node, 16 channels per thread -------
// (unchanged from round 4 — validated)
__global__ __launch_bounds__(256, 2) void node_kernel(
    const float* __restrict__ gVW1, const float* __restrict__ gVB1,
    const float* __restrict__ gVW2, const float* __restrict__ gVB2,
    const float* __restrict__ gGW1, const float* __restrict__ gGB1,
    const float* __restrict__ gGW2, const float* __restrict__ gGB2,
    const float* __restrict__ gNW1, const float* __restrict__ gNB1,
    const float* __restrict__ gNW2, const float* __restrict__ gNB2,
    const float* __restrict__ csum, const int* __restrict__ off,
    const float* __restrict__ vsrc, const float* __restrict__ field,
    const float* __restrict__ magg,
    float* __restrict__ coord, float* __restrict__ hh)
{
    __shared__ __align__(16) float sNW1[128 * 64];     // 32 KB
    __shared__ __align__(16) float tile[NPB * 64];     // 16 KB exchange
    __shared__ float sNB1[64], sNB2[64];

    const int t = threadIdx.x;
    for (int i = t; i < 2048; i += 256) ((float4*)sNW1)[i] = ((const float4*)gNW1)[i];
    if (t < 64) { sNB1[t] = gNB1[t]; sNB2[t] = gNB2[t]; }
    __syncthreads();

    const int ni = t >> 2;          // node in block
    const int q  = t & 3;           // channel chunk
    const int sw = ni & 7;          // tile swizzle key
    int n = blockIdx.x * NPB + ni;
    const bool valid = (n < NN);
    n = valid ? n : (NN - 1);       // clamp for safe reads; writes predicated

    const float4* hh4 = (const float4*)(hh + (size_t)n * 64);
    const float4* mg4 = (const float4*)(magg + (size_t)n * 64);
    float4* tile4 = (float4*)tile;

    // ---- vw = silu(hh @ vW1 + vb1) @ vW2 + vb2 ----
    float a16[16];
    #pragma unroll
    for (int j = 0; j < 16; j++) a16[j] = gVB1[q * 16 + j];
    #pragma unroll 2
    for (int kk = 0; kk < 16; kk++) {
        const float4 h4 = hh4[kk];
        const float hv[4] = {h4.x, h4.y, h4.z, h4.w};
        #pragma unroll
        for (int u = 0; u < 4; u++) {
            const float v = hv[u];
            const float4* w4 = (const float4*)(gVW1 + (kk * 4 + u) * 64 + q * 16);
            #pragma unroll
            for (int j4 = 0; j4 < 4; j4++) {
                const float4 w = w4[j4];
                a16[4 * j4 + 0] += v * w.x; a16[4 * j4 + 1] += v * w.y;
                a16[4 * j4 + 2] += v * w.z; a16[4 * j4 + 3] += v * w.w;
            }
        }
    }
    float part = 0.f;
    #pragma unroll
    for (int j = 0; j < 16; j++) part += silu(a16[j]) * gVW2[q * 16 + j];
    part += __shfl_xor(part, 1);
    part += __shfl_xor(part, 2);
    const float vw = part + gVB2[0];

    // ---- gw = silu(hh @ gW1 + gb1) @ gW2 + gb2 (reuses a16) ----
    #pragma unroll
    for (int j = 0; j < 16; j++) a16[j] = gGB1[q * 16 + j];
    #pragma unroll 2
    for (int kk = 0; kk < 16; kk++) {
        const float4 h4 = hh4[kk];
        const float hv[4] = {h4.x, h4.y, h4.z, h4.w};
        #pragma unroll
        for (int u = 0; u < 4; u++) {
            const float v = hv[u];
            const float4* w4 = (const float4*)(gGW1 + (kk * 4 + u) * 64 + q * 16);
            #pragma unroll
            for (int j4 = 0; j4 < 4; j4++) {
                const float4 w = w4[j4];
                a16[4 * j4 + 0] += v * w.x; a16[4 * j4 + 1] += v * w.y;
                a16[4 * j4 + 2] += v * w.z; a16[4 * j4 + 3] += v * w.w;
            }
        }
    }
    part = 0.f;
    #pragma unroll
    for (int j = 0; j < 16; j++) part += silu(a16[j]) * gGW2[q * 16 + j];
    part += __shfl_xor(part, 1);
    part += __shfl_xor(part, 2);
    const float gw = part + gGB2[0];

    // ---- coord update (one thread per node) ----
    if (valid && q == 0) {
        const float cn = fmaxf((float)(off[n + 1] - off[n]), 1.0f);
        #pragma unroll
        for (int d = 0; d < 3; d++)
            coord[3 * n + d] += csum[3 * n + d] / cn
                              + vw * vsrc[3 * n + d]
                              + gw * field[3 * n + d];
    }

    // ---- node MLP hidden: a16 = silu([hh, magg] @ NW1[:, q*16..+16] + b1) ----
    #pragma unroll
    for (int j = 0; j < 16; j++) a16[j] = sNB1[q * 16 + j];
    #pragma unroll 2
    for (int kk = 0; kk < 16; kk++) {
        const float4 h4 = hh4[kk];
        const float hv[4] = {h4.x, h4.y, h4.z, h4.w};
        #pragma unroll
        for (int u = 0; u < 4; u++) {
            const float v = hv[u];
            const float* w = &sNW1[(kk * 4 + u) * 64 + q * 16];
            #pragma unroll
            for (int j = 0; j < 16; j++) a16[j] += v * w[j];
        }
    }
    #pragma unroll 2
    for (int kk = 0; kk < 16; kk++) {
        const float4 m4 = mg4[kk];
        const float mv[4] = {m4.x, m4.y, m4.z, m4.w};
        #pragma unroll
        for (int u = 0; u < 4; u++) {
            const float v = mv[u];
            const float* w = &sNW1[(64 + kk * 4 + u) * 64 + q * 16];
            #pragma unroll
            for (int j = 0; j < 16; j++) a16[j] += v * w[j];
        }
    }
    #pragma unroll
    for (int j = 0; j < 16; j++) a16[j] = silu(a16[j]);

    // ---- exchange hidden through swizzled tile ----
    #pragma unroll
    for (int j = 0; j < 4; j++) {
        float4 v; v.x = a16[4 * j]; v.y = a16[4 * j + 1];
        v.z = a16[4 * j + 2]; v.w = a16[4 * j + 3];
        tile4[ni * 16 + ((q * 4 + j) ^ sw)] = v;
    }
    __syncthreads();

    // ---- output: o16 = hid64 @ NW2[:, q*16..+16] + b2 ----
    float o16[16];
    #pragma unroll
    for (int j = 0; j < 16; j++) o16[j] = sNB2[q * 16 + j];
    #pragma unroll 2
    for (int kk = 0; kk < 16; kk++) {
        const float4 h4 = tile4[ni * 16 + (kk ^ sw)];
        const float hv[4] = {h4.x, h4.y, h4.z, h4.w};
        #pragma unroll
        for (int u = 0; u < 4; u++) {
            const float v = hv[u];
            const float4* w4 = (const float4*)(gNW2 + (kk * 4 + u) * 64 + q * 16);
            #pragma unroll
            for (int j4 = 0; j4 < 4; j4++) {
                const float4 w = w4[j4];
                o16[4 * j4 + 0] += v * w.x; o16[4 * j4 + 1] += v * w.y;
                o16[4 * j4 + 2] += v * w.z; o16[4 * j4 + 3] += v * w.w;
            }
        }
    }
    if (valid) {
        float4* out4 = (float4*)(hh + (size_t)n * 64 + q * 16);
        #pragma unroll
        for (int j4 = 0; j4 < 4; j4++) {
            float4 v; v.x = o16[4 * j4]; v.y = o16[4 * j4 + 1];
            v.z = o16[4 * j4 + 2]; v.w = o16[4 * j4 + 3];
            out4[j4] = v;
        }
    }
}

// ---- host launch -------------------------------------------------------------
extern "C" void kernel_launch(void* const* d_in, const int* in_sizes, int n_in,
                              void* d_out, int out_size, void* d_ws, size_t ws_size,
                              hipStream_t stream) {
    float* wsf = (float*)d_ws;
    int*   wsi = (int*)(wsf + 1340000);
    float* coord = (float*)d_out;          // fp32 coord state lives in d_out
    const int* edges = (const int*)d_in[4];
    const int* rows = edges;
    const int* cols = edges + NE;

    // ---- CSR build (once per call) ----
    hipMemsetAsync(wsi + IOFF_CNTI, 0, NN * sizeof(int), stream);
    counti_kernel<<<(NE + 255) / 256, 256, 0, stream>>>(rows, wsi + IOFF_CNTI);
    scan_kernel<<<1, 1024, 0, stream>>>(wsi + IOFF_CNTI, wsi + IOFF_OFF, wsi + IOFF_CURSOR);
    scatter_kernel<<<(NE + 255) / 256, 256, 0, stream>>>(rows, wsi + IOFF_CURSOR,
                                                         wsi + IOFF_PERM);

    node_init<<<(NN + 255) / 256, 256, 0, stream>>>(
        (const float*)d_in[0], (const float*)d_in[1], (const float*)d_in[2],
        (const int*)d_in[5], (const float*)d_in[8],
        (const float*)d_in[9],  (const float*)d_in[10],
        (const float*)d_in[11], (const float*)d_in[12],
        (const float*)d_in[13], (const float*)d_in[14],
        (const float*)d_in[6],  (const float*)d_in[7],
        coord, wsf + OFF_FIELD, wsf + OFF_HH);

    for (int l = 0; l < NL; l++) {
        hipMemsetAsync(wsf + OFF_CSUM, 0, (30000 + 640000) * sizeof(float), stream);
        edge_kernel<<<NEBLK, 256, 0, stream>>>(
            rows, cols, wsi + IOFF_PERM,
            coord, wsf + OFF_HH, (const float*)d_in[3],
            ((const float*)d_in[15]) + l * 8384, ((const float*)d_in[16]) + l * 64,
            ((const float*)d_in[17]) + l * 4096, ((const float*)d_in[18]) + l * 64,
            ((const float*)d_in[23]) + l * 4096, ((const float*)d_in[24]) + l * 64,
            ((const float*)d_in[25]) + l * 64,
            wsf + OFF_CSUM, wsf + OFF_MAGG);
        node_kernel<<<NNODEBLK, 256, 0, stream>>>(
            ((const float*)d_in[26]) + l * 4096, ((const float*)d_in[27]) + l * 64,
            ((const float*)d_in[28]) + l * 64,   ((const float*)d_in[29]) + l,
            ((const float*)d_in[30]) + l * 4096, ((const float*)d_in[31]) + l * 64,
            ((const float*)d_in[32]) + l * 64,   ((const float*)d_in[33]) + l,
            ((const float*)d_in[19]) + l * 8192, ((const float*)d_in[20]) + l * 64,
            ((const float*)d_in[21]) + l * 4096, ((const float*)d_in[22]) + l * 64,
            wsf + OFF_CSUM, wsi + IOFF_OFF, (const float*)d_in[2],
            wsf + OFF_FIELD, wsf + OFF_MAGG, coord, wsf + OFF_HH);
    }
}

// Round 7
// 1432.339 us; speedup vs baseline: 1.9647x; 1.9647x over previous
//
#include <hip/hip_runtime.h>
#include <hip/hip_bf16.h>

typedef unsigned short ushort_t;
typedef unsigned int uint_t;

#define NN    10000
#define NE    320000
#define NL    4
#define EBLK  64        // edges per block (4 threads per edge)
#define NEBLK 5000      // NE / EBLK exactly
#define NPB   64        // nodes per block in node_kernel (4 threads per node)
#define NNODEBLK 157    // ceil(NN / NPB)

// ---- workspace float offsets -------------------------------------------------
// coord lives directly in d_out (fp32, 30000 elems, fully initialized by node_init)
#define OFF_FIELD 0        // 30000
#define OFF_HH    30000    // 640000
#define OFF_CSUM  670000   // 30000  (contiguous with MAGG for one memset)
#define OFF_MAGG  700000   // 640000 -> float end 1340000
// ---- int region (starts at float offset 1340000) ----------------------------
#define IOFF_CNTI   0        // 10000
#define IOFF_OFF    10000    // 10001
#define IOFF_CURSOR 20001    // 10000
#define IOFF_PERM   30001    // 320000 -> int end 350001 (total ws ~6.76 MB)

// fast silu: v_rcp_f32 instead of IEEE divide (~1e-7 rel err, VALU-bound paths)
__device__ __forceinline__ float silu(float x) {
    return x * __builtin_amdgcn_rcpf(1.0f + __expf(-x));
}
// fp32 -> bf16 round-to-nearest-even
__device__ __forceinline__ ushort_t f2bf(float f) {
    union { float f; uint_t u; } v; v.f = f;
    const uint_t r = (v.u + 0x7FFFu + ((v.u >> 16) & 1u)) >> 16;
    return (ushort_t)r;
}
__device__ __forceinline__ void unpack2(uint_t p, float& lo, float& hi) {
    union { uint_t u; float f; } a, b;
    a.u = p << 16; b.u = p & 0xffff0000u;
    lo = a.f; hi = b.f;
}

// ---- CSR build: per-row int counts ------------------------------------------
__global__ __launch_bounds__(256) void counti_kernel(const int* __restrict__ rows,
                                                     int* __restrict__ cnti) {
    const int e = blockIdx.x * 256 + threadIdx.x;
    if (e < NE) {
        int r = rows[e];
        r = ((uint_t)r < (uint_t)NN) ? r : 0;
        atomicAdd(&cnti[r], 1);
    }
}

// ---- CSR build: exclusive scan over 10000 counts (single block) --------------
__global__ __launch_bounds__(1024) void scan_kernel(const int* __restrict__ cnti,
                                                    int* __restrict__ off,
                                                    int* __restrict__ cursor) {
    __shared__ int part[1024];
    const int t = threadIdx.x;
    const int base = t * 10;
    int loc[10];
    int s = 0;
    #pragma unroll
    for (int i = 0; i < 10; i++) {
        const int idx = base + i;
        const int v = (idx < NN) ? cnti[idx] : 0;
        loc[i] = s; s += v;
    }
    part[t] = s;
    __syncthreads();
    const int own = s;
    for (int d = 1; d < 1024; d <<= 1) {
        const int v = (t >= d) ? part[t - d] : 0;
        __syncthreads();
        part[t] += v;
        __syncthreads();
    }
    const int excl = part[t] - own;
    #pragma unroll
    for (int i = 0; i < 10; i++) {
        const int idx = base + i;
        if (idx < NN) { const int o = excl + loc[i]; off[idx] = o; cursor[idx] = o; }
    }
    if (t == 0) off[NN] = NE;
}

// ---- CSR build: scatter edge ids into row-sorted order -----------------------
__global__ __launch_bounds__(256) void scatter_kernel(const int* __restrict__ rows,
                                                      int* __restrict__ cursor,
                                                      int* __restrict__ perm) {
    const int e = blockIdx.x * 256 + threadIdx.x;
    if (e < NE) {
        int r = rows[e];
        r = ((uint_t)r < (uint_t)NN) ? r : 0;
        const int pos = atomicAdd(&cursor[r], 1);
        if ((uint_t)pos < (uint_t)NE) perm[pos] = e;
    }
}

// ---- field network + node embedding + coord init (once per call) ------------
__global__ __launch_bounds__(256) void node_init(
    const float* __restrict__ hsrc, const float* __restrict__ xsrc,
    const float* __restrict__ vsrc, const int* __restrict__ charges,
    const float* __restrict__ cls,
    const float* __restrict__ fW1, const float* __restrict__ fb1,
    const float* __restrict__ fW2, const float* __restrict__ fb2,
    const float* __restrict__ fW3, const float* __restrict__ fb3,
    const float* __restrict__ embW, const float* __restrict__ embb,
    float* __restrict__ coord, float* __restrict__ field, float* __restrict__ hh)
{
    __shared__ float sFW1[704], sFW2[1024], sFW3[96];
    __shared__ float sFB1[32], sFB2[32], sFB3[3], sCLS[32], sEW[64], sEB[64];
    const int t = threadIdx.x;
    for (int i = t; i < 704; i += 256) sFW1[i] = fW1[i];
    for (int i = t; i < 1024; i += 256) sFW2[i] = fW2[i];
    if (t < 96) sFW3[t] = fW3[t];
    if (t < 32) { sFB1[t] = fb1[t]; sFB2[t] = fb2[t]; sCLS[t] = cls[t]; }
    if (t < 3)  sFB3[t] = fb3[t];
    if (t < 64) { sEW[t] = embW[t]; sEB[t] = embb[t]; }
    __syncthreads();

    const int n = blockIdx.x * 256 + t;
    if (n >= NN) return;

    float fin[22];
    #pragma unroll
    for (int d = 0; d < 3; d++) {
        fin[d]     = xsrc[3 * n + d];
        fin[3 + d] = vsrc[3 * n + d];
        coord[3 * n + d] = fin[d];
    }
    int ci = charges[n];
    ci = ((uint_t)ci < 2u) ? ci : 0;
    const int cix = ci * 16;
    #pragma unroll
    for (int k = 0; k < 16; k++) fin[6 + k] = sCLS[cix + k];

    float h1[32];
    #pragma unroll
    for (int j = 0; j < 32; j++) h1[j] = sFB1[j];
    #pragma unroll
    for (int k = 0; k < 22; k++) {
        const float v = fin[k];
        #pragma unroll
        for (int j = 0; j < 32; j++) h1[j] += v * sFW1[k * 32 + j];
    }
    #pragma unroll
    for (int j = 0; j < 32; j++) h1[j] = silu(h1[j]);

    float h2[32];
    #pragma unroll
    for (int j = 0; j < 32; j++) h2[j] = sFB2[j];
    #pragma unroll
    for (int k = 0; k < 32; k++) {
        const float v = h1[k];
        #pragma unroll
        for (int j = 0; j < 32; j++) h2[j] += v * sFW2[k * 32 + j];
    }
    #pragma unroll
    for (int j = 0; j < 32; j++) h2[j] = silu(h2[j]);

    #pragma unroll
    for (int d = 0; d < 3; d++) {
        float s = sFB3[d];
        #pragma unroll
        for (int j = 0; j < 32; j++) s += h2[j] * sFW3[j * 3 + d];
        field[3 * n + d] = s;
    }

    const float hv = hsrc[n];
    #pragma unroll
    for (int j = 0; j < 64; j++) hh[(size_t)n * 64 + j] = hv * sEW[j] + sEB[j];
}

// ---- per-layer edge kernel: 4 threads per edge, 16 channels per thread -------
// Round-7: revert to round-3/4 LDS-weight GEMMs (round-6 proved global weight
// reads are L1-bandwidth-bound: 8KB/thread of unshared L1 traffic ~= 260us;
// LDS same-address broadcast serves 16 lanes/address for free).
// Occupancy lever done right: sW1 (16.8KB, phase-1 only) ALIASES the exchange
// tile (16KB, phase-2+) via a union buffer, with one extra barrier between the
// last sW1 read and the first tile write.
// LDS: union 16768 + sW2 16384 + sCW1 8192 + biases 1024 + misc ~1.1KB
//   ~= 43.7 KB  =>  3 blocks/CU (launch_bounds(256,3); VGPR ~88 << 170 cap).
__global__ __launch_bounds__(256, 3) void edge_kernel(
    const int* __restrict__ rows, const int* __restrict__ cols,
    const int* __restrict__ perm,
    const float* __restrict__ coord, const float* __restrict__ hh,
    const float* __restrict__ eattr,
    const float* __restrict__ gEW1, const float* __restrict__ gEB1,
    const float* __restrict__ gEW2, const float* __restrict__ gEB2,
    const float* __restrict__ gCW1, const float* __restrict__ gCB1,
    const float* __restrict__ gCW2,
    float* __restrict__ csum, float* __restrict__ magg)
{
    // union region: phase 1 = bf16 W1 (131*64 ushort = 16768 B)
    //               phase 2+ = fp32 exchange tile (64*64 float = 16384 B)
    __shared__ __align__(16) uint_t uBuf[4192];        // 16768 B
    __shared__ __align__(16) float    sW2[64 * 64];    // fp32 edge-MLP W2 (16384 B)
    __shared__ __align__(16) ushort_t sCW1[64 * 64];   // bf16 coord-MLP W1 (8192 B)
    __shared__ float sB1[64], sB2[64], sCB1[64], sCW2v[64];
    __shared__ int   sr[EBLK], sc[EBLK], se[EBLK];
    __shared__ int   segstart[EBLK + 1];
    __shared__ int   snseg;

    ushort_t* sW1  = (ushort_t*)uBuf;
    float*    tile = (float*)uBuf;
    float4*   tile4 = (float4*)uBuf;

    const int t = threadIdx.x;
    // ---- stage weights ----
    for (int i = t; i < 2096; i += 256) {          // 131*64 = 8384 = 2096 float4
        const float4 v = ((const float4*)gEW1)[i];
        sW1[4 * i + 0] = f2bf(v.x); sW1[4 * i + 1] = f2bf(v.y);
        sW1[4 * i + 2] = f2bf(v.z); sW1[4 * i + 3] = f2bf(v.w);
    }
    for (int i = t; i < 1024; i += 256) ((float4*)sW2)[i] = ((const float4*)gEW2)[i];
    for (int i = t; i < 1024; i += 256) {          // 64*64 = 4096 = 1024 float4
        const float4 v = ((const float4*)gCW1)[i];
        sCW1[4 * i + 0] = f2bf(v.x); sCW1[4 * i + 1] = f2bf(v.y);
        sCW1[4 * i + 2] = f2bf(v.z); sCW1[4 * i + 3] = f2bf(v.w);
    }
    if (t < 64) { sB1[t] = gEB1[t]; sB2[t] = gEB2[t];
                  sCB1[t] = gCB1[t]; sCW2v[t] = gCW2[t]; }

    // ---- load this block's 64 edges (sorted by row via perm) ----
    if (t < EBLK) {
        int e = perm[blockIdx.x * EBLK + t];
        e = ((uint_t)e < (uint_t)NE) ? e : 0;
        int r = rows[e], c = cols[e];
        r = ((uint_t)r < (uint_t)NN) ? r : 0;
        c = ((uint_t)c < (uint_t)NN) ? c : 0;
        se[t] = e; sr[t] = r; sc[t] = c;
    }
    __syncthreads();

    // ---- segment boundaries over the 64 sorted rows: wave-0 shfl scan ----
    if (t < EBLK) {                     // exactly wave 0 (256-thread block)
        const int flag = (t == 0) ? 1 : ((sr[t] != sr[t - 1]) ? 1 : 0);
        int isc = flag;
        #pragma unroll
        for (int d = 1; d < EBLK; d <<= 1) {
            const int up = __shfl_up(isc, d);
            if (t >= d) isc += up;
        }
        if (flag) segstart[isc - 1] = t;
        if (t == EBLK - 1) { snseg = isc; segstart[isc] = EBLK; }
    }
    __syncthreads();
    const int nseg = snseg;

    // ---- per-thread edge/chunk identity ----
    const int ei = t >> 2;          // edge in block
    const int q  = t & 3;           // channel chunk (16 ch)
    const int sw = ei & 7;          // tile swizzle key
    const int r = sr[ei], c = sc[ei], e = se[ei];

    const float dx = coord[3 * r + 0] - coord[3 * c + 0];
    const float dy = coord[3 * r + 1] - coord[3 * c + 1];
    const float dz = coord[3 * r + 2] - coord[3 * c + 2];
    const float radial = dx * dx + dy * dy + dz * dz;
    const float2 ea = ((const float2*)eattr)[e];

    const float4* hr4 = (const float4*)(hh + (size_t)r * 64);
    const float4* hc4 = (const float4*)(hh + (size_t)c * 64);
    const uint_t* sW1u = (const uint_t*)sW1;

    // ---- phase 1: acc16 = silu(in131 @ W1[:, q*16..+16])  (reads sW1) ----
    float acc16[16];
    #pragma unroll
    for (int j = 0; j < 16; j++) acc16[j] = sB1[q * 16 + j];

    #pragma unroll 2
    for (int kk = 0; kk < 16; kk++) {
        const float4 a = hr4[kk];
        const float av[4] = {a.x, a.y, a.z, a.w};
        #pragma unroll
        for (int u = 0; u < 4; u++) {
            const float v = av[u];
            const uint_t* w = sW1u + (kk * 4 + u) * 32 + q * 8;
            #pragma unroll
            for (int jj = 0; jj < 8; jj++) {
                float lo, hi; unpack2(w[jj], lo, hi);
                acc16[2 * jj]     += v * lo;
                acc16[2 * jj + 1] += v * hi;
            }
        }
    }
    #pragma unroll 2
    for (int kk = 0; kk < 16; kk++) {
        const float4 a = hc4[kk];
        const float av[4] = {a.x, a.y, a.z, a.w};
        #pragma unroll
        for (int u = 0; u < 4; u++) {
            const float v = av[u];
            const uint_t* w = sW1u + (64 + kk * 4 + u) * 32 + q * 8;
            #pragma unroll
            for (int jj = 0; jj < 8; jj++) {
                float lo, hi; unpack2(w[jj], lo, hi);
                acc16[2 * jj]     += v * lo;
                acc16[2 * jj + 1] += v * hi;
            }
        }
    }
    {
        const float ext[3] = {radial, ea.x, ea.y};
        #pragma unroll
        for (int x = 0; x < 3; x++) {
            const float v = ext[x];
            const uint_t* w = sW1u + (128 + x) * 32 + q * 8;
            #pragma unroll
            for (int jj = 0; jj < 8; jj++) {
                float lo, hi; unpack2(w[jj], lo, hi);
                acc16[2 * jj]     += v * lo;
                acc16[2 * jj + 1] += v * hi;
            }
        }
    }
    #pragma unroll
    for (int j = 0; j < 16; j++) acc16[j] = silu(acc16[j]);

    __syncthreads();   // ALL sW1 reads complete before tile overwrites uBuf

    // ---- stage hidden to tile (swizzled; clobbers sW1 region) ----
    #pragma unroll
    for (int j = 0; j < 4; j++) {
        float4 v; v.x = acc16[4 * j]; v.y = acc16[4 * j + 1];
        v.z = acc16[4 * j + 2]; v.w = acc16[4 * j + 3];
        tile4[ei * 16 + ((q * 4 + j) ^ sw)] = v;
    }
    __syncthreads();

    // ---- layer 2: m16 = silu(hid64 @ W2[:, q*16..+16] + b2)  (W2 in LDS) ----
    float m16[16];
    #pragma unroll
    for (int j = 0; j < 16; j++) m16[j] = sB2[q * 16 + j];
    #pragma unroll 4
    for (int kk = 0; kk < 16; kk++) {
        const float4 h4 = tile4[ei * 16 + (kk ^ sw)];
        const float hv[4] = {h4.x, h4.y, h4.z, h4.w};
        #pragma unroll
        for (int u = 0; u < 4; u++) {
            const float v = hv[u];
            const float* w = &sW2[(kk * 4 + u) * 64 + q * 16];
            #pragma unroll
            for (int j = 0; j < 16; j++) m16[j] += v * w[j];
        }
    }
    #pragma unroll
    for (int j = 0; j < 16; j++) m16[j] = silu(m16[j]);

    __syncthreads();                 // everyone done reading hid
    #pragma unroll
    for (int j = 0; j < 4; j++) {
        float4 v; v.x = m16[4 * j]; v.y = m16[4 * j + 1];
        v.z = m16[4 * j + 2]; v.w = m16[4 * j + 3];
        tile4[ei * 16 + ((q * 4 + j) ^ sw)] = v;
    }
    __syncthreads();                 // tile now holds m for all edges

    // ---- cw = silu(m @ cW1 + cb1) @ cW2  (cW1 bf16 in LDS) ----
    float ch16[16];
    #pragma unroll
    for (int j = 0; j < 16; j++) ch16[j] = sCB1[q * 16 + j];
    {
        const uint_t* sCW1u = (const uint_t*)sCW1;
        #pragma unroll 4
        for (int kk = 0; kk < 16; kk++) {
            const float4 m4 = tile4[ei * 16 + (kk ^ sw)];
            const float mv[4] = {m4.x, m4.y, m4.z, m4.w};
            #pragma unroll
            for (int u = 0; u < 4; u++) {
                const float v = mv[u];
                const uint_t* w = sCW1u + (kk * 4 + u) * 32 + q * 8;
                #pragma unroll
                for (int jj = 0; jj < 8; jj++) {
                    float lo, hi; unpack2(w[jj], lo, hi);
                    ch16[2 * jj]     += v * lo;
                    ch16[2 * jj + 1] += v * hi;
                }
            }
        }
    }
    float part = 0.f;
    #pragma unroll
    for (int j = 0; j < 16; j++) part += silu(ch16[j]) * sCW2v[q * 16 + j];
    part += __shfl_xor(part, 1);
    part += __shfl_xor(part, 2);
    const float cw = part;

    // ---- segmented reduction: magg (all 64 channels from tile-m) ----
    for (int w = t; w < nseg * 64; w += 256) {
        const int lr2 = w >> 6, cc = w & 63;
        const int p0 = segstart[lr2], p1 = segstart[lr2 + 1];
        float s = 0.f;
        for (int p = p0; p < p1; p++)
            s += tile[p * 64 + ((((cc >> 2) ^ (p & 7)) << 2) | (cc & 3))];
        atomicAdd(&magg[(size_t)sr[p0] * 64 + cc], s);
    }
    __syncthreads();

    // ---- segmented reduction: csum (3 coords; stage in tile[0..255]) ----
    if (q < 3) tile[ei * 4 + q] = (q == 0 ? dx : (q == 1 ? dy : dz)) * cw;
    __syncthreads();
    for (int w = t; w < nseg * 3; w += 256) {
        const int lr2 = w / 3, cc = w - 3 * lr2;
        const int p0 = segstart[lr2], p1 = segstart[lr2 + 1];
        float s = 0.f;
        for (int p = p0; p < p1; p++) s += tile[p * 4 + cc];
        atomicAdd(&csum[3 * sr[p0] + cc], s);
    }
}

// ---- per-layer node kernel: 4 threads per node, 16 channels per thread -------
// (unchanged from round 4 — validated)
__global__ __launch_bounds__(256, 2) void node_kernel(
    const float* __restrict__ gVW1, const float* __restrict__ gVB1,
    const float* __restrict__ gVW2, const float* __restrict__ gVB2,
    const float* __restrict__ gGW1, const float* __restrict__ gGB1,
    const float* __restrict__ gGW2, const float* __restrict__ gGB2,
    const float* __restrict__ gNW1, const float* __restrict__ gNB1,
    const float* __restrict__ gNW2, const float* __restrict__ gNB2,
    const float* __restrict__ csum, const int* __restrict__ off,
    const float* __restrict__ vsrc, const float* __restrict__ field,
    const float* __restrict__ magg,
    float* __restrict__ coord, float* __restrict__ hh)
{
    __shared__ __align__(16) float sNW1[128 * 64];     // 32 KB
    __shared__ __align__(16) float tile[NPB * 64];     // 16 KB exchange
    __shared__ float sNB1[64], sNB2[64];

    const int t = threadIdx.x;
    for (int i = t; i < 2048; i += 256) ((float4*)sNW1)[i] = ((const float4*)gNW1)[i];
    if (t < 64) { sNB1[t] = gNB1[t]; sNB2[t] = gNB2[t]; }
    __syncthreads();

    const int ni = t >> 2;          // node in block
    const int q  = t & 3;           // channel chunk
    const int sw = ni & 7;          // tile swizzle key
    int n = blockIdx.x * NPB + ni;
    const bool valid = (n < NN);
    n = valid ? n : (NN - 1);       // clamp for safe reads; writes predicated

    const float4* hh4 = (const float4*)(hh + (size_t)n * 64);
    const float4* mg4 = (const float4*)(magg + (size_t)n * 64);
    float4* tile4 = (float4*)tile;

    // ---- vw = silu(hh @ vW1 + vb1) @ vW2 + vb2 ----
    float a16[16];
    #pragma unroll
    for (int j = 0; j < 16; j++) a16[j] = gVB1[q * 16 + j];
    #pragma unroll 2
    for (int kk = 0; kk < 16; kk++) {
        const float4 h4 = hh4[kk];
        const float hv[4] = {h4.x, h4.y, h4.z, h4.w};
        #pragma unroll
        for (int u = 0; u < 4; u++) {
            const float v = hv[u];
            const float4* w4 = (const float4*)(gVW1 + (kk * 4 + u) * 64 + q * 16);
            #pragma unroll
            for (int j4 = 0; j4 < 4; j4++) {
                const float4 w = w4[j4];
                a16[4 * j4 + 0] += v * w.x; a16[4 * j4 + 1] += v * w.y;
                a16[4 * j4 + 2] += v * w.z; a16[4 * j4 + 3] += v * w.w;
            }
        }
    }
    float part = 0.f;
    #pragma unroll
    for (int j = 0; j < 16; j++) part += silu(a16[j]) * gVW2[q * 16 + j];
    part += __shfl_xor(part, 1);
    part += __shfl_xor(part, 2);
    const float vw = part + gVB2[0];

    // ---- gw = silu(hh @ gW1 + gb1) @ gW2 + gb2 (reuses a16) ----
    #pragma unroll
    for (int j = 0; j < 16; j++) a16[j] = gGB1[q * 16 + j];
    #pragma unroll 2
    for (int kk = 0; kk < 16; kk++) {
        const float4 h4 = hh4[kk];
        const float hv[4] = {h4.x, h4.y, h4.z, h4.w};
        #pragma unroll
        for (int u = 0; u < 4; u++) {
            const float v = hv[u];
            const float4* w4 = (const float4*)(gGW1 + (kk * 4 + u) * 64 + q * 16);
            #pragma unroll
            for (int j4 = 0; j4 < 4; j4++) {
                const float4 w = w4[j4];
                a16[4 * j4 + 0] += v * w.x; a16[4 * j4 + 1] += v * w.y;
                a16[4 * j4 + 2] += v * w.z; a16[4 * j4 + 3] += v * w.w;
            }
        }
    }
    part = 0.f;
    #pragma unroll
    for (int j = 0; j < 16; j++) part += silu(a16[j]) * gGW2[q * 16 + j];
    part += __shfl_xor(part, 1);
    part += __shfl_xor(part, 2);
    const float gw = part + gGB2[0];

    // ---- coord update (one thread per node) ----
    if (valid && q == 0) {
        const float cn = fmaxf((float)(off[n + 1] - off[n]), 1.0f);
        #pragma unroll
        for (int d = 0; d < 3; d++)
            coord[3 * n + d] += csum[3 * n + d] / cn
                              + vw * vsrc[3 * n + d]
                              + gw * field[3 * n + d];
    }

    // ---- node MLP hidden: a16 = silu([hh, magg] @ NW1[:, q*16..+16] + b1) ----
    #pragma unroll
    for (int j = 0; j < 16; j++) a16[j] = sNB1[q * 16 + j];
    #pragma unroll 2
    for (int kk = 0; kk < 16; kk++) {
        const float4 h4 = hh4[kk];
        const float hv[4] = {h4.x, h4.y, h4.z, h4.w};
        #pragma unroll
        for (int u = 0; u < 4; u++) {
            const float v = hv[u];
            const float* w = &sNW1[(kk * 4 + u) * 64 + q * 16];
            #pragma unroll
            for (int j = 0; j < 16; j++) a16[j] += v * w[j];
        }
    }
    #pragma unroll 2
    for (int kk = 0; kk < 16; kk++) {
        const float4 m4 = mg4[kk];
        const float mv[4] = {m4.x, m4.y, m4.z, m4.w};
        #pragma unroll
        for (int u = 0; u < 4; u++) {
            const float v = mv[u];
            const float* w = &sNW1[(64 + kk * 4 + u) * 64 + q * 16];
            #pragma unroll
            for (int j = 0; j < 16; j++) a16[j] += v * w[j];
        }
    }
    #pragma unroll
    for (int j = 0; j < 16; j++) a16[j] = silu(a16[j]);

    // ---- exchange hidden through swizzled tile ----
    #pragma unroll
    for (int j = 0; j < 4; j++) {
        float4 v; v.x = a16[4 * j]; v.y = a16[4 * j + 1];
        v.z = a16[4 * j + 2]; v.w = a16[4 * j + 3];
        tile4[ni * 16 + ((q * 4 + j) ^ sw)] = v;
    }
    __syncthreads();

    // ---- output: o16 = hid64 @ NW2[:, q*16..+16] + b2 ----
    float o16[16];
    #pragma unroll
    for (int j = 0; j < 16; j++) o16[j] = sNB2[q * 16 + j];
    #pragma unroll 2
    for (int kk = 0; kk < 16; kk++) {
        const float4 h4 = tile4[ni * 16 + (kk ^ sw)];
        const float hv[4] = {h4.x, h4.y, h4.z, h4.w};
        #pragma unroll
        for (int u = 0; u < 4; u++) {
            const float v = hv[u];
            const float4* w4 = (const float4*)(gNW2 + (kk * 4 + u) * 64 + q * 16);
            #pragma unroll
            for (int j4 = 0; j4 < 4; j4++) {
                const float4 w = w4[j4];
                o16[4 * j4 + 0] += v * w.x; o16[4 * j4 + 1] += v * w.y;
                o16[4 * j4 + 2] += v * w.z; o16[4 * j4 + 3] += v * w.w;
            }
        }
    }
    if (valid) {
        float4* out4 = (float4*)(hh + (size_t)n * 64 + q * 16);
        #pragma unroll
        for (int j4 = 0; j4 < 4; j4++) {
            float4 v; v.x = o16[4 * j4]; v.y = o16[4 * j4 + 1];
            v.z = o16[4 * j4 + 2]; v.w = o16[4 * j4 + 3];
            out4[j4] = v;
        }
    }
}

// ---- host launch -------------------------------------------------------------
extern "C" void kernel_launch(void* const* d_in, const int* in_sizes, int n_in,
                              void* d_out, int out_size, void* d_ws, size_t ws_size,
                              hipStream_t stream) {
    float* wsf = (float*)d_ws;
    int*   wsi = (int*)(wsf + 1340000);
    float* coord = (float*)d_out;          // fp32 coord state lives in d_out
    const int* edges = (const int*)d_in[4];
    const int* rows = edges;
    const int* cols = edges + NE;

    // ---- CSR build (once per call) ----
    hipMemsetAsync(wsi + IOFF_CNTI, 0, NN * sizeof(int), stream);
    counti_kernel<<<(NE + 255) / 256, 256, 0, stream>>>(rows, wsi + IOFF_CNTI);
    scan_kernel<<<1, 1024, 0, stream>>>(wsi + IOFF_CNTI, wsi + IOFF_OFF, wsi + IOFF_CURSOR);
    scatter_kernel<<<(NE + 255) / 256, 256, 0, stream>>>(rows, wsi + IOFF_CURSOR,
                                                         wsi + IOFF_PERM);

    node_init<<<(NN + 255) / 256, 256, 0, stream>>>(
        (const float*)d_in[0], (const float*)d_in[1], (const float*)d_in[2],
        (const int*)d_in[5], (const float*)d_in[8],
        (const float*)d_in[9],  (const float*)d_in[10],
        (const float*)d_in[11], (const float*)d_in[12],
        (const float*)d_in[13], (const float*)d_in[14],
        (const float*)d_in[6],  (const float*)d_in[7],
        coord, wsf + OFF_FIELD, wsf + OFF_HH);

    for (int l = 0; l < NL; l++) {
        hipMemsetAsync(wsf + OFF_CSUM, 0, (30000 + 640000) * sizeof(float), stream);
        edge_kernel<<<NEBLK, 256, 0, stream>>>(
            rows, cols, wsi + IOFF_PERM,
            coord, wsf + OFF_HH, (const float*)d_in[3],
            ((const float*)d_in[15]) + l * 8384, ((const float*)d_in[16]) + l * 64,
            ((const float*)d_in[17]) + l * 4096, ((const float*)d_in[18]) + l * 64,
            ((const float*)d_in[23]) + l * 4096, ((const float*)d_in[24]) + l * 64,
            ((const float*)d_in[25]) + l * 64,
            wsf + OFF_CSUM, wsf + OFF_MAGG);
        node_kernel<<<NNODEBLK, 256, 0, stream>>>(
            ((const float*)d_in[26]) + l * 4096, ((const float*)d_in[27]) + l * 64,
            ((const float*)d_in[28]) + l * 64,   ((const float*)d_in[29]) + l,
            ((const float*)d_in[30]) + l * 4096, ((const float*)d_in[31]) + l * 64,
            ((const float*)d_in[32]) + l * 64,   ((const float*)d_in[33]) + l,
            ((const float*)d_in[19]) + l * 8192, ((const float*)d_in[20]) + l * 64,
            ((const float*)d_in[21]) + l * 4096, ((const float*)d_in[22]) + l * 64,
            wsf + OFF_CSUM, wsi + IOFF_OFF, (const float*)d_in[2],
            wsf + OFF_FIELD, wsf + OFF_MAGG, coord, wsf + OFF_HH);
    }
}

// Round 8
// 1258.368 us; speedup vs baseline: 2.2363x; 1.1383x over previous
//
#include <hip/hip_runtime.h>
#include <hip/hip_bf16.h>

typedef unsigned short ushort_t;
typedef unsigned int uint_t;

#define NN    10000
#define NE    320000
#define NL    4
#define EBLK  64        // edges per block (4 threads per edge)
#define NEBLK 5000      // NE / EBLK exactly
#define NPB   64        // nodes per block in node_kernel (4 threads per node)
#define NNODEBLK 157    // ceil(NN / NPB)

// ---- workspace float offsets -------------------------------------------------
#define OFF_FIELD 0        // 30000
#define OFF_HH    30000    // 640000
#define OFF_CSUM  670000   // 30000  (contiguous with MAGG for one memset)
#define OFF_MAGG  700000   // 640000 -> float end 1340000
// ---- int region (starts at float offset 1340000) ----------------------------
#define IOFF_CNTI   0        // 10000
#define IOFF_OFF    10000    // 10001
#define IOFF_CURSOR 20001    // 10000
#define IOFF_PERM   30001    // 320000 -> int end 350001 (total ws ~6.76 MB)

// fast silu: v_rcp_f32 instead of IEEE divide (~1e-7 rel err, VALU-bound paths)
__device__ __forceinline__ float silu(float x) {
    return x * __builtin_amdgcn_rcpf(1.0f + __expf(-x));
}
// fp32 -> bf16 round-to-nearest-even
__device__ __forceinline__ ushort_t f2bf(float f) {
    union { float f; uint_t u; } v; v.f = f;
    const uint_t r = (v.u + 0x7FFFu + ((v.u >> 16) & 1u)) >> 16;
    return (ushort_t)r;
}
__device__ __forceinline__ void unpack2(uint_t p, float& lo, float& hi) {
    union { uint_t u; float f; } a, b;
    a.u = p << 16; b.u = p & 0xffff0000u;
    lo = a.f; hi = b.f;
}
__device__ __forceinline__ float bfbits(uint_t hi16) {
    union { uint_t u; float f; } a; a.u = hi16; return a.f;
}

// ---- CSR build: per-row int counts ------------------------------------------
__global__ __launch_bounds__(256) void counti_kernel(const int* __restrict__ rows,
                                                     int* __restrict__ cnti) {
    const int e = blockIdx.x * 256 + threadIdx.x;
    if (e < NE) {
        int r = rows[e];
        r = ((uint_t)r < (uint_t)NN) ? r : 0;
        atomicAdd(&cnti[r], 1);
    }
}

// ---- CSR build: exclusive scan over 10000 counts (single block) --------------
__global__ __launch_bounds__(1024) void scan_kernel(const int* __restrict__ cnti,
                                                    int* __restrict__ off,
                                                    int* __restrict__ cursor) {
    __shared__ int part[1024];
    const int t = threadIdx.x;
    const int base = t * 10;
    int loc[10];
    int s = 0;
    #pragma unroll
    for (int i = 0; i < 10; i++) {
        const int idx = base + i;
        const int v = (idx < NN) ? cnti[idx] : 0;
        loc[i] = s; s += v;
    }
    part[t] = s;
    __syncthreads();
    const int own = s;
    for (int d = 1; d < 1024; d <<= 1) {
        const int v = (t >= d) ? part[t - d] : 0;
        __syncthreads();
        part[t] += v;
        __syncthreads();
    }
    const int excl = part[t] - own;
    #pragma unroll
    for (int i = 0; i < 10; i++) {
        const int idx = base + i;
        if (idx < NN) { const int o = excl + loc[i]; off[idx] = o; cursor[idx] = o; }
    }
    if (t == 0) off[NN] = NE;
}

// ---- CSR build: scatter edge ids into row-sorted order -----------------------
__global__ __launch_bounds__(256) void scatter_kernel(const int* __restrict__ rows,
                                                      int* __restrict__ cursor,
                                                      int* __restrict__ perm) {
    const int e = blockIdx.x * 256 + threadIdx.x;
    if (e < NE) {
        int r = rows[e];
        r = ((uint_t)r < (uint_t)NN) ? r : 0;
        const int pos = atomicAdd(&cursor[r], 1);
        if ((uint_t)pos < (uint_t)NE) perm[pos] = e;
    }
}

// ---- field network + node embedding + coord init (once per call) ------------
__global__ __launch_bounds__(256) void node_init(
    const float* __restrict__ hsrc, const float* __restrict__ xsrc,
    const float* __restrict__ vsrc, const int* __restrict__ charges,
    const float* __restrict__ cls,
    const float* __restrict__ fW1, const float* __restrict__ fb1,
    const float* __restrict__ fW2, const float* __restrict__ fb2,
    const float* __restrict__ fW3, const float* __restrict__ fb3,
    const float* __restrict__ embW, const float* __restrict__ embb,
    float* __restrict__ coord, float* __restrict__ field, float* __restrict__ hh)
{
    __shared__ float sFW1[704], sFW2[1024], sFW3[96];
    __shared__ float sFB1[32], sFB2[32], sFB3[3], sCLS[32], sEW[64], sEB[64];
    const int t = threadIdx.x;
    for (int i = t; i < 704; i += 256) sFW1[i] = fW1[i];
    for (int i = t; i < 1024; i += 256) sFW2[i] = fW2[i];
    if (t < 96) sFW3[t] = fW3[t];
    if (t < 32) { sFB1[t] = fb1[t]; sFB2[t] = fb2[t]; sCLS[t] = cls[t]; }
    if (t < 3)  sFB3[t] = fb3[t];
    if (t < 64) { sEW[t] = embW[t]; sEB[t] = embb[t]; }
    __syncthreads();

    const int n = blockIdx.x * 256 + t;
    if (n >= NN) return;

    float fin[22];
    #pragma unroll
    for (int d = 0; d < 3; d++) {
        fin[d]     = xsrc[3 * n + d];
        fin[3 + d] = vsrc[3 * n + d];
        coord[3 * n + d] = fin[d];
    }
    int ci = charges[n];
    ci = ((uint_t)ci < 2u) ? ci : 0;
    const int cix = ci * 16;
    #pragma unroll
    for (int k = 0; k < 16; k++) fin[6 + k] = sCLS[cix + k];

    float h1[32];
    #pragma unroll
    for (int j = 0; j < 32; j++) h1[j] = sFB1[j];
    #pragma unroll
    for (int k = 0; k < 22; k++) {
        const float v = fin[k];
        #pragma unroll
        for (int j = 0; j < 32; j++) h1[j] += v * sFW1[k * 32 + j];
    }
    #pragma unroll
    for (int j = 0; j < 32; j++) h1[j] = silu(h1[j]);

    float h2[32];
    #pragma unroll
    for (int j = 0; j < 32; j++) h2[j] = sFB2[j];
    #pragma unroll
    for (int k = 0; k < 32; k++) {
        const float v = h1[k];
        #pragma unroll
        for (int j = 0; j < 32; j++) h2[j] += v * sFW2[k * 32 + j];
    }
    #pragma unroll
    for (int j = 0; j < 32; j++) h2[j] = silu(h2[j]);

    #pragma unroll
    for (int d = 0; d < 3; d++) {
        float s = sFB3[d];
        #pragma unroll
        for (int j = 0; j < 32; j++) s += h2[j] * sFW3[j * 3 + d];
        field[3 * n + d] = s;
    }

    const float hv = hsrc[n];
    #pragma unroll
    for (int j = 0; j < 64; j++) hh[(size_t)n * 64 + j] = hv * sEW[j] + sEB[j];
}

// ---- per-layer edge kernel: 4 threads per edge, 16 channels per thread -------
// Round-8: segment-shared r-half. Edges are row-sorted, so all edges in a
// segment share hh[r] -> the r-half of the W1 GEMM (1024 FMA + 512 unpack per
// thread) is computed ONCE per (segment, channel) by phase 1a (one 64-MAC dot
// per thread, nseg*64 <= 256 dots typically) into pre[seg][64], which ALIASES
// the sW2 region. sW2's staging is deferred (T14): held in 4 float4 regs from
// kernel start, ds_written after phase-1b when pre dies. LDS stays 43.7 KB ->
// 3 blocks/CU (round-7's proven occupancy).
__global__ __launch_bounds__(256, 3) void edge_kernel(
    const int* __restrict__ rows, const int* __restrict__ cols,
    const int* __restrict__ perm,
    const float* __restrict__ coord, const float* __restrict__ hh,
    const float* __restrict__ eattr,
    const float* __restrict__ gEW1, const float* __restrict__ gEB1,
    const float* __restrict__ gEW2, const float* __restrict__ gEB2,
    const float* __restrict__ gCW1, const float* __restrict__ gCB1,
    const float* __restrict__ gCW2,
    float* __restrict__ csum, float* __restrict__ magg)
{
    // union region A: phase 1 = bf16 W1 (16768 B); phase 2+ = fp32 tile (16384 B)
    __shared__ __align__(16) uint_t uBuf[4192];
    // union region B: phase 1 = pre[64][64] fp32; phase 2+ = fp32 W2
    __shared__ __align__(16) float    sW2[64 * 64];
    __shared__ __align__(16) ushort_t sCW1[64 * 64];   // bf16 coord-MLP W1
    __shared__ float sB1[64], sB2[64], sCB1[64], sCW2v[64];
    __shared__ int   sr[EBLK], sc[EBLK], se[EBLK];
    __shared__ int   sSegId[EBLK];
    __shared__ int   segstart[EBLK + 1];
    __shared__ int   snseg;

    ushort_t* sW1   = (ushort_t*)uBuf;
    float*    tile  = (float*)uBuf;
    float4*   tile4 = (float4*)uBuf;
    float*    pre   = sW2;              // alias: pre lives before W2 is written

    const int t = threadIdx.x;

    // ---- T14 issue-early: W2 global->reg (written to LDS after phase 1b) ----
    const float4 w2a = ((const float4*)gEW2)[t];
    const float4 w2b = ((const float4*)gEW2)[t + 256];
    const float4 w2c = ((const float4*)gEW2)[t + 512];
    const float4 w2d = ((const float4*)gEW2)[t + 768];

    // ---- stage W1 (bf16), cW1 (bf16), biases ----
    for (int i = t; i < 2096; i += 256) {          // 131*64 = 8384 = 2096 float4
        const float4 v = ((const float4*)gEW1)[i];
        sW1[4 * i + 0] = f2bf(v.x); sW1[4 * i + 1] = f2bf(v.y);
        sW1[4 * i + 2] = f2bf(v.z); sW1[4 * i + 3] = f2bf(v.w);
    }
    for (int i = t; i < 1024; i += 256) {          // 64*64 = 4096 = 1024 float4
        const float4 v = ((const float4*)gCW1)[i];
        sCW1[4 * i + 0] = f2bf(v.x); sCW1[4 * i + 1] = f2bf(v.y);
        sCW1[4 * i + 2] = f2bf(v.z); sCW1[4 * i + 3] = f2bf(v.w);
    }
    if (t < 64) { sB1[t] = gEB1[t]; sB2[t] = gEB2[t];
                  sCB1[t] = gCB1[t]; sCW2v[t] = gCW2[t]; }

    // ---- load this block's 64 edges (sorted by row via perm) ----
    if (t < EBLK) {
        int e = perm[blockIdx.x * EBLK + t];
        e = ((uint_t)e < (uint_t)NE) ? e : 0;
        int r = rows[e], c = cols[e];
        r = ((uint_t)r < (uint_t)NN) ? r : 0;
        c = ((uint_t)c < (uint_t)NN) ? c : 0;
        se[t] = e; sr[t] = r; sc[t] = c;
    }
    __syncthreads();

    // ---- segment boundaries over the 64 sorted rows: wave-0 shfl scan ----
    if (t < EBLK) {                     // exactly wave 0 (256-thread block)
        const int flag = (t == 0) ? 1 : ((sr[t] != sr[t - 1]) ? 1 : 0);
        int isc = flag;
        #pragma unroll
        for (int d = 1; d < EBLK; d <<= 1) {
            const int up = __shfl_up(isc, d);
            if (t >= d) isc += up;
        }
        sSegId[t] = isc - 1;
        if (flag) segstart[isc - 1] = t;
        if (t == EBLK - 1) { snseg = isc; segstart[isc] = EBLK; }
    }
    __syncthreads();
    const int nseg = snseg;
    const uint_t* sW1u = (const uint_t*)sW1;

    // ---- phase 1a: pre[seg][ch] = hh[row(seg)] . W1col(ch) over k=0..63 ----
    // one dot per thread (nseg*64 <= 256 typically); conflict-free LDS cols.
    for (int w = t; w < nseg * 64; w += 256) {
        const int seg = w >> 6, ch = w & 63;
        const int row = sr[segstart[seg]];
        const float4* hr4 = (const float4*)(hh + (size_t)row * 64);
        const uint_t* wcol = sW1u + (ch >> 1);
        const int sh = (ch & 1) * 16;
        float s = 0.f;
        #pragma unroll 4
        for (int kk = 0; kk < 16; kk++) {
            const float4 a = hr4[kk];
            const float av[4] = {a.x, a.y, a.z, a.w};
            #pragma unroll
            for (int u = 0; u < 4; u++) {
                const uint_t uw = wcol[(kk * 4 + u) * 32];
                s += av[u] * bfbits((uw >> sh) << 16);
            }
        }
        pre[seg * 64 + ch] = s;
    }
    __syncthreads();   // pre visible to all

    // ---- per-thread edge/chunk identity ----
    const int ei = t >> 2;          // edge in block
    const int q  = t & 3;           // channel chunk (16 ch)
    const int sw = ei & 7;          // tile swizzle key
    const int r = sr[ei], c = sc[ei], e = se[ei];
    const int seg = sSegId[ei];

    const float dx = coord[3 * r + 0] - coord[3 * c + 0];
    const float dy = coord[3 * r + 1] - coord[3 * c + 1];
    const float dz = coord[3 * r + 2] - coord[3 * c + 2];
    const float radial = dx * dx + dy * dy + dz * dz;
    const float2 ea = ((const float2*)eattr)[e];

    const float4* hc4 = (const float4*)(hh + (size_t)c * 64);

    // ---- phase 1b: acc16 = b1 + pre[seg] + hh[c]-half + ext ----
    float acc16[16];
    {
        const float4* pre4 = (const float4*)(pre + seg * 64 + q * 16);
        #pragma unroll
        for (int j4 = 0; j4 < 4; j4++) {
            const float4 p = pre4[j4];
            acc16[4 * j4 + 0] = sB1[q * 16 + 4 * j4 + 0] + p.x;
            acc16[4 * j4 + 1] = sB1[q * 16 + 4 * j4 + 1] + p.y;
            acc16[4 * j4 + 2] = sB1[q * 16 + 4 * j4 + 2] + p.z;
            acc16[4 * j4 + 3] = sB1[q * 16 + 4 * j4 + 3] + p.w;
        }
    }
    #pragma unroll 2
    for (int kk = 0; kk < 16; kk++) {
        const float4 a = hc4[kk];
        const float av[4] = {a.x, a.y, a.z, a.w};
        #pragma unroll
        for (int u = 0; u < 4; u++) {
            const float v = av[u];
            const uint_t* w = sW1u + (64 + kk * 4 + u) * 32 + q * 8;
            #pragma unroll
            for (int jj = 0; jj < 8; jj++) {
                float lo, hi; unpack2(w[jj], lo, hi);
                acc16[2 * jj]     += v * lo;
                acc16[2 * jj + 1] += v * hi;
            }
        }
    }
    {
        const float ext[3] = {radial, ea.x, ea.y};
        #pragma unroll
        for (int x = 0; x < 3; x++) {
            const float v = ext[x];
            const uint_t* w = sW1u + (128 + x) * 32 + q * 8;
            #pragma unroll
            for (int jj = 0; jj < 8; jj++) {
                float lo, hi; unpack2(w[jj], lo, hi);
                acc16[2 * jj]     += v * lo;
                acc16[2 * jj + 1] += v * hi;
            }
        }
    }
    #pragma unroll
    for (int j = 0; j < 16; j++) acc16[j] = silu(acc16[j]);

    __syncthreads();   // ALL sW1 + pre reads complete before both clobbers

    // ---- T14 write-late: W2 reg->LDS (clobbers pre) ----
    ((float4*)sW2)[t]       = w2a;
    ((float4*)sW2)[t + 256] = w2b;
    ((float4*)sW2)[t + 512] = w2c;
    ((float4*)sW2)[t + 768] = w2d;
    // ---- stage hidden to tile (swizzled; clobbers sW1 region) ----
    #pragma unroll
    for (int j = 0; j < 4; j++) {
        float4 v; v.x = acc16[4 * j]; v.y = acc16[4 * j + 1];
        v.z = acc16[4 * j + 2]; v.w = acc16[4 * j + 3];
        tile4[ei * 16 + ((q * 4 + j) ^ sw)] = v;
    }
    __syncthreads();

    // ---- layer 2: m16 = silu(hid64 @ W2[:, q*16..+16] + b2)  (W2 in LDS) ----
    float m16[16];
    #pragma unroll
    for (int j = 0; j < 16; j++) m16[j] = sB2[q * 16 + j];
    #pragma unroll 4
    for (int kk = 0; kk < 16; kk++) {
        const float4 h4 = tile4[ei * 16 + (kk ^ sw)];
        const float hv[4] = {h4.x, h4.y, h4.z, h4.w};
        #pragma unroll
        for (int u = 0; u < 4; u++) {
            const float v = hv[u];
            const float* w = &sW2[(kk * 4 + u) * 64 + q * 16];
            #pragma unroll
            for (int j = 0; j < 16; j++) m16[j] += v * w[j];
        }
    }
    #pragma unroll
    for (int j = 0; j < 16; j++) m16[j] = silu(m16[j]);

    __syncthreads();                 // everyone done reading hid
    #pragma unroll
    for (int j = 0; j < 4; j++) {
        float4 v; v.x = m16[4 * j]; v.y = m16[4 * j + 1];
        v.z = m16[4 * j + 2]; v.w = m16[4 * j + 3];
        tile4[ei * 16 + ((q * 4 + j) ^ sw)] = v;
    }
    __syncthreads();                 // tile now holds m for all edges

    // ---- cw = silu(m @ cW1 + cb1) @ cW2  (cW1 bf16 in LDS) ----
    float ch16[16];
    #pragma unroll
    for (int j = 0; j < 16; j++) ch16[j] = sCB1[q * 16 + j];
    {
        const uint_t* sCW1u = (const uint_t*)sCW1;
        #pragma unroll 4
        for (int kk = 0; kk < 16; kk++) {
            const float4 m4 = tile4[ei * 16 + (kk ^ sw)];
            const float mv[4] = {m4.x, m4.y, m4.z, m4.w};
            #pragma unroll
            for (int u = 0; u < 4; u++) {
                const float v = mv[u];
                const uint_t* w = sCW1u + (kk * 4 + u) * 32 + q * 8;
                #pragma unroll
                for (int jj = 0; jj < 8; jj++) {
                    float lo, hi; unpack2(w[jj], lo, hi);
                    ch16[2 * jj]     += v * lo;
                    ch16[2 * jj + 1] += v * hi;
                }
            }
        }
    }
    float part = 0.f;
    #pragma unroll
    for (int j = 0; j < 16; j++) part += silu(ch16[j]) * sCW2v[q * 16 + j];
    part += __shfl_xor(part, 1);
    part += __shfl_xor(part, 2);
    const float cw = part;

    // ---- segmented reduction: magg (all 64 channels from tile-m) ----
    for (int w = t; w < nseg * 64; w += 256) {
        const int lr2 = w >> 6, cc = w & 63;
        const int p0 = segstart[lr2], p1 = segstart[lr2 + 1];
        float s = 0.f;
        for (int p = p0; p < p1; p++)
            s += tile[p * 64 + ((((cc >> 2) ^ (p & 7)) << 2) | (cc & 3))];
        atomicAdd(&magg[(size_t)sr[p0] * 64 + cc], s);
    }
    __syncthreads();

    // ---- segmented reduction: csum (3 coords; stage in tile[0..255]) ----
    if (q < 3) tile[ei * 4 + q] = (q == 0 ? dx : (q == 1 ? dy : dz)) * cw;
    __syncthreads();
    for (int w = t; w < nseg * 3; w += 256) {
        const int lr2 = w / 3, cc = w - 3 * lr2;
        const int p0 = segstart[lr2], p1 = segstart[lr2 + 1];
        float s = 0.f;
        for (int p = p0; p < p1; p++) s += tile[p * 4 + cc];
        atomicAdd(&csum[3 * sr[p0] + cc], s);
    }
}

// ---- per-layer node kernel: 4 threads per node, 16 channels per thread -------
// (unchanged from round 4 — validated)
__global__ __launch_bounds__(256, 2) void node_kernel(
    const float* __restrict__ gVW1, const float* __restrict__ gVB1,
    const float* __restrict__ gVW2, const float* __restrict__ gVB2,
    const float* __restrict__ gGW1, const float* __restrict__ gGB1,
    const float* __restrict__ gGW2, const float* __restrict__ gGB2,
    const float* __restrict__ gNW1, const float* __restrict__ gNB1,
    const float* __restrict__ gNW2, const float* __restrict__ gNB2,
    const float* __restrict__ csum, const int* __restrict__ off,
    const float* __restrict__ vsrc, const float* __restrict__ field,
    const float* __restrict__ magg,
    float* __restrict__ coord, float* __restrict__ hh)
{
    __shared__ __align__(16) float sNW1[128 * 64];     // 32 KB
    __shared__ __align__(16) float tile[NPB * 64];     // 16 KB exchange
    __shared__ float sNB1[64], sNB2[64];

    const int t = threadIdx.x;
    for (int i = t; i < 2048; i += 256) ((float4*)sNW1)[i] = ((const float4*)gNW1)[i];
    if (t < 64) { sNB1[t] = gNB1[t]; sNB2[t] = gNB2[t]; }
    __syncthreads();

    const int ni = t >> 2;          // node in block
    const int q  = t & 3;           // channel chunk
    const int sw = ni & 7;          // tile swizzle key
    int n = blockIdx.x * NPB + ni;
    const bool valid = (n < NN);
    n = valid ? n : (NN - 1);       // clamp for safe reads; writes predicated

    const float4* hh4 = (const float4*)(hh + (size_t)n * 64);
    const float4* mg4 = (const float4*)(magg + (size_t)n * 64);
    float4* tile4 = (float4*)tile;

    // ---- vw = silu(hh @ vW1 + vb1) @ vW2 + vb2 ----
    float a16[16];
    #pragma unroll
    for (int j = 0; j < 16; j++) a16[j] = gVB1[q * 16 + j];
    #pragma unroll 2
    for (int kk = 0; kk < 16; kk++) {
        const float4 h4 = hh4[kk];
        const float hv[4] = {h4.x, h4.y, h4.z, h4.w};
        #pragma unroll
        for (int u = 0; u < 4; u++) {
            const float v = hv[u];
            const float4* w4 = (const float4*)(gVW1 + (kk * 4 + u) * 64 + q * 16);
            #pragma unroll
            for (int j4 = 0; j4 < 4; j4++) {
                const float4 w = w4[j4];
                a16[4 * j4 + 0] += v * w.x; a16[4 * j4 + 1] += v * w.y;
                a16[4 * j4 + 2] += v * w.z; a16[4 * j4 + 3] += v * w.w;
            }
        }
    }
    float part = 0.f;
    #pragma unroll
    for (int j = 0; j < 16; j++) part += silu(a16[j]) * gVW2[q * 16 + j];
    part += __shfl_xor(part, 1);
    part += __shfl_xor(part, 2);
    const float vw = part + gVB2[0];

    // ---- gw = silu(hh @ gW1 + gb1) @ gW2 + gb2 (reuses a16) ----
    #pragma unroll
    for (int j = 0; j < 16; j++) a16[j] = gGB1[q * 16 + j];
    #pragma unroll 2
    for (int kk = 0; kk < 16; kk++) {
        const float4 h4 = hh4[kk];
        const float hv[4] = {h4.x, h4.y, h4.z, h4.w};
        #pragma unroll
        for (int u = 0; u < 4; u++) {
            const float v = hv[u];
            const float4* w4 = (const float4*)(gGW1 + (kk * 4 + u) * 64 + q * 16);
            #pragma unroll
            for (int j4 = 0; j4 < 4; j4++) {
                const float4 w = w4[j4];
                a16[4 * j4 + 0] += v * w.x; a16[4 * j4 + 1] += v * w.y;
                a16[4 * j4 + 2] += v * w.z; a16[4 * j4 + 3] += v * w.w;
            }
        }
    }
    part = 0.f;
    #pragma unroll
    for (int j = 0; j < 16; j++) part += silu(a16[j]) * gGW2[q * 16 + j];
    part += __shfl_xor(part, 1);
    part += __shfl_xor(part, 2);
    const float gw = part + gGB2[0];

    // ---- coord update (one thread per node) ----
    if (valid && q == 0) {
        const float cn = fmaxf((float)(off[n + 1] - off[n]), 1.0f);
        #pragma unroll
        for (int d = 0; d < 3; d++)
            coord[3 * n + d] += csum[3 * n + d] / cn
                              + vw * vsrc[3 * n + d]
                              + gw * field[3 * n + d];
    }

    // ---- node MLP hidden: a16 = silu([hh, magg] @ NW1[:, q*16..+16] + b1) ----
    #pragma unroll
    for (int j = 0; j < 16; j++) a16[j] = sNB1[q * 16 + j];
    #pragma unroll 2
    for (int kk = 0; kk < 16; kk++) {
        const float4 h4 = hh4[kk];
        const float hv[4] = {h4.x, h4.y, h4.z, h4.w};
        #pragma unroll
        for (int u = 0; u < 4; u++) {
            const float v = hv[u];
            const float* w = &sNW1[(kk * 4 + u) * 64 + q * 16];
            #pragma unroll
            for (int j = 0; j < 16; j++) a16[j] += v * w[j];
        }
    }
    #pragma unroll 2
    for (int kk = 0; kk < 16; kk++) {
        const float4 m4 = mg4[kk];
        const float mv[4] = {m4.x, m4.y, m4.z, m4.w};
        #pragma unroll
        for (int u = 0; u < 4; u++) {
            const float v = mv[u];
            const float* w = &sNW1[(64 + kk * 4 + u) * 64 + q * 16];
            #pragma unroll
            for (int j = 0; j < 16; j++) a16[j] += v * w[j];
        }
    }
    #pragma unroll
    for (int j = 0; j < 16; j++) a16[j] = silu(a16[j]);

    // ---- exchange hidden through swizzled tile ----
    #pragma unroll
    for (int j = 0; j < 4; j++) {
        float4 v; v.x = a16[4 * j]; v.y = a16[4 * j + 1];
        v.z = a16[4 * j + 2]; v.w = a16[4 * j + 3];
        tile4[ni * 16 + ((q * 4 + j) ^ sw)] = v;
    }
    __syncthreads();

    // ---- output: o16 = hid64 @ NW2[:, q*16..+16] + b2 ----
    float o16[16];
    #pragma unroll
    for (int j = 0; j < 16; j++) o16[j] = sNB2[q * 16 + j];
    #pragma unroll 2
    for (int kk = 0; kk < 16; kk++) {
        const float4 h4 = tile4[ni * 16 + (kk ^ sw)];
        const float hv[4] = {h4.x, h4.y, h4.z, h4.w};
        #pragma unroll
        for (int u = 0; u < 4; u++) {
            const float v = hv[u];
            const float4* w4 = (const float4*)(gNW2 + (kk * 4 + u) * 64 + q * 16);
            #pragma unroll
            for (int j4 = 0; j4 < 4; j4++) {
                const float4 w = w4[j4];
                o16[4 * j4 + 0] += v * w.x; o16[4 * j4 + 1] += v * w.y;
                o16[4 * j4 + 2] += v * w.z; o16[4 * j4 + 3] += v * w.w;
            }
        }
    }
    if (valid) {
        float4* out4 = (float4*)(hh + (size_t)n * 64 + q * 16);
        #pragma unroll
        for (int j4 = 0; j4 < 4; j4++) {
            float4 v; v.x = o16[4 * j4]; v.y = o16[4 * j4 + 1];
            v.z = o16[4 * j4 + 2]; v.w = o16[4 * j4 + 3];
            out4[j4] = v;
        }
    }
}

// ---- host launch -------------------------------------------------------------
extern "C" void kernel_launch(void* const* d_in, const int* in_sizes, int n_in,
                              void* d_out, int out_size, void* d_ws, size_t ws_size,
                              hipStream_t stream) {
    float* wsf = (float*)d_ws;
    int*   wsi = (int*)(wsf + 1340000);
    float* coord = (float*)d_out;          // fp32 coord state lives in d_out
    const int* edges = (const int*)d_in[4];
    const int* rows = edges;
    const int* cols = edges + NE;

    // ---- CSR build (once per call) ----
    hipMemsetAsync(wsi + IOFF_CNTI, 0, NN * sizeof(int), stream);
    counti_kernel<<<(NE + 255) / 256, 256, 0, stream>>>(rows, wsi + IOFF_CNTI);
    scan_kernel<<<1, 1024, 0, stream>>>(wsi + IOFF_CNTI, wsi + IOFF_OFF, wsi + IOFF_CURSOR);
    scatter_kernel<<<(NE + 255) / 256, 256, 0, stream>>>(rows, wsi + IOFF_CURSOR,
                                                         wsi + IOFF_PERM);

    node_init<<<(NN + 255) / 256, 256, 0, stream>>>(
        (const float*)d_in[0], (const float*)d_in[1], (const float*)d_in[2],
        (const int*)d_in[5], (const float*)d_in[8],
        (const float*)d_in[9],  (const float*)d_in[10],
        (const float*)d_in[11], (const float*)d_in[12],
        (const float*)d_in[13], (const float*)d_in[14],
        (const float*)d_in[6],  (const float*)d_in[7],
        coord, wsf + OFF_FIELD, wsf + OFF_HH);

    for (int l = 0; l < NL; l++) {
        hipMemsetAsync(wsf + OFF_CSUM, 0, (30000 + 640000) * sizeof(float), stream);
        edge_kernel<<<NEBLK, 256, 0, stream>>>(
            rows, cols, wsi + IOFF_PERM,
            coord, wsf + OFF_HH, (const float*)d_in[3],
            ((const float*)d_in[15]) + l * 8384, ((const float*)d_in[16]) + l * 64,
            ((const float*)d_in[17]) + l * 4096, ((const float*)d_in[18]) + l * 64,
            ((const float*)d_in[23]) + l * 4096, ((const float*)d_in[24]) + l * 64,
            ((const float*)d_in[25]) + l * 64,
            wsf + OFF_CSUM, wsf + OFF_MAGG);
        node_kernel<<<NNODEBLK, 256, 0, stream>>>(
            ((const float*)d_in[26]) + l * 4096, ((const float*)d_in[27]) + l * 64,
            ((const float*)d_in[28]) + l * 64,   ((const float*)d_in[29]) + l,
            ((const float*)d_in[30]) + l * 4096, ((const float*)d_in[31]) + l * 64,
            ((const float*)d_in[32]) + l * 64,   ((const float*)d_in[33]) + l,
            ((const float*)d_in[19]) + l * 8192, ((const float*)d_in[20]) + l * 64,
            ((const float*)d_in[21]) + l * 4096, ((const float*)d_in[22]) + l * 64,
            wsf + OFF_CSUM, wsi + IOFF_OFF, (const float*)d_in[2],
            wsf + OFF_FIELD, wsf + OFF_MAGG, coord, wsf + OFF_HH);
    }
}

// Round 11
// 920.198 us; speedup vs baseline: 3.0582x; 1.3675x over previous
//
#include <hip/hip_runtime.h>
#include <hip/hip_bf16.h>

typedef unsigned short ushort_t;
typedef unsigned int uint_t;

#define NN    10000
#define NE    320000
#define NL    4
#define EBLK  64        // edges per block (4 threads per edge)
#define NEBLK 5000      // NE / EBLK exactly
#define NPB   64        // nodes per block in node_kernel (4 threads per node)
#define NNODEBLK 157    // ceil(NN / NPB)

// ---- workspace float offsets -------------------------------------------------
#define OFF_FIELD 0        // 30000
#define OFF_HH    30000    // 640000
#define OFF_CSUM  670000   // 30000  (contiguous with MAGG for one memset)
#define OFF_MAGG  700000   // 640000 -> float end 1340000
// ---- int region (starts at float offset 1340000) ----------------------------
#define IOFF_CNTI   0        // 10000
#define IOFF_OFF    10000    // 10001
#define IOFF_CURSOR 20001    // 10000
#define IOFF_PERM   30001    // 320000 -> int end 350001 (total ws ~6.76 MB)

// fast silu: v_rcp_f32 instead of IEEE divide (~1e-7 rel err, VALU-bound paths)
__device__ __forceinline__ float silu(float x) {
    return x * __builtin_amdgcn_rcpf(1.0f + __expf(-x));
}

// ---- f16 pair helpers for v_dot2_f32_f16 -------------------------------------
// NOTE: clang's AMDGPU builtins (cvt_pkrtz, fdot2) use __fp16 vectors (V2h),
// NOT _Float16 — round-9 compile failure was this exact mismatch.
typedef __fp16 half2v __attribute__((ext_vector_type(2)));
__device__ __forceinline__ half2v u2h(uint_t u) {
    union { uint_t u; half2v h; } x; x.u = u; return x.h;
}
__device__ __forceinline__ uint_t h2u(half2v h) {
    union { half2v h; uint_t u; } x; x.h = h; return x.u;
}
// (lo = a, hi = b) packed f16 pair, RTZ
__device__ __forceinline__ half2v pkrtz(float a, float b) {
    return __builtin_amdgcn_cvt_pkrtz(a, b);
}
// c += a.lo*w.lo + a.hi*w.hi  — single v_dot2_f32_f16 when available
__device__ __forceinline__ float dot2h(half2v a, uint_t w, float c) {
#if __has_builtin(__builtin_amdgcn_fdot2)
    return __builtin_amdgcn_fdot2(a, u2h(w), c, false);
#else
    union { uint_t u; __fp16 h[2]; } x; x.u = w;
    return c + (float)a.x * (float)x.h[0] + (float)a.y * (float)x.h[1];
#endif
}

// ---- CSR build: per-row int counts ------------------------------------------
__global__ __launch_bounds__(256) void counti_kernel(const int* __restrict__ rows,
                                                     int* __restrict__ cnti) {
    const int e = blockIdx.x * 256 + threadIdx.x;
    if (e < NE) {
        int r = rows[e];
        r = ((uint_t)r < (uint_t)NN) ? r : 0;
        atomicAdd(&cnti[r], 1);
    }
}

// ---- CSR build: exclusive scan over 10000 counts (single block) --------------
__global__ __launch_bounds__(1024) void scan_kernel(const int* __restrict__ cnti,
                                                    int* __restrict__ off,
                                                    int* __restrict__ cursor) {
    __shared__ int part[1024];
    const int t = threadIdx.x;
    const int base = t * 10;
    int loc[10];
    int s = 0;
    #pragma unroll
    for (int i = 0; i < 10; i++) {
        const int idx = base + i;
        const int v = (idx < NN) ? cnti[idx] : 0;
        loc[i] = s; s += v;
    }
    part[t] = s;
    __syncthreads();
    const int own = s;
    for (int d = 1; d < 1024; d <<= 1) {
        const int v = (t >= d) ? part[t - d] : 0;
        __syncthreads();
        part[t] += v;
        __syncthreads();
    }
    const int excl = part[t] - own;
    #pragma unroll
    for (int i = 0; i < 10; i++) {
        const int idx = base + i;
        if (idx < NN) { const int o = excl + loc[i]; off[idx] = o; cursor[idx] = o; }
    }
    if (t == 0) off[NN] = NE;
}

// ---- CSR build: scatter edge ids into row-sorted order -----------------------
__global__ __launch_bounds__(256) void scatter_kernel(const int* __restrict__ rows,
                                                      int* __restrict__ cursor,
                                                      int* __restrict__ perm) {
    const int e = blockIdx.x * 256 + threadIdx.x;
    if (e < NE) {
        int r = rows[e];
        r = ((uint_t)r < (uint_t)NN) ? r : 0;
        const int pos = atomicAdd(&cursor[r], 1);
        if ((uint_t)pos < (uint_t)NE) perm[pos] = e;
    }
}

// ---- field network + node embedding + coord init (once per call) ------------
__global__ __launch_bounds__(256) void node_init(
    const float* __restrict__ hsrc, const float* __restrict__ xsrc,
    const float* __restrict__ vsrc, const int* __restrict__ charges,
    const float* __restrict__ cls,
    const float* __restrict__ fW1, const float* __restrict__ fb1,
    const float* __restrict__ fW2, const float* __restrict__ fb2,
    const float* __restrict__ fW3, const float* __restrict__ fb3,
    const float* __restrict__ embW, const float* __restrict__ embb,
    float* __restrict__ coord, float* __restrict__ field, float* __restrict__ hh)
{
    __shared__ float sFW1[704], sFW2[1024], sFW3[96];
    __shared__ float sFB1[32], sFB2[32], sFB3[3], sCLS[32], sEW[64], sEB[64];
    const int t = threadIdx.x;
    for (int i = t; i < 704; i += 256) sFW1[i] = fW1[i];
    for (int i = t; i < 1024; i += 256) sFW2[i] = fW2[i];
    if (t < 96) sFW3[t] = fW3[t];
    if (t < 32) { sFB1[t] = fb1[t]; sFB2[t] = fb2[t]; sCLS[t] = cls[t]; }
    if (t < 3)  sFB3[t] = fb3[t];
    if (t < 64) { sEW[t] = embW[t]; sEB[t] = embb[t]; }
    __syncthreads();

    const int n = blockIdx.x * 256 + t;
    if (n >= NN) return;

    float fin[22];
    #pragma unroll
    for (int d = 0; d < 3; d++) {
        fin[d]     = xsrc[3 * n + d];
        fin[3 + d] = vsrc[3 * n + d];
        coord[3 * n + d] = fin[d];
    }
    int ci = charges[n];
    ci = ((uint_t)ci < 2u) ? ci : 0;
    const int cix = ci * 16;
    #pragma unroll
    for (int k = 0; k < 16; k++) fin[6 + k] = sCLS[cix + k];

    float h1[32];
    #pragma unroll
    for (int j = 0; j < 32; j++) h1[j] = sFB1[j];
    #pragma unroll
    for (int k = 0; k < 22; k++) {
        const float v = fin[k];
        #pragma unroll
        for (int j = 0; j < 32; j++) h1[j] += v * sFW1[k * 32 + j];
    }
    #pragma unroll
    for (int j = 0; j < 32; j++) h1[j] = silu(h1[j]);

    float h2[32];
    #pragma unroll
    for (int j = 0; j < 32; j++) h2[j] = sFB2[j];
    #pragma unroll
    for (int k = 0; k < 32; k++) {
        const float v = h1[k];
        #pragma unroll
        for (int j = 0; j < 32; j++) h2[j] += v * sFW2[k * 32 + j];
    }
    #pragma unroll
    for (int j = 0; j < 32; j++) h2[j] = silu(h2[j]);

    #pragma unroll
    for (int d = 0; d < 3; d++) {
        float s = sFB3[d];
        #pragma unroll
        for (int j = 0; j < 32; j++) s += h2[j] * sFW3[j * 3 + d];
        field[3 * n + d] = s;
    }

    const float hv = hsrc[n];
    #pragma unroll
    for (int j = 0; j < 64; j++) hh[(size_t)n * 64 + j] = hv * sEW[j] + sEB[j];
}

// ---- per-layer edge kernel: 4 threads per edge, 16 channels per thread -------
// Round-11 (= round-10 resubmit after container flake): all three edge GEMMs
// (W1 c-half, W2, cW1) use f16 k-pair packing + v_dot2_f32_f16:
// (2 unpack ops + 2 FMA) -> 1 dot2 (+1 cvt_pkrtz per 2 acts). f16 weights
// (10 mantissa bits) are MORE precise than the previous bf16 (7).
// Layout: wp[kp][ch] = (w[2kp][ch] lo, w[2kp+1][ch] hi), kp-major, 64 ch/row.
// W2 packed f16 = 8 KB; pre (f16, 8 KB) aliases it with T14 deferred staging
// (W2 held in 2 uint4 regs from kernel start, ds_written after phase 1b).
// LDS: uBuf 16384 (W1p / tile alias) + sW2p 8192 + sCW1p 8192 + sExtW 768
//    + biases 1024 + misc ~1.1 KB ~= 36 KB -> 4 blocks/CU.
__global__ __launch_bounds__(256, 4) void edge_kernel(
    const int* __restrict__ rows, const int* __restrict__ cols,
    const int* __restrict__ perm,
    const float* __restrict__ coord, const float* __restrict__ hh,
    const float* __restrict__ eattr,
    const float* __restrict__ gEW1, const float* __restrict__ gEB1,
    const float* __restrict__ gEW2, const float* __restrict__ gEB2,
    const float* __restrict__ gCW1, const float* __restrict__ gCB1,
    const float* __restrict__ gCW2,
    float* __restrict__ csum, float* __restrict__ magg)
{
    // union A: phase 1 = f16-pair W1 (64 kp x 64 ch = 4096 uint = 16384 B)
    //          phase 2+ = fp32 exchange tile (64*64 = 16384 B)
    __shared__ __align__(16) uint_t uBuf[4096];
    // union B: phase 1 = pre[64][64] f16 (8192 B); phase 2+ = f16-pair W2
    __shared__ __align__(16) uint_t sW2p[2048];
    __shared__ __align__(16) uint_t sCW1p[2048];       // f16-pair cW1 (8192 B)
    __shared__ float sExtW[3 * 64];                    // W1 rows 128..130 fp32
    __shared__ float sB1[64], sB2[64], sCB1[64], sCW2v[64];
    __shared__ int   sr[EBLK], sc[EBLK], se[EBLK];
    __shared__ int   sSegId[EBLK];
    __shared__ int   segstart[EBLK + 1];
    __shared__ int   snseg;

    uint_t*   sW1p  = uBuf;
    float*    tile  = (float*)uBuf;
    float4*   tile4 = (float4*)uBuf;
    ushort_t* preh  = (ushort_t*)sW2p;   // alias: pre lives before W2p staged

    const int t = threadIdx.x;

    // ---- T14 issue-early: W2 global->reg, packed f16 pairs (2 uint4/thread) --
    uint4 w2r0, w2r1;
    {
        const int i0 = t, i1 = t + 256;            // uint4 idx: kp = i>>4, j4 = i&15
        const float4 a0 = ((const float4*)gEW2)[(i0 >> 4) * 32 + (i0 & 15)];
        const float4 b0 = ((const float4*)gEW2)[(i0 >> 4) * 32 + 16 + (i0 & 15)];
        w2r0.x = h2u(pkrtz(a0.x, b0.x)); w2r0.y = h2u(pkrtz(a0.y, b0.y));
        w2r0.z = h2u(pkrtz(a0.z, b0.z)); w2r0.w = h2u(pkrtz(a0.w, b0.w));
        const float4 a1 = ((const float4*)gEW2)[(i1 >> 4) * 32 + (i1 & 15)];
        const float4 b1 = ((const float4*)gEW2)[(i1 >> 4) * 32 + 16 + (i1 & 15)];
        w2r1.x = h2u(pkrtz(a1.x, b1.x)); w2r1.y = h2u(pkrtz(a1.y, b1.y));
        w2r1.z = h2u(pkrtz(a1.z, b1.z)); w2r1.w = h2u(pkrtz(a1.w, b1.w));
    }

    // ---- stage W1 (f16 pairs, k=0..127), ext rows (fp32), cW1 (f16 pairs) ----
    for (int i = t; i < 1024; i += 256) {          // 64 kp x 16 j4-groups
        const int kp = i >> 4, j4 = i & 15;
        const float4 w0 = ((const float4*)gEW1)[kp * 32 + j4];       // row 2kp
        const float4 w1 = ((const float4*)gEW1)[kp * 32 + 16 + j4];  // row 2kp+1
        uint4 u;
        u.x = h2u(pkrtz(w0.x, w1.x)); u.y = h2u(pkrtz(w0.y, w1.y));
        u.z = h2u(pkrtz(w0.z, w1.z)); u.w = h2u(pkrtz(w0.w, w1.w));
        ((uint4*)sW1p)[i] = u;
    }
    if (t < 192) sExtW[t] = gEW1[8192 + t];        // rows 128..130
    for (int i = t; i < 512; i += 256) {           // 32 kp x 16 j4-groups
        const int kp = i >> 4, j4 = i & 15;
        const float4 w0 = ((const float4*)gCW1)[kp * 32 + j4];
        const float4 w1 = ((const float4*)gCW1)[kp * 32 + 16 + j4];
        uint4 u;
        u.x = h2u(pkrtz(w0.x, w1.x)); u.y = h2u(pkrtz(w0.y, w1.y));
        u.z = h2u(pkrtz(w0.z, w1.z)); u.w = h2u(pkrtz(w0.w, w1.w));
        ((uint4*)sCW1p)[i] = u;
    }
    if (t < 64) { sB1[t] = gEB1[t]; sB2[t] = gEB2[t];
                  sCB1[t] = gCB1[t]; sCW2v[t] = gCW2[t]; }

    // ---- load this block's 64 edges (sorted by row via perm) ----
    if (t < EBLK) {
        int e = perm[blockIdx.x * EBLK + t];
        e = ((uint_t)e < (uint_t)NE) ? e : 0;
        int r = rows[e], c = cols[e];
        r = ((uint_t)r < (uint_t)NN) ? r : 0;
        c = ((uint_t)c < (uint_t)NN) ? c : 0;
        se[t] = e; sr[t] = r; sc[t] = c;
    }
    __syncthreads();

    // ---- segment boundaries over the 64 sorted rows: wave-0 shfl scan ----
    if (t < EBLK) {
        const int flag = (t == 0) ? 1 : ((sr[t] != sr[t - 1]) ? 1 : 0);
        int isc = flag;
        #pragma unroll
        for (int d = 1; d < EBLK; d <<= 1) {
            const int up = __shfl_up(isc, d);
            if (t >= d) isc += up;
        }
        sSegId[t] = isc - 1;
        if (flag) segstart[isc - 1] = t;
        if (t == EBLK - 1) { snseg = isc; segstart[isc] = EBLK; }
    }
    __syncthreads();
    const int nseg = snseg;

    // ---- phase 1a: pre[seg][ch] = hh[row(seg)] . W1col(ch), k=0..63 ----
    for (int w = t; w < nseg * 64; w += 256) {
        const int seg = w >> 6, ch = w & 63;
        const int row = sr[segstart[seg]];
        const float4* hr4 = (const float4*)(hh + (size_t)row * 64);
        float s = 0.f;
        #pragma unroll 4
        for (int kk = 0; kk < 16; kk++) {
            const float4 a = hr4[kk];
            const half2v p0 = pkrtz(a.x, a.y);
            const half2v p1 = pkrtz(a.z, a.w);
            s = dot2h(p0, sW1p[(2 * kk) * 64 + ch], s);
            s = dot2h(p1, sW1p[(2 * kk + 1) * 64 + ch], s);
        }
        union { __fp16 h; ushort_t u; } cvt; cvt.h = (__fp16)s;
        preh[seg * 64 + ch] = cvt.u;
    }
    __syncthreads();   // pre visible to all

    // ---- per-thread edge/chunk identity ----
    const int ei = t >> 2;          // edge in block
    const int q  = t & 3;           // channel chunk (16 ch)
    const int sw = ei & 7;          // tile swizzle key
    const int r = sr[ei], c = sc[ei], e = se[ei];
    const int seg = sSegId[ei];

    const float dx = coord[3 * r + 0] - coord[3 * c + 0];
    const float dy = coord[3 * r + 1] - coord[3 * c + 1];
    const float dz = coord[3 * r + 2] - coord[3 * c + 2];
    const float radial = dx * dx + dy * dy + dz * dz;
    const float2 ea = ((const float2*)eattr)[e];

    const float4* hc4 = (const float4*)(hh + (size_t)c * 64);

    // ---- phase 1b: acc16 = b1 + pre(f16) + hh[c]-half(dot2) + ext(fp32) ----
    float acc16[16];
    #pragma unroll
    for (int j = 0; j < 16; j++) {
        union { ushort_t u; __fp16 h; } cvt; cvt.u = preh[seg * 64 + q * 16 + j];
        acc16[j] = sB1[q * 16 + j] + (float)cvt.h;
    }
    #pragma unroll 2
    for (int kk = 0; kk < 16; kk++) {
        const float4 a = hc4[kk];
        const half2v p0 = pkrtz(a.x, a.y);
        const half2v p1 = pkrtz(a.z, a.w);
        const uint_t* wr0 = &sW1p[(32 + 2 * kk) * 64 + q * 16];
        const uint_t* wr1 = wr0 + 64;
        #pragma unroll
        for (int j = 0; j < 16; j++) {
            acc16[j] = dot2h(p0, wr0[j], acc16[j]);
            acc16[j] = dot2h(p1, wr1[j], acc16[j]);
        }
    }
    {
        const float ext3[3] = {radial, ea.x, ea.y};
        #pragma unroll
        for (int x = 0; x < 3; x++) {
            const float v = ext3[x];
            const float* w = &sExtW[x * 64 + q * 16];
            #pragma unroll
            for (int j = 0; j < 16; j++) acc16[j] += v * w[j];
        }
    }
    #pragma unroll
    for (int j = 0; j < 16; j++) acc16[j] = silu(acc16[j]);

    __syncthreads();   // ALL sW1p + preh reads complete before both clobbers

    // ---- T14 write-late: W2p reg->LDS (clobbers preh) ----
    ((uint4*)sW2p)[t]       = w2r0;
    ((uint4*)sW2p)[t + 256] = w2r1;
    // ---- stage hidden to tile (swizzled; clobbers sW1p region) ----
    #pragma unroll
    for (int j = 0; j < 4; j++) {
        float4 v; v.x = acc16[4 * j]; v.y = acc16[4 * j + 1];
        v.z = acc16[4 * j + 2]; v.w = acc16[4 * j + 3];
        tile4[ei * 16 + ((q * 4 + j) ^ sw)] = v;
    }
    __syncthreads();

    // ---- layer 2: m16 = silu(hid64 @ W2[:, q*16..+16] + b2), f16 dot2 ----
    float m16[16];
    #pragma unroll
    for (int j = 0; j < 16; j++) m16[j] = sB2[q * 16 + j];
    #pragma unroll 4
    for (int kk = 0; kk < 16; kk++) {
        const float4 h4 = tile4[ei * 16 + (kk ^ sw)];
        const half2v p0 = pkrtz(h4.x, h4.y);
        const half2v p1 = pkrtz(h4.z, h4.w);
        const uint_t* wr0 = &sW2p[(2 * kk) * 64 + q * 16];
        const uint_t* wr1 = wr0 + 64;
        #pragma unroll
        for (int j = 0; j < 16; j++) {
            m16[j] = dot2h(p0, wr0[j], m16[j]);
            m16[j] = dot2h(p1, wr1[j], m16[j]);
        }
    }
    #pragma unroll
    for (int j = 0; j < 16; j++) m16[j] = silu(m16[j]);

    __syncthreads();                 // everyone done reading hid
    #pragma unroll
    for (int j = 0; j < 4; j++) {
        float4 v; v.x = m16[4 * j]; v.y = m16[4 * j + 1];
        v.z = m16[4 * j + 2]; v.w = m16[4 * j + 3];
        tile4[ei * 16 + ((q * 4 + j) ^ sw)] = v;
    }
    __syncthreads();                 // tile now holds m for all edges

    // ---- cw = silu(m @ cW1 + cb1) @ cW2, f16 dot2 ----
    float ch16[16];
    #pragma unroll
    for (int j = 0; j < 16; j++) ch16[j] = sCB1[q * 16 + j];
    #pragma unroll 4
    for (int kk = 0; kk < 16; kk++) {
        const float4 m4 = tile4[ei * 16 + (kk ^ sw)];
        const half2v p0 = pkrtz(m4.x, m4.y);
        const half2v p1 = pkrtz(m4.z, m4.w);
        const uint_t* wr0 = &sCW1p[(2 * kk) * 64 + q * 16];
        const uint_t* wr1 = wr0 + 64;
        #pragma unroll
        for (int j = 0; j < 16; j++) {
            ch16[j] = dot2h(p0, wr0[j], ch16[j]);
            ch16[j] = dot2h(p1, wr1[j], ch16[j]);
        }
    }
    float part = 0.f;
    #pragma unroll
    for (int j = 0; j < 16; j++) part += silu(ch16[j]) * sCW2v[q * 16 + j];
    part += __shfl_xor(part, 1);
    part += __shfl_xor(part, 2);
    const float cw = part;

    // ---- segmented reduction: magg (all 64 channels from tile-m) ----
    for (int w = t; w < nseg * 64; w += 256) {
        const int lr2 = w >> 6, cc = w & 63;
        const int p0 = segstart[lr2], p1 = segstart[lr2 + 1];
        float s = 0.f;
        for (int p = p0; p < p1; p++)
            s += tile[p * 64 + ((((cc >> 2) ^ (p & 7)) << 2) | (cc & 3))];
        atomicAdd(&magg[(size_t)sr[p0] * 64 + cc], s);
    }
    __syncthreads();

    // ---- segmented reduction: csum (3 coords; stage in tile[0..255]) ----
    if (q < 3) tile[ei * 4 + q] = (q == 0 ? dx : (q == 1 ? dy : dz)) * cw;
    __syncthreads();
    for (int w = t; w < nseg * 3; w += 256) {
        const int lr2 = w / 3, cc = w - 3 * lr2;
        const int p0 = segstart[lr2], p1 = segstart[lr2 + 1];
        float s = 0.f;
        for (int p = p0; p < p1; p++) s += tile[p * 4 + cc];
        atomicAdd(&csum[3 * sr[p0] + cc], s);
    }
}

// ---- per-layer node kernel: 4 threads per node, 16 channels per thread -------
// (unchanged from round 4 — validated)
__global__ __launch_bounds__(256, 2) void node_kernel(
    const float* __restrict__ gVW1, const float* __restrict__ gVB1,
    const float* __restrict__ gVW2, const float* __restrict__ gVB2,
    const float* __restrict__ gGW1, const float* __restrict__ gGB1,
    const float* __restrict__ gGW2, const float* __restrict__ gGB2,
    const float* __restrict__ gNW1, const float* __restrict__ gNB1,
    const float* __restrict__ gNW2, const float* __restrict__ gNB2,
    const float* __restrict__ csum, const int* __restrict__ off,
    const float* __restrict__ vsrc, const float* __restrict__ field,
    const float* __restrict__ magg,
    float* __restrict__ coord, float* __restrict__ hh)
{
    __shared__ __align__(16) float sNW1[128 * 64];     // 32 KB
    __shared__ __align__(16) float tile[NPB * 64];     // 16 KB exchange
    __shared__ float sNB1[64], sNB2[64];

    const int t = threadIdx.x;
    for (int i = t; i < 2048; i += 256) ((float4*)sNW1)[i] = ((const float4*)gNW1)[i];
    if (t < 64) { sNB1[t] = gNB1[t]; sNB2[t] = gNB2[t]; }
    __syncthreads();

    const int ni = t >> 2;          // node in block
    const int q  = t & 3;           // channel chunk
    const int sw = ni & 7;          // tile swizzle key
    int n = blockIdx.x * NPB + ni;
    const bool valid = (n < NN);
    n = valid ? n : (NN - 1);       // clamp for safe reads; writes predicated

    const float4* hh4 = (const float4*)(hh + (size_t)n * 64);
    const float4* mg4 = (const float4*)(magg + (size_t)n * 64);
    float4* tile4 = (float4*)tile;

    // ---- vw = silu(hh @ vW1 + vb1) @ vW2 + vb2 ----
    float a16[16];
    #pragma unroll
    for (int j = 0; j < 16; j++) a16[j] = gVB1[q * 16 + j];
    #pragma unroll 2
    for (int kk = 0; kk < 16; kk++) {
        const float4 h4 = hh4[kk];
        const float hv[4] = {h4.x, h4.y, h4.z, h4.w};
        #pragma unroll
        for (int u = 0; u < 4; u++) {
            const float v = hv[u];
            const float4* w4 = (const float4*)(gVW1 + (kk * 4 + u) * 64 + q * 16);
            #pragma unroll
            for (int j4 = 0; j4 < 4; j4++) {
                const float4 w = w4[j4];
                a16[4 * j4 + 0] += v * w.x; a16[4 * j4 + 1] += v * w.y;
                a16[4 * j4 + 2] += v * w.z; a16[4 * j4 + 3] += v * w.w;
            }
        }
    }
    float part = 0.f;
    #pragma unroll
    for (int j = 0; j < 16; j++) part += silu(a16[j]) * gVW2[q * 16 + j];
    part += __shfl_xor(part, 1);
    part += __shfl_xor(part, 2);
    const float vw = part + gVB2[0];

    // ---- gw = silu(hh @ gW1 + gb1) @ gW2 + gb2 (reuses a16) ----
    #pragma unroll
    for (int j = 0; j < 16; j++) a16[j] = gGB1[q * 16 + j];
    #pragma unroll 2
    for (int kk = 0; kk < 16; kk++) {
        const float4 h4 = hh4[kk];
        const float hv[4] = {h4.x, h4.y, h4.z, h4.w};
        #pragma unroll
        for (int u = 0; u < 4; u++) {
            const float v = hv[u];
            const float4* w4 = (const float4*)(gGW1 + (kk * 4 + u) * 64 + q * 16);
            #pragma unroll
            for (int j4 = 0; j4 < 4; j4++) {
                const float4 w = w4[j4];
                a16[4 * j4 + 0] += v * w.x; a16[4 * j4 + 1] += v * w.y;
                a16[4 * j4 + 2] += v * w.z; a16[4 * j4 + 3] += v * w.w;
            }
        }
    }
    part = 0.f;
    #pragma unroll
    for (int j = 0; j < 16; j++) part += silu(a16[j]) * gGW2[q * 16 + j];
    part += __shfl_xor(part, 1);
    part += __shfl_xor(part, 2);
    const float gw = part + gGB2[0];

    // ---- coord update (one thread per node) ----
    if (valid && q == 0) {
        const float cn = fmaxf((float)(off[n + 1] - off[n]), 1.0f);
        #pragma unroll
        for (int d = 0; d < 3; d++)
            coord[3 * n + d] += csum[3 * n + d] / cn
                              + vw * vsrc[3 * n + d]
                              + gw * field[3 * n + d];
    }

    // ---- node MLP hidden: a16 = silu([hh, magg] @ NW1[:, q*16..+16] + b1) ----
    #pragma unroll
    for (int j = 0; j < 16; j++) a16[j] = sNB1[q * 16 + j];
    #pragma unroll 2
    for (int kk = 0; kk < 16; kk++) {
        const float4 h4 = hh4[kk];
        const float hv[4] = {h4.x, h4.y, h4.z, h4.w};
        #pragma unroll
        for (int u = 0; u < 4; u++) {
            const float v = hv[u];
            const float* w = &sNW1[(kk * 4 + u) * 64 + q * 16];
            #pragma unroll
            for (int j = 0; j < 16; j++) a16[j] += v * w[j];
        }
    }
    #pragma unroll 2
    for (int kk = 0; kk < 16; kk++) {
        const float4 m4 = mg4[kk];
        const float mv[4] = {m4.x, m4.y, m4.z, m4.w};
        #pragma unroll
        for (int u = 0; u < 4; u++) {
            const float v = mv[u];
            const float* w = &sNW1[(64 + kk * 4 + u) * 64 + q * 16];
            #pragma unroll
            for (int j = 0; j < 16; j++) a16[j] += v * w[j];
        }
    }
    #pragma unroll
    for (int j = 0; j < 16; j++) a16[j] = silu(a16[j]);

    // ---- exchange hidden through swizzled tile ----
    #pragma unroll
    for (int j = 0; j < 4; j++) {
        float4 v; v.x = a16[4 * j]; v.y = a16[4 * j + 1];
        v.z = a16[4 * j + 2]; v.w = a16[4 * j + 3];
        tile4[ni * 16 + ((q * 4 + j) ^ sw)] = v;
    }
    __syncthreads();

    // ---- output: o16 = hid64 @ NW2[:, q*16..+16] + b2 ----
    float o16[16];
    #pragma unroll
    for (int j = 0; j < 16; j++) o16[j] = sNB2[q * 16 + j];
    #pragma unroll 2
    for (int kk = 0; kk < 16; kk++) {
        const float4 h4 = tile4[ni * 16 + (kk ^ sw)];
        const float hv[4] = {h4.x, h4.y, h4.z, h4.w};
        #pragma unroll
        for (int u = 0; u < 4; u++) {
            const float v = hv[u];
            const float4* w4 = (const float4*)(gNW2 + (kk * 4 + u) * 64 + q * 16);
            #pragma unroll
            for (int j4 = 0; j4 < 4; j4++) {
                const float4 w = w4[j4];
                o16[4 * j4 + 0] += v * w.x; o16[4 * j4 + 1] += v * w.y;
                o16[4 * j4 + 2] += v * w.z; o16[4 * j4 + 3] += v * w.w;
            }
        }
    }
    if (valid) {
        float4* out4 = (float4*)(hh + (size_t)n * 64 + q * 16);
        #pragma unroll
        for (int j4 = 0; j4 < 4; j4++) {
            float4 v; v.x = o16[4 * j4]; v.y = o16[4 * j4 + 1];
            v.z = o16[4 * j4 + 2]; v.w = o16[4 * j4 + 3];
            out4[j4] = v;
        }
    }
}

// ---- host launch -------------------------------------------------------------
extern "C" void kernel_launch(void* const* d_in, const int* in_sizes, int n_in,
                              void* d_out, int out_size, void* d_ws, size_t ws_size,
                              hipStream_t stream) {
    float* wsf = (float*)d_ws;
    int*   wsi = (int*)(wsf + 1340000);
    float* coord = (float*)d_out;          // fp32 coord state lives in d_out
    const int* edges = (const int*)d_in[4];
    const int* rows = edges;
    const int* cols = edges + NE;

    // ---- CSR build (once per call) ----
    hipMemsetAsync(wsi + IOFF_CNTI, 0, NN * sizeof(int), stream);
    counti_kernel<<<(NE + 255) / 256, 256, 0, stream>>>(rows, wsi + IOFF_CNTI);
    scan_kernel<<<1, 1024, 0, stream>>>(wsi + IOFF_CNTI, wsi + IOFF_OFF, wsi + IOFF_CURSOR);
    scatter_kernel<<<(NE + 255) / 256, 256, 0, stream>>>(rows, wsi + IOFF_CURSOR,
                                                         wsi + IOFF_PERM);

    node_init<<<(NN + 255) / 256, 256, 0, stream>>>(
        (const float*)d_in[0], (const float*)d_in[1], (const float*)d_in[2],
        (const int*)d_in[5], (const float*)d_in[8],
        (const float*)d_in[9],  (const float*)d_in[10],
        (const float*)d_in[11], (const float*)d_in[12],
        (const float*)d_in[13], (const float*)d_in[14],
        (const float*)d_in[6],  (const float*)d_in[7],
        coord, wsf + OFF_FIELD, wsf + OFF_HH);

    for (int l = 0; l < NL; l++) {
        hipMemsetAsync(wsf + OFF_CSUM, 0, (30000 + 640000) * sizeof(float), stream);
        edge_kernel<<<NEBLK, 256, 0, stream>>>(
            rows, cols, wsi + IOFF_PERM,
            coord, wsf + OFF_HH, (const float*)d_in[3],
            ((const float*)d_in[15]) + l * 8384, ((const float*)d_in[16]) + l * 64,
            ((const float*)d_in[17]) + l * 4096, ((const float*)d_in[18]) + l * 64,
            ((const float*)d_in[23]) + l * 4096, ((const float*)d_in[24]) + l * 64,
            ((const float*)d_in[25]) + l * 64,
            wsf + OFF_CSUM, wsf + OFF_MAGG);
        node_kernel<<<NNODEBLK, 256, 0, stream>>>(
            ((const float*)d_in[26]) + l * 4096, ((const float*)d_in[27]) + l * 64,
            ((const float*)d_in[28]) + l * 64,   ((const float*)d_in[29]) + l,
            ((const float*)d_in[30]) + l * 4096, ((const float*)d_in[31]) + l * 64,
            ((const float*)d_in[32]) + l * 64,   ((const float*)d_in[33]) + l,
            ((const float*)d_in[19]) + l * 8192, ((const float*)d_in[20]) + l * 64,
            ((const float*)d_in[21]) + l * 4096, ((const float*)d_in[22]) + l * 64,
            wsf + OFF_CSUM, wsi + IOFF_OFF, (const float*)d_in[2],
            wsf + OFF_FIELD, wsf + OFF_MAGG, coord, wsf + OFF_HH);
    }
}

// Round 12
// 817.619 us; speedup vs baseline: 3.4419x; 1.1255x over previous
//
#include <hip/hip_runtime.h>
#include <hip/hip_bf16.h>

typedef unsigned short ushort_t;
typedef unsigned int uint_t;

#define NN    10000
#define NE    320000
#define NL    4
#define EBLK  64        // edges per block (4 threads per edge)
#define NEBLK 5000      // NE / EBLK exactly
#define NPB   64        // nodes per block (4 threads per node)
#define NNODEBLK 157    // ceil(NN / NPB)

// ---- workspace float offsets -------------------------------------------------
#define OFF_FIELD 0        // 30000
#define OFF_HH    30000    // 640000
#define OFF_CSUM  670000   // 30000  (contiguous with MAGG for one memset)
#define OFF_MAGG  700000   // 640000 -> float end 1340000
// ---- int region (starts at float offset 1340000) ----------------------------
#define IOFF_CNTI   0        // 10000
#define IOFF_OFF    10000    // 10001
#define IOFF_CURSOR 20001    // 10000
#define IOFF_PERM   30001    // 320000
#define IOFF_PRER   350004   // 320000 uints (f16-pair preR; 16B-aligned)
#define IOFF_PREC   670004   // 320000 uints -> int end 990004
// total ws = (1340000 + 990004) * 4 = 9,320,016 B  (REQUIRES ws_size >= 9.4 MB)

// fast silu: v_rcp_f32 instead of IEEE divide (~1e-7 rel err, VALU-bound paths)
__device__ __forceinline__ float silu(float x) {
    return x * __builtin_amdgcn_rcpf(1.0f + __expf(-x));
}

// ---- f16 pair helpers for v_dot2_f32_f16 (clang builtins use __fp16 V2h) -----
typedef __fp16 half2v __attribute__((ext_vector_type(2)));
__device__ __forceinline__ half2v u2h(uint_t u) {
    union { uint_t u; half2v h; } x; x.u = u; return x.h;
}
__device__ __forceinline__ uint_t h2u(half2v h) {
    union { half2v h; uint_t u; } x; x.h = h; return x.u;
}
__device__ __forceinline__ half2v pkrtz(float a, float b) {
    return __builtin_amdgcn_cvt_pkrtz(a, b);
}
__device__ __forceinline__ float dot2h(half2v a, uint_t w, float c) {
#if __has_builtin(__builtin_amdgcn_fdot2)
    return __builtin_amdgcn_fdot2(a, u2h(w), c, false);
#else
    union { uint_t u; __fp16 h[2]; } x; x.u = w;
    return c + (float)a.x * (float)x.h[0] + (float)a.y * (float)x.h[1];
#endif
}

// ---- CSR build: per-row int counts ------------------------------------------
__global__ __launch_bounds__(256) void counti_kernel(const int* __restrict__ rows,
                                                     int* __restrict__ cnti) {
    const int e = blockIdx.x * 256 + threadIdx.x;
    if (e < NE) {
        int r = rows[e];
        r = ((uint_t)r < (uint_t)NN) ? r : 0;
        atomicAdd(&cnti[r], 1);
    }
}

// ---- CSR build: exclusive scan over 10000 counts (single block) --------------
__global__ __launch_bounds__(1024) void scan_kernel(const int* __restrict__ cnti,
                                                    int* __restrict__ off,
                                                    int* __restrict__ cursor) {
    __shared__ int part[1024];
    const int t = threadIdx.x;
    const int base = t * 10;
    int loc[10];
    int s = 0;
    #pragma unroll
    for (int i = 0; i < 10; i++) {
        const int idx = base + i;
        const int v = (idx < NN) ? cnti[idx] : 0;
        loc[i] = s; s += v;
    }
    part[t] = s;
    __syncthreads();
    const int own = s;
    for (int d = 1; d < 1024; d <<= 1) {
        const int v = (t >= d) ? part[t - d] : 0;
        __syncthreads();
        part[t] += v;
        __syncthreads();
    }
    const int excl = part[t] - own;
    #pragma unroll
    for (int i = 0; i < 10; i++) {
        const int idx = base + i;
        if (idx < NN) { const int o = excl + loc[i]; off[idx] = o; cursor[idx] = o; }
    }
    if (t == 0) off[NN] = NE;
}

// ---- CSR build: scatter edge ids into row-sorted order -----------------------
__global__ __launch_bounds__(256) void scatter_kernel(const int* __restrict__ rows,
                                                      int* __restrict__ cursor,
                                                      int* __restrict__ perm) {
    const int e = blockIdx.x * 256 + threadIdx.x;
    if (e < NE) {
        int r = rows[e];
        r = ((uint_t)r < (uint_t)NN) ? r : 0;
        const int pos = atomicAdd(&cursor[r], 1);
        if ((uint_t)pos < (uint_t)NE) perm[pos] = e;
    }
}

// ---- field network + node embedding + coord init (once per call) ------------
__global__ __launch_bounds__(256) void node_init(
    const float* __restrict__ hsrc, const float* __restrict__ xsrc,
    const float* __restrict__ vsrc, const int* __restrict__ charges,
    const float* __restrict__ cls,
    const float* __restrict__ fW1, const float* __restrict__ fb1,
    const float* __restrict__ fW2, const float* __restrict__ fb2,
    const float* __restrict__ fW3, const float* __restrict__ fb3,
    const float* __restrict__ embW, const float* __restrict__ embb,
    float* __restrict__ coord, float* __restrict__ field, float* __restrict__ hh)
{
    __shared__ float sFW1[704], sFW2[1024], sFW3[96];
    __shared__ float sFB1[32], sFB2[32], sFB3[3], sCLS[32], sEW[64], sEB[64];
    const int t = threadIdx.x;
    for (int i = t; i < 704; i += 256) sFW1[i] = fW1[i];
    for (int i = t; i < 1024; i += 256) sFW2[i] = fW2[i];
    if (t < 96) sFW3[t] = fW3[t];
    if (t < 32) { sFB1[t] = fb1[t]; sFB2[t] = fb2[t]; sCLS[t] = cls[t]; }
    if (t < 3)  sFB3[t] = fb3[t];
    if (t < 64) { sEW[t] = embW[t]; sEB[t] = embb[t]; }
    __syncthreads();

    const int n = blockIdx.x * 256 + t;
    if (n >= NN) return;

    float fin[22];
    #pragma unroll
    for (int d = 0; d < 3; d++) {
        fin[d]     = xsrc[3 * n + d];
        fin[3 + d] = vsrc[3 * n + d];
        coord[3 * n + d] = fin[d];
    }
    int ci = charges[n];
    ci = ((uint_t)ci < 2u) ? ci : 0;
    const int cix = ci * 16;
    #pragma unroll
    for (int k = 0; k < 16; k++) fin[6 + k] = sCLS[cix + k];

    float h1[32];
    #pragma unroll
    for (int j = 0; j < 32; j++) h1[j] = sFB1[j];
    #pragma unroll
    for (int k = 0; k < 22; k++) {
        const float v = fin[k];
        #pragma unroll
        for (int j = 0; j < 32; j++) h1[j] += v * sFW1[k * 32 + j];
    }
    #pragma unroll
    for (int j = 0; j < 32; j++) h1[j] = silu(h1[j]);

    float h2[32];
    #pragma unroll
    for (int j = 0; j < 32; j++) h2[j] = sFB2[j];
    #pragma unroll
    for (int k = 0; k < 32; k++) {
        const float v = h1[k];
        #pragma unroll
        for (int j = 0; j < 32; j++) h2[j] += v * sFW2[k * 32 + j];
    }
    #pragma unroll
    for (int j = 0; j < 32; j++) h2[j] = silu(h2[j]);

    #pragma unroll
    for (int d = 0; d < 3; d++) {
        float s = sFB3[d];
        #pragma unroll
        for (int j = 0; j < 32; j++) s += h2[j] * sFW3[j * 3 + d];
        field[3 * n + d] = s;
    }

    const float hv = hsrc[n];
    #pragma unroll
    for (int j = 0; j < 64; j++) hh[(size_t)n * 64 + j] = hv * sEW[j] + sEB[j];
}

// ---- per-layer pre kernel: preR[n] = b1 + W1r.hh[n], preC[n] = W1c.hh[n] -----
// The W1 GEMM is per-NODE work (both halves depend only on the endpoint node);
// computing it once per node instead of once per edge removes ~650 VALU ops
// per edge-thread (avg degree 32 => 32x redundancy). Outputs f16-pair packed.
__global__ __launch_bounds__(256, 4) void pre_kernel(
    const float* __restrict__ hh,
    const float* __restrict__ gEW1, const float* __restrict__ gEB1,
    uint_t* __restrict__ preR, uint_t* __restrict__ preC)
{
    __shared__ __align__(16) uint_t sW1p[4096];   // rows 0..127 f16-paired, 16 KB
    __shared__ float sB1[64];
    const int t = threadIdx.x;
    for (int i = t; i < 1024; i += 256) {          // 64 kp x 16 j4-groups
        const int kp = i >> 4, j4 = i & 15;
        const float4 w0 = ((const float4*)gEW1)[kp * 32 + j4];
        const float4 w1 = ((const float4*)gEW1)[kp * 32 + 16 + j4];
        uint4 u;
        u.x = h2u(pkrtz(w0.x, w1.x)); u.y = h2u(pkrtz(w0.y, w1.y));
        u.z = h2u(pkrtz(w0.z, w1.z)); u.w = h2u(pkrtz(w0.w, w1.w));
        ((uint4*)sW1p)[i] = u;
    }
    if (t < 64) sB1[t] = gEB1[t];
    __syncthreads();

    const int ni = t >> 2, q = t & 3;
    int n = blockIdx.x * NPB + ni;
    const bool valid = (n < NN);
    n = valid ? n : (NN - 1);
    const float4* h4p = (const float4*)(hh + (size_t)n * 64);

    // preR: W1 rows 0..63 (kp 0..31), bias folded
    float acc[16];
    #pragma unroll
    for (int j = 0; j < 16; j++) acc[j] = sB1[q * 16 + j];
    #pragma unroll
    for (int kk = 0; kk < 16; kk++) {
        const float4 a = h4p[kk];
        const half2v p0 = pkrtz(a.x, a.y);
        const half2v p1 = pkrtz(a.z, a.w);
        const uint_t* w0 = &sW1p[(2 * kk) * 64 + q * 16];
        const uint_t* w1 = w0 + 64;
        #pragma unroll
        for (int j = 0; j < 16; j++) {
            acc[j] = dot2h(p0, w0[j], acc[j]);
            acc[j] = dot2h(p1, w1[j], acc[j]);
        }
    }
    if (valid) {
        uint4 o0, o1;
        o0.x = h2u(pkrtz(acc[0],  acc[1]));  o0.y = h2u(pkrtz(acc[2],  acc[3]));
        o0.z = h2u(pkrtz(acc[4],  acc[5]));  o0.w = h2u(pkrtz(acc[6],  acc[7]));
        o1.x = h2u(pkrtz(acc[8],  acc[9]));  o1.y = h2u(pkrtz(acc[10], acc[11]));
        o1.z = h2u(pkrtz(acc[12], acc[13])); o1.w = h2u(pkrtz(acc[14], acc[15]));
        uint4* dst = (uint4*)(preR + (size_t)n * 32 + q * 8);
        dst[0] = o0; dst[1] = o1;
    }

    // preC: W1 rows 64..127 (kp 32..63), no bias
    #pragma unroll
    for (int j = 0; j < 16; j++) acc[j] = 0.f;
    #pragma unroll
    for (int kk = 0; kk < 16; kk++) {
        const float4 a = h4p[kk];
        const half2v p0 = pkrtz(a.x, a.y);
        const half2v p1 = pkrtz(a.z, a.w);
        const uint_t* w0 = &sW1p[(32 + 2 * kk) * 64 + q * 16];
        const uint_t* w1 = w0 + 64;
        #pragma unroll
        for (int j = 0; j < 16; j++) {
            acc[j] = dot2h(p0, w0[j], acc[j]);
            acc[j] = dot2h(p1, w1[j], acc[j]);
        }
    }
    if (valid) {
        uint4 o0, o1;
        o0.x = h2u(pkrtz(acc[0],  acc[1]));  o0.y = h2u(pkrtz(acc[2],  acc[3]));
        o0.z = h2u(pkrtz(acc[4],  acc[5]));  o0.w = h2u(pkrtz(acc[6],  acc[7]));
        o1.x = h2u(pkrtz(acc[8],  acc[9]));  o1.y = h2u(pkrtz(acc[10], acc[11]));
        o1.z = h2u(pkrtz(acc[12], acc[13])); o1.w = h2u(pkrtz(acc[14], acc[15]));
        uint4* dst = (uint4*)(preC + (size_t)n * 32 + q * 8);
        dst[0] = o0; dst[1] = o1;
    }
}

// ---- per-layer edge kernel: 4 threads per edge, 16 channels per thread -------
// Round-12: W1 phases replaced by preR/preC gathers (see pre_kernel); W1p no
// longer staged -> activation tile stored as f16 pairs (8 KB, kp^(ei&31)
// swizzle, max 2-way bank alias = free). LDS ~27 KB -> 5 blocks/CU. hh no
// longer read by this kernel at all.
__global__ __launch_bounds__(256, 5) void edge_kernel(
    const int* __restrict__ rows, const int* __restrict__ cols,
    const int* __restrict__ perm,
    const float* __restrict__ coord,
    const float* __restrict__ eattr,
    const float* __restrict__ gEW1,                 // only ext rows 128..130
    const float* __restrict__ gEW2, const float* __restrict__ gEB2,
    const float* __restrict__ gCW1, const float* __restrict__ gCB1,
    const float* __restrict__ gCW2,
    const uint_t* __restrict__ preR, const uint_t* __restrict__ preC,
    float* __restrict__ csum, float* __restrict__ magg)
{
    __shared__ __align__(16) uint_t tileh[EBLK * 32];  // f16-pair activations, 8 KB
    __shared__ __align__(16) uint_t sW2p[2048];        // f16-pair W2, 8 KB
    __shared__ __align__(16) uint_t sCW1p[2048];       // f16-pair cW1, 8 KB
    __shared__ float sExtW[3 * 64];                    // W1 rows 128..130 fp32
    __shared__ float sB2[64], sCB1[64], sCW2v[64];
    __shared__ int   sr[EBLK], sc[EBLK], se[EBLK];
    __shared__ int   segstart[EBLK + 1];
    __shared__ int   snseg;

    const int t = threadIdx.x;
    // ---- stage W2, cW1 (f16 pairs), ext rows, biases ----
    for (int i = t; i < 512; i += 256) {           // 32 kp x 16 j4-groups
        const int kp = i >> 4, j4 = i & 15;
        const float4 w0 = ((const float4*)gEW2)[kp * 32 + j4];
        const float4 w1 = ((const float4*)gEW2)[kp * 32 + 16 + j4];
        uint4 u;
        u.x = h2u(pkrtz(w0.x, w1.x)); u.y = h2u(pkrtz(w0.y, w1.y));
        u.z = h2u(pkrtz(w0.z, w1.z)); u.w = h2u(pkrtz(w0.w, w1.w));
        ((uint4*)sW2p)[i] = u;
    }
    for (int i = t; i < 512; i += 256) {
        const int kp = i >> 4, j4 = i & 15;
        const float4 w0 = ((const float4*)gCW1)[kp * 32 + j4];
        const float4 w1 = ((const float4*)gCW1)[kp * 32 + 16 + j4];
        uint4 u;
        u.x = h2u(pkrtz(w0.x, w1.x)); u.y = h2u(pkrtz(w0.y, w1.y));
        u.z = h2u(pkrtz(w0.z, w1.z)); u.w = h2u(pkrtz(w0.w, w1.w));
        ((uint4*)sCW1p)[i] = u;
    }
    if (t < 192) sExtW[t] = gEW1[8192 + t];        // rows 128..130
    if (t < 64) { sB2[t] = gEB2[t]; sCB1[t] = gCB1[t]; sCW2v[t] = gCW2[t]; }

    // ---- load this block's 64 edges (sorted by row via perm) ----
    if (t < EBLK) {
        int e = perm[blockIdx.x * EBLK + t];
        e = ((uint_t)e < (uint_t)NE) ? e : 0;
        int r = rows[e], c = cols[e];
        r = ((uint_t)r < (uint_t)NN) ? r : 0;
        c = ((uint_t)c < (uint_t)NN) ? c : 0;
        se[t] = e; sr[t] = r; sc[t] = c;
    }
    __syncthreads();

    // ---- segment boundaries over the 64 sorted rows: wave-0 shfl scan ----
    if (t < EBLK) {
        const int flag = (t == 0) ? 1 : ((sr[t] != sr[t - 1]) ? 1 : 0);
        int isc = flag;
        #pragma unroll
        for (int d = 1; d < EBLK; d <<= 1) {
            const int up = __shfl_up(isc, d);
            if (t >= d) isc += up;
        }
        if (flag) segstart[isc - 1] = t;
        if (t == EBLK - 1) { snseg = isc; segstart[isc] = EBLK; }
    }
    __syncthreads();
    const int nseg = snseg;

    // ---- per-thread edge/chunk identity ----
    const int ei = t >> 2;          // edge in block
    const int q  = t & 3;           // channel chunk (16 ch)
    const int swz = ei & 31;        // tileh swizzle key
    const int r = sr[ei], c = sc[ei], e = se[ei];

    const float dx = coord[3 * r + 0] - coord[3 * c + 0];
    const float dy = coord[3 * r + 1] - coord[3 * c + 1];
    const float dz = coord[3 * r + 2] - coord[3 * c + 2];
    const float radial = dx * dx + dy * dy + dz * dz;
    const float2 ea = ((const float2*)eattr)[e];

    // ---- phase 1: acc16 = preR[r] + preC[c] + ext; silu; pack to tileh ----
    union { uint4 v[2]; uint_t a[8]; } R, C;
    {
        const uint4* pr = (const uint4*)(preR + (size_t)r * 32);
        const uint4* pc = (const uint4*)(preC + (size_t)c * 32);
        R.v[0] = pr[q * 2]; R.v[1] = pr[q * 2 + 1];
        C.v[0] = pc[q * 2]; C.v[1] = pc[q * 2 + 1];
    }
    float acc16[16];
    #pragma unroll
    for (int p = 0; p < 8; p++) {
        const half2v hr = u2h(R.a[p]);
        const half2v hc = u2h(C.a[p]);
        acc16[2 * p]     = (float)hr.x + (float)hc.x;
        acc16[2 * p + 1] = (float)hr.y + (float)hc.y;
    }
    {
        const float ext3[3] = {radial, ea.x, ea.y};
        #pragma unroll
        for (int x = 0; x < 3; x++) {
            const float v = ext3[x];
            const float* w = &sExtW[x * 64 + q * 16];
            #pragma unroll
            for (int j = 0; j < 16; j++) acc16[j] += v * w[j];
        }
    }
    #pragma unroll
    for (int j = 0; j < 16; j++) acc16[j] = silu(acc16[j]);
    #pragma unroll
    for (int p = 0; p < 8; p++)
        tileh[ei * 32 + ((q * 8 + p) ^ swz)] = h2u(pkrtz(acc16[2 * p], acc16[2 * p + 1]));
    __syncthreads();

    // ---- layer 2: m16 = silu(hid64 @ W2[:, q*16..+16] + b2) ----
    float m16[16];
    #pragma unroll
    for (int j = 0; j < 16; j++) m16[j] = sB2[q * 16 + j];
    #pragma unroll 8
    for (int kp = 0; kp < 32; kp++) {
        const half2v hp = u2h(tileh[ei * 32 + (kp ^ swz)]);
        const uint_t* w = &sW2p[kp * 64 + q * 16];
        #pragma unroll
        for (int j = 0; j < 16; j++) m16[j] = dot2h(hp, w[j], m16[j]);
    }
    #pragma unroll
    for (int j = 0; j < 16; j++) m16[j] = silu(m16[j]);

    __syncthreads();                 // all hid reads done before m overwrites
    #pragma unroll
    for (int p = 0; p < 8; p++)
        tileh[ei * 32 + ((q * 8 + p) ^ swz)] = h2u(pkrtz(m16[2 * p], m16[2 * p + 1]));
    __syncthreads();                 // tileh now holds m for all edges

    // ---- cw = silu(m @ cW1 + cb1) @ cW2 ----
    float ch16[16];
    #pragma unroll
    for (int j = 0; j < 16; j++) ch16[j] = sCB1[q * 16 + j];
    #pragma unroll 8
    for (int kp = 0; kp < 32; kp++) {
        const half2v hp = u2h(tileh[ei * 32 + (kp ^ swz)]);
        const uint_t* w = &sCW1p[kp * 64 + q * 16];
        #pragma unroll
        for (int j = 0; j < 16; j++) ch16[j] = dot2h(hp, w[j], ch16[j]);
    }
    float part = 0.f;
    #pragma unroll
    for (int j = 0; j < 16; j++) part += silu(ch16[j]) * sCW2v[q * 16 + j];
    part += __shfl_xor(part, 1);
    part += __shfl_xor(part, 2);
    const float cw = part;

    // ---- segmented reduction: magg (64 channels from f16 tileh-m) ----
    for (int w = t; w < nseg * 64; w += 256) {
        const int lr2 = w >> 6, cc = w & 63;
        const int p0 = segstart[lr2], p1 = segstart[lr2 + 1];
        const int kp = cc >> 1, hi = cc & 1;
        float s = 0.f;
        for (int p = p0; p < p1; p++) {
            const half2v h = u2h(tileh[p * 32 + (kp ^ (p & 31))]);
            s += hi ? (float)h.y : (float)h.x;
        }
        atomicAdd(&magg[(size_t)sr[p0] * 64 + cc], s);
    }
    __syncthreads();

    // ---- segmented reduction: csum (3 coords; tileh reused as fp32 scratch) --
    float* tf = (float*)tileh;
    if (q < 3) tf[ei * 4 + q] = (q == 0 ? dx : (q == 1 ? dy : dz)) * cw;
    __syncthreads();
    for (int w = t; w < nseg * 3; w += 256) {
        const int lr2 = w / 3, cc = w - 3 * lr2;
        const int p0 = segstart[lr2], p1 = segstart[lr2 + 1];
        float s = 0.f;
        for (int p = p0; p < p1; p++) s += tf[p * 4 + cc];
        atomicAdd(&csum[3 * sr[p0] + cc], s);
    }
}

// ---- per-layer node kernel: 4 threads per node, 16 channels per thread -------
// Round-12 change: zeroes magg/csum after consuming them (replaces 3 of the 4
// per-layer memset dispatches). Otherwise the round-4-validated structure.
__global__ __launch_bounds__(256, 2) void node_kernel(
    const float* __restrict__ gVW1, const float* __restrict__ gVB1,
    const float* __restrict__ gVW2, const float* __restrict__ gVB2,
    const float* __restrict__ gGW1, const float* __restrict__ gGB1,
    const float* __restrict__ gGW2, const float* __restrict__ gGB2,
    const float* __restrict__ gNW1, const float* __restrict__ gNB1,
    const float* __restrict__ gNW2, const float* __restrict__ gNB2,
    float* __restrict__ csum, const int* __restrict__ off,
    const float* __restrict__ vsrc, const float* __restrict__ field,
    float* __restrict__ magg,
    float* __restrict__ coord, float* __restrict__ hh)
{
    __shared__ __align__(16) float sNW1[128 * 64];     // 32 KB
    __shared__ __align__(16) float tile[NPB * 64];     // 16 KB exchange
    __shared__ float sNB1[64], sNB2[64];

    const int t = threadIdx.x;
    for (int i = t; i < 2048; i += 256) ((float4*)sNW1)[i] = ((const float4*)gNW1)[i];
    if (t < 64) { sNB1[t] = gNB1[t]; sNB2[t] = gNB2[t]; }
    __syncthreads();

    const int ni = t >> 2;          // node in block
    const int q  = t & 3;           // channel chunk
    const int sw = ni & 7;          // tile swizzle key
    int n = blockIdx.x * NPB + ni;
    const bool valid = (n < NN);
    n = valid ? n : (NN - 1);       // clamp for safe reads; writes predicated

    const float4* hh4 = (const float4*)(hh + (size_t)n * 64);
    const float4* mg4 = (const float4*)(magg + (size_t)n * 64);
    float4* tile4 = (float4*)tile;

    // ---- vw = silu(hh @ vW1 + vb1) @ vW2 + vb2 ----
    float a16[16];
    #pragma unroll
    for (int j = 0; j < 16; j++) a16[j] = gVB1[q * 16 + j];
    #pragma unroll 2
    for (int kk = 0; kk < 16; kk++) {
        const float4 h4 = hh4[kk];
        const float hv[4] = {h4.x, h4.y, h4.z, h4.w};
        #pragma unroll
        for (int u = 0; u < 4; u++) {
            const float v = hv[u];
            const float4* w4 = (const float4*)(gVW1 + (kk * 4 + u) * 64 + q * 16);
            #pragma unroll
            for (int j4 = 0; j4 < 4; j4++) {
                const float4 w = w4[j4];
                a16[4 * j4 + 0] += v * w.x; a16[4 * j4 + 1] += v * w.y;
                a16[4 * j4 + 2] += v * w.z; a16[4 * j4 + 3] += v * w.w;
            }
        }
    }
    float part = 0.f;
    #pragma unroll
    for (int j = 0; j < 16; j++) part += silu(a16[j]) * gVW2[q * 16 + j];
    part += __shfl_xor(part, 1);
    part += __shfl_xor(part, 2);
    const float vw = part + gVB2[0];

    // ---- gw = silu(hh @ gW1 + gb1) @ gW2 + gb2 (reuses a16) ----
    #pragma unroll
    for (int j = 0; j < 16; j++) a16[j] = gGB1[q * 16 + j];
    #pragma unroll 2
    for (int kk = 0; kk < 16; kk++) {
        const float4 h4 = hh4[kk];
        const float hv[4] = {h4.x, h4.y, h4.z, h4.w};
        #pragma unroll
        for (int u = 0; u < 4; u++) {
            const float v = hv[u];
            const float4* w4 = (const float4*)(gGW1 + (kk * 4 + u) * 64 + q * 16);
            #pragma unroll
            for (int j4 = 0; j4 < 4; j4++) {
                const float4 w = w4[j4];
                a16[4 * j4 + 0] += v * w.x; a16[4 * j4 + 1] += v * w.y;
                a16[4 * j4 + 2] += v * w.z; a16[4 * j4 + 3] += v * w.w;
            }
        }
    }
    part = 0.f;
    #pragma unroll
    for (int j = 0; j < 16; j++) part += silu(a16[j]) * gGW2[q * 16 + j];
    part += __shfl_xor(part, 1);
    part += __shfl_xor(part, 2);
    const float gw = part + gGB2[0];

    // ---- coord update (one thread per node) ----
    if (valid && q == 0) {
        const float cn = fmaxf((float)(off[n + 1] - off[n]), 1.0f);
        #pragma unroll
        for (int d = 0; d < 3; d++)
            coord[3 * n + d] += csum[3 * n + d] / cn
                              + vw * vsrc[3 * n + d]
                              + gw * field[3 * n + d];
    }

    // ---- node MLP hidden: a16 = silu([hh, magg] @ NW1[:, q*16..+16] + b1) ----
    #pragma unroll
    for (int j = 0; j < 16; j++) a16[j] = sNB1[q * 16 + j];
    #pragma unroll 2
    for (int kk = 0; kk < 16; kk++) {
        const float4 h4 = hh4[kk];
        const float hv[4] = {h4.x, h4.y, h4.z, h4.w};
        #pragma unroll
        for (int u = 0; u < 4; u++) {
            const float v = hv[u];
            const float* w = &sNW1[(kk * 4 + u) * 64 + q * 16];
            #pragma unroll
            for (int j = 0; j < 16; j++) a16[j] += v * w[j];
        }
    }
    #pragma unroll 2
    for (int kk = 0; kk < 16; kk++) {
        const float4 m4 = mg4[kk];
        const float mv[4] = {m4.x, m4.y, m4.z, m4.w};
        #pragma unroll
        for (int u = 0; u < 4; u++) {
            const float v = mv[u];
            const float* w = &sNW1[(64 + kk * 4 + u) * 64 + q * 16];
            #pragma unroll
            for (int j = 0; j < 16; j++) a16[j] += v * w[j];
        }
    }
    #pragma unroll
    for (int j = 0; j < 16; j++) a16[j] = silu(a16[j]);

    // ---- exchange hidden through swizzled tile ----
    #pragma unroll
    for (int j = 0; j < 4; j++) {
        float4 v; v.x = a16[4 * j]; v.y = a16[4 * j + 1];
        v.z = a16[4 * j + 2]; v.w = a16[4 * j + 3];
        tile4[ni * 16 + ((q * 4 + j) ^ sw)] = v;
    }
    __syncthreads();

    // ---- zero magg/csum for next layer (all reads completed above) ----
    if (valid) {
        float4 z; z.x = z.y = z.z = z.w = 0.f;
        float4* mz = (float4*)(magg + (size_t)n * 64);
        #pragma unroll
        for (int j4 = 0; j4 < 4; j4++) mz[q * 4 + j4] = z;
        if (q == 0) { csum[3 * n] = 0.f; csum[3 * n + 1] = 0.f; csum[3 * n + 2] = 0.f; }
    }

    // ---- output: o16 = hid64 @ NW2[:, q*16..+16] + b2 ----
    float o16[16];
    #pragma unroll
    for (int j = 0; j < 16; j++) o16[j] = sNB2[q * 16 + j];
    #pragma unroll 2
    for (int kk = 0; kk < 16; kk++) {
        const float4 h4 = tile4[ni * 16 + (kk ^ sw)];
        const float hv[4] = {h4.x, h4.y, h4.z, h4.w};
        #pragma unroll
        for (int u = 0; u < 4; u++) {
            const float v = hv[u];
            const float4* w4 = (const float4*)(gNW2 + (kk * 4 + u) * 64 + q * 16);
            #pragma unroll
            for (int j4 = 0; j4 < 4; j4++) {
                const float4 w = w4[j4];
                o16[4 * j4 + 0] += v * w.x; o16[4 * j4 + 1] += v * w.y;
                o16[4 * j4 + 2] += v * w.z; o16[4 * j4 + 3] += v * w.w;
            }
        }
    }
    if (valid) {
        float4* out4 = (float4*)(hh + (size_t)n * 64 + q * 16);
        #pragma unroll
        for (int j4 = 0; j4 < 4; j4++) {
            float4 v; v.x = o16[4 * j4]; v.y = o16[4 * j4 + 1];
            v.z = o16[4 * j4 + 2]; v.w = o16[4 * j4 + 3];
            out4[j4] = v;
        }
    }
}

// ---- host launch -------------------------------------------------------------
extern "C" void kernel_launch(void* const* d_in, const int* in_sizes, int n_in,
                              void* d_out, int out_size, void* d_ws, size_t ws_size,
                              hipStream_t stream) {
    float* wsf = (float*)d_ws;
    int*   wsi = (int*)(wsf + 1340000);
    uint_t* preR = (uint_t*)(wsi + IOFF_PRER);
    uint_t* preC = (uint_t*)(wsi + IOFF_PREC);
    float* coord = (float*)d_out;          // fp32 coord state lives in d_out
    const int* edges = (const int*)d_in[4];
    const int* rows = edges;
    const int* cols = edges + NE;

    // ---- CSR build (once per call) ----
    hipMemsetAsync(wsi + IOFF_CNTI, 0, NN * sizeof(int), stream);
    counti_kernel<<<(NE + 255) / 256, 256, 0, stream>>>(rows, wsi + IOFF_CNTI);
    scan_kernel<<<1, 1024, 0, stream>>>(wsi + IOFF_CNTI, wsi + IOFF_OFF, wsi + IOFF_CURSOR);
    scatter_kernel<<<(NE + 255) / 256, 256, 0, stream>>>(rows, wsi + IOFF_CURSOR,
                                                         wsi + IOFF_PERM);

    node_init<<<(NN + 255) / 256, 256, 0, stream>>>(
        (const float*)d_in[0], (const float*)d_in[1], (const float*)d_in[2],
        (const int*)d_in[5], (const float*)d_in[8],
        (const float*)d_in[9],  (const float*)d_in[10],
        (const float*)d_in[11], (const float*)d_in[12],
        (const float*)d_in[13], (const float*)d_in[14],
        (const float*)d_in[6],  (const float*)d_in[7],
        coord, wsf + OFF_FIELD, wsf + OFF_HH);

    // csum+magg zeroed once; node_kernel re-zeroes them for subsequent layers
    hipMemsetAsync(wsf + OFF_CSUM, 0, (30000 + 640000) * sizeof(float), stream);

    for (int l = 0; l < NL; l++) {
        pre_kernel<<<NNODEBLK, 256, 0, stream>>>(
            wsf + OFF_HH,
            ((const float*)d_in[15]) + l * 8384, ((const float*)d_in[16]) + l * 64,
            preR, preC);
        edge_kernel<<<NEBLK, 256, 0, stream>>>(
            rows, cols, wsi + IOFF_PERM,
            coord, (const float*)d_in[3],
            ((const float*)d_in[15]) + l * 8384,
            ((const float*)d_in[17]) + l * 4096, ((const float*)d_in[18]) + l * 64,
            ((const float*)d_in[23]) + l * 4096, ((const float*)d_in[24]) + l * 64,
            ((const float*)d_in[25]) + l * 64,
            preR, preC,
            wsf + OFF_CSUM, wsf + OFF_MAGG);
        node_kernel<<<NNODEBLK, 256, 0, stream>>>(
            ((const float*)d_in[26]) + l * 4096, ((const float*)d_in[27]) + l * 64,
            ((const float*)d_in[28]) + l * 64,   ((const float*)d_in[29]) + l,
            ((const float*)d_in[30]) + l * 4096, ((const float*)d_in[31]) + l * 64,
            ((const float*)d_in[32]) + l * 64,   ((const float*)d_in[33]) + l,
            ((const float*)d_in[19]) + l * 8192, ((const float*)d_in[20]) + l * 64,
            ((const float*)d_in[21]) + l * 4096, ((const float*)d_in[22]) + l * 64,
            wsf + OFF_CSUM, wsi + IOFF_OFF, (const float*)d_in[2],
            wsf + OFF_FIELD, wsf + OFF_MAGG, coord, wsf + OFF_HH);
    }
}

// Round 13
// 796.838 us; speedup vs baseline: 3.5316x; 1.0261x over previous
//
#include <hip/hip_runtime.h>
#include <hip/hip_bf16.h>

typedef unsigned short ushort_t;
typedef unsigned int uint_t;

#define NN    10000
#define NE    320000
#define NL    4
#define EBLK  64        // edges per block (4 threads per edge)
#define NEBLK 5000      // NE / EBLK exactly
#define NPB   64        // nodes per block (4 threads per node)
#define NNODEBLK 157    // ceil(NN / NPB)

// ---- workspace float offsets -------------------------------------------------
#define OFF_FIELD 0        // 30000
#define OFF_HH    30000    // 640000
#define OFF_CSUM  670000   // 30000  (contiguous with MAGG for one memset)
#define OFF_MAGG  700000   // 640000 -> float end 1340000
// ---- int region (starts at float offset 1340000) ----------------------------
#define IOFF_CNTI   0        // 10000
#define IOFF_OFF    10000    // 10001
#define IOFF_CURSOR 20001    // 10000
#define IOFF_PERM   30001    // 320000
#define IOFF_PRER   350004   // 320000 uints (f16-pair preR; 16B-aligned)
#define IOFF_PREC   670004   // 320000 uints -> int end 990004
// total ws = (1340000 + 990004) * 4 = 9,320,016 B  (ws_size >= 9.4 MB verified r12)

// fast silu: v_rcp_f32 instead of IEEE divide (~1e-7 rel err, VALU-bound paths)
__device__ __forceinline__ float silu(float x) {
    return x * __builtin_amdgcn_rcpf(1.0f + __expf(-x));
}

// ---- f16 pair helpers for v_dot2_f32_f16 (clang builtins use __fp16 V2h) -----
typedef __fp16 half2v __attribute__((ext_vector_type(2)));
__device__ __forceinline__ half2v u2h(uint_t u) {
    union { uint_t u; half2v h; } x; x.u = u; return x.h;
}
__device__ __forceinline__ uint_t h2u(half2v h) {
    union { half2v h; uint_t u; } x; x.h = h; return x.u;
}
__device__ __forceinline__ half2v pkrtz(float a, float b) {
    return __builtin_amdgcn_cvt_pkrtz(a, b);
}
__device__ __forceinline__ float dot2h(half2v a, uint_t w, float c) {
#if __has_builtin(__builtin_amdgcn_fdot2)
    return __builtin_amdgcn_fdot2(a, u2h(w), c, false);
#else
    union { uint_t u; __fp16 h[2]; } x; x.u = w;
    return c + (float)a.x * (float)x.h[0] + (float)a.y * (float)x.h[1];
#endif
}

// ---- CSR build: per-row int counts ------------------------------------------
__global__ __launch_bounds__(256) void counti_kernel(const int* __restrict__ rows,
                                                     int* __restrict__ cnti) {
    const int e = blockIdx.x * 256 + threadIdx.x;
    if (e < NE) {
        int r = rows[e];
        r = ((uint_t)r < (uint_t)NN) ? r : 0;
        atomicAdd(&cnti[r], 1);
    }
}

// ---- CSR build: exclusive scan over 10000 counts (single block) --------------
__global__ __launch_bounds__(1024) void scan_kernel(const int* __restrict__ cnti,
                                                    int* __restrict__ off,
                                                    int* __restrict__ cursor) {
    __shared__ int part[1024];
    const int t = threadIdx.x;
    const int base = t * 10;
    int loc[10];
    int s = 0;
    #pragma unroll
    for (int i = 0; i < 10; i++) {
        const int idx = base + i;
        const int v = (idx < NN) ? cnti[idx] : 0;
        loc[i] = s; s += v;
    }
    part[t] = s;
    __syncthreads();
    const int own = s;
    for (int d = 1; d < 1024; d <<= 1) {
        const int v = (t >= d) ? part[t - d] : 0;
        __syncthreads();
        part[t] += v;
        __syncthreads();
    }
    const int excl = part[t] - own;
    #pragma unroll
    for (int i = 0; i < 10; i++) {
        const int idx = base + i;
        if (idx < NN) { const int o = excl + loc[i]; off[idx] = o; cursor[idx] = o; }
    }
    if (t == 0) off[NN] = NE;
}

// ---- CSR build: scatter edge ids into row-sorted order -----------------------
__global__ __launch_bounds__(256) void scatter_kernel(const int* __restrict__ rows,
                                                      int* __restrict__ cursor,
                                                      int* __restrict__ perm) {
    const int e = blockIdx.x * 256 + threadIdx.x;
    if (e < NE) {
        int r = rows[e];
        r = ((uint_t)r < (uint_t)NN) ? r : 0;
        const int pos = atomicAdd(&cursor[r], 1);
        if ((uint_t)pos < (uint_t)NE) perm[pos] = e;
    }
}

// ---- field network + node embedding + coord init (once per call) ------------
__global__ __launch_bounds__(256) void node_init(
    const float* __restrict__ hsrc, const float* __restrict__ xsrc,
    const float* __restrict__ vsrc, const int* __restrict__ charges,
    const float* __restrict__ cls,
    const float* __restrict__ fW1, const float* __restrict__ fb1,
    const float* __restrict__ fW2, const float* __restrict__ fb2,
    const float* __restrict__ fW3, const float* __restrict__ fb3,
    const float* __restrict__ embW, const float* __restrict__ embb,
    float* __restrict__ coord, float* __restrict__ field, float* __restrict__ hh)
{
    __shared__ float sFW1[704], sFW2[1024], sFW3[96];
    __shared__ float sFB1[32], sFB2[32], sFB3[3], sCLS[32], sEW[64], sEB[64];
    const int t = threadIdx.x;
    for (int i = t; i < 704; i += 256) sFW1[i] = fW1[i];
    for (int i = t; i < 1024; i += 256) sFW2[i] = fW2[i];
    if (t < 96) sFW3[t] = fW3[t];
    if (t < 32) { sFB1[t] = fb1[t]; sFB2[t] = fb2[t]; sCLS[t] = cls[t]; }
    if (t < 3)  sFB3[t] = fb3[t];
    if (t < 64) { sEW[t] = embW[t]; sEB[t] = embb[t]; }
    __syncthreads();

    const int n = blockIdx.x * 256 + t;
    if (n >= NN) return;

    float fin[22];
    #pragma unroll
    for (int d = 0; d < 3; d++) {
        fin[d]     = xsrc[3 * n + d];
        fin[3 + d] = vsrc[3 * n + d];
        coord[3 * n + d] = fin[d];
    }
    int ci = charges[n];
    ci = ((uint_t)ci < 2u) ? ci : 0;
    const int cix = ci * 16;
    #pragma unroll
    for (int k = 0; k < 16; k++) fin[6 + k] = sCLS[cix + k];

    float h1[32];
    #pragma unroll
    for (int j = 0; j < 32; j++) h1[j] = sFB1[j];
    #pragma unroll
    for (int k = 0; k < 22; k++) {
        const float v = fin[k];
        #pragma unroll
        for (int j = 0; j < 32; j++) h1[j] += v * sFW1[k * 32 + j];
    }
    #pragma unroll
    for (int j = 0; j < 32; j++) h1[j] = silu(h1[j]);

    float h2[32];
    #pragma unroll
    for (int j = 0; j < 32; j++) h2[j] = sFB2[j];
    #pragma unroll
    for (int k = 0; k < 32; k++) {
        const float v = h1[k];
        #pragma unroll
        for (int j = 0; j < 32; j++) h2[j] += v * sFW2[k * 32 + j];
    }
    #pragma unroll
    for (int j = 0; j < 32; j++) h2[j] = silu(h2[j]);

    #pragma unroll
    for (int d = 0; d < 3; d++) {
        float s = sFB3[d];
        #pragma unroll
        for (int j = 0; j < 32; j++) s += h2[j] * sFW3[j * 3 + d];
        field[3 * n + d] = s;
    }

    const float hv = hsrc[n];
    #pragma unroll
    for (int j = 0; j < 64; j++) hh[(size_t)n * 64 + j] = hv * sEW[j] + sEB[j];
}

// ---- layer-0 pre kernel: preR[n] = b1 + W1r.hh[n], preC[n] = W1c.hh[n] -------
// (layers 1..3 get pre emitted by node_kernel's fused epilogue)
__global__ __launch_bounds__(256, 4) void pre_kernel(
    const float* __restrict__ hh,
    const float* __restrict__ gEW1, const float* __restrict__ gEB1,
    uint_t* __restrict__ preR, uint_t* __restrict__ preC)
{
    __shared__ __align__(16) uint_t sW1p[4096];   // rows 0..127 f16-paired, 16 KB
    __shared__ float sB1[64];
    const int t = threadIdx.x;
    for (int i = t; i < 1024; i += 256) {          // 64 kp x 16 j4-groups
        const int kp = i >> 4, j4 = i & 15;
        const float4 w0 = ((const float4*)gEW1)[kp * 32 + j4];
        const float4 w1 = ((const float4*)gEW1)[kp * 32 + 16 + j4];
        uint4 u;
        u.x = h2u(pkrtz(w0.x, w1.x)); u.y = h2u(pkrtz(w0.y, w1.y));
        u.z = h2u(pkrtz(w0.z, w1.z)); u.w = h2u(pkrtz(w0.w, w1.w));
        ((uint4*)sW1p)[i] = u;
    }
    if (t < 64) sB1[t] = gEB1[t];
    __syncthreads();

    const int ni = t >> 2, q = t & 3;
    int n = blockIdx.x * NPB + ni;
    const bool valid = (n < NN);
    n = valid ? n : (NN - 1);
    const float4* h4p = (const float4*)(hh + (size_t)n * 64);

    float acc[16];
    #pragma unroll
    for (int j = 0; j < 16; j++) acc[j] = sB1[q * 16 + j];
    #pragma unroll
    for (int kk = 0; kk < 16; kk++) {
        const float4 a = h4p[kk];
        const half2v p0 = pkrtz(a.x, a.y);
        const half2v p1 = pkrtz(a.z, a.w);
        const uint4* w0 = (const uint4*)&sW1p[(2 * kk) * 64 + q * 16];
        const uint4* w1 = (const uint4*)&sW1p[(2 * kk + 1) * 64 + q * 16];
        #pragma unroll
        for (int j4 = 0; j4 < 4; j4++) {
            const uint4 wa = w0[j4], wb = w1[j4];
            acc[4*j4+0] = dot2h(p1, wb.x, dot2h(p0, wa.x, acc[4*j4+0]));
            acc[4*j4+1] = dot2h(p1, wb.y, dot2h(p0, wa.y, acc[4*j4+1]));
            acc[4*j4+2] = dot2h(p1, wb.z, dot2h(p0, wa.z, acc[4*j4+2]));
            acc[4*j4+3] = dot2h(p1, wb.w, dot2h(p0, wa.w, acc[4*j4+3]));
        }
    }
    if (valid) {
        uint4 o0, o1;
        o0.x = h2u(pkrtz(acc[0],  acc[1]));  o0.y = h2u(pkrtz(acc[2],  acc[3]));
        o0.z = h2u(pkrtz(acc[4],  acc[5]));  o0.w = h2u(pkrtz(acc[6],  acc[7]));
        o1.x = h2u(pkrtz(acc[8],  acc[9]));  o1.y = h2u(pkrtz(acc[10], acc[11]));
        o1.z = h2u(pkrtz(acc[12], acc[13])); o1.w = h2u(pkrtz(acc[14], acc[15]));
        uint4* dst = (uint4*)(preR + (size_t)n * 32 + q * 8);
        dst[0] = o0; dst[1] = o1;
    }

    #pragma unroll
    for (int j = 0; j < 16; j++) acc[j] = 0.f;
    #pragma unroll
    for (int kk = 0; kk < 16; kk++) {
        const float4 a = h4p[kk];
        const half2v p0 = pkrtz(a.x, a.y);
        const half2v p1 = pkrtz(a.z, a.w);
        const uint4* w0 = (const uint4*)&sW1p[(32 + 2 * kk) * 64 + q * 16];
        const uint4* w1 = (const uint4*)&sW1p[(33 + 2 * kk) * 64 + q * 16];
        #pragma unroll
        for (int j4 = 0; j4 < 4; j4++) {
            const uint4 wa = w0[j4], wb = w1[j4];
            acc[4*j4+0] = dot2h(p1, wb.x, dot2h(p0, wa.x, acc[4*j4+0]));
            acc[4*j4+1] = dot2h(p1, wb.y, dot2h(p0, wa.y, acc[4*j4+1]));
            acc[4*j4+2] = dot2h(p1, wb.z, dot2h(p0, wa.z, acc[4*j4+2]));
            acc[4*j4+3] = dot2h(p1, wb.w, dot2h(p0, wa.w, acc[4*j4+3]));
        }
    }
    if (valid) {
        uint4 o0, o1;
        o0.x = h2u(pkrtz(acc[0],  acc[1]));  o0.y = h2u(pkrtz(acc[2],  acc[3]));
        o0.z = h2u(pkrtz(acc[4],  acc[5]));  o0.w = h2u(pkrtz(acc[6],  acc[7]));
        o1.x = h2u(pkrtz(acc[8],  acc[9]));  o1.y = h2u(pkrtz(acc[10], acc[11]));
        o1.z = h2u(pkrtz(acc[12], acc[13])); o1.w = h2u(pkrtz(acc[14], acc[15]));
        uint4* dst = (uint4*)(preC + (size_t)n * 32 + q * 8);
        dst[0] = o0; dst[1] = o1;
    }
}

// ---- per-layer edge kernel (r12 structure + explicit uint4 LDS weight reads) -
__global__ __launch_bounds__(256, 5) void edge_kernel(
    const int* __restrict__ rows, const int* __restrict__ cols,
    const int* __restrict__ perm,
    const float* __restrict__ coord,
    const float* __restrict__ eattr,
    const float* __restrict__ gEW1,                 // only ext rows 128..130
    const float* __restrict__ gEW2, const float* __restrict__ gEB2,
    const float* __restrict__ gCW1, const float* __restrict__ gCB1,
    const float* __restrict__ gCW2,
    const uint_t* __restrict__ preR, const uint_t* __restrict__ preC,
    float* __restrict__ csum, float* __restrict__ magg)
{
    __shared__ __align__(16) uint_t tileh[EBLK * 32];  // f16-pair activations, 8 KB
    __shared__ __align__(16) uint_t sW2p[2048];        // f16-pair W2, 8 KB
    __shared__ __align__(16) uint_t sCW1p[2048];       // f16-pair cW1, 8 KB
    __shared__ float sExtW[3 * 64];                    // W1 rows 128..130 fp32
    __shared__ float sB2[64], sCB1[64], sCW2v[64];
    __shared__ int   sr[EBLK], sc[EBLK], se[EBLK];
    __shared__ int   segstart[EBLK + 1];
    __shared__ int   snseg;

    const int t = threadIdx.x;
    for (int i = t; i < 512; i += 256) {           // 32 kp x 16 j4-groups
        const int kp = i >> 4, j4 = i & 15;
        const float4 w0 = ((const float4*)gEW2)[kp * 32 + j4];
        const float4 w1 = ((const float4*)gEW2)[kp * 32 + 16 + j4];
        uint4 u;
        u.x = h2u(pkrtz(w0.x, w1.x)); u.y = h2u(pkrtz(w0.y, w1.y));
        u.z = h2u(pkrtz(w0.z, w1.z)); u.w = h2u(pkrtz(w0.w, w1.w));
        ((uint4*)sW2p)[i] = u;
    }
    for (int i = t; i < 512; i += 256) {
        const int kp = i >> 4, j4 = i & 15;
        const float4 w0 = ((const float4*)gCW1)[kp * 32 + j4];
        const float4 w1 = ((const float4*)gCW1)[kp * 32 + 16 + j4];
        uint4 u;
        u.x = h2u(pkrtz(w0.x, w1.x)); u.y = h2u(pkrtz(w0.y, w1.y));
        u.z = h2u(pkrtz(w0.z, w1.z)); u.w = h2u(pkrtz(w0.w, w1.w));
        ((uint4*)sCW1p)[i] = u;
    }
    if (t < 192) sExtW[t] = gEW1[8192 + t];        // rows 128..130
    if (t < 64) { sB2[t] = gEB2[t]; sCB1[t] = gCB1[t]; sCW2v[t] = gCW2[t]; }

    if (t < EBLK) {
        int e = perm[blockIdx.x * EBLK + t];
        e = ((uint_t)e < (uint_t)NE) ? e : 0;
        int r = rows[e], c = cols[e];
        r = ((uint_t)r < (uint_t)NN) ? r : 0;
        c = ((uint_t)c < (uint_t)NN) ? c : 0;
        se[t] = e; sr[t] = r; sc[t] = c;
    }
    __syncthreads();

    if (t < EBLK) {
        const int flag = (t == 0) ? 1 : ((sr[t] != sr[t - 1]) ? 1 : 0);
        int isc = flag;
        #pragma unroll
        for (int d = 1; d < EBLK; d <<= 1) {
            const int up = __shfl_up(isc, d);
            if (t >= d) isc += up;
        }
        if (flag) segstart[isc - 1] = t;
        if (t == EBLK - 1) { snseg = isc; segstart[isc] = EBLK; }
    }
    __syncthreads();
    const int nseg = snseg;

    const int ei = t >> 2;
    const int q  = t & 3;
    const int swz = ei & 31;
    const int r = sr[ei], c = sc[ei], e = se[ei];

    const float dx = coord[3 * r + 0] - coord[3 * c + 0];
    const float dy = coord[3 * r + 1] - coord[3 * c + 1];
    const float dz = coord[3 * r + 2] - coord[3 * c + 2];
    const float radial = dx * dx + dy * dy + dz * dz;
    const float2 ea = ((const float2*)eattr)[e];

    // ---- phase 1: acc16 = preR[r] + preC[c] + ext; silu; pack to tileh ----
    union { uint4 v[2]; uint_t a[8]; } R, C;
    {
        const uint4* pr = (const uint4*)(preR + (size_t)r * 32);
        const uint4* pc = (const uint4*)(preC + (size_t)c * 32);
        R.v[0] = pr[q * 2]; R.v[1] = pr[q * 2 + 1];
        C.v[0] = pc[q * 2]; C.v[1] = pc[q * 2 + 1];
    }
    float acc16[16];
    #pragma unroll
    for (int p = 0; p < 8; p++) {
        const half2v hr = u2h(R.a[p]);
        const half2v hc = u2h(C.a[p]);
        acc16[2 * p]     = (float)hr.x + (float)hc.x;
        acc16[2 * p + 1] = (float)hr.y + (float)hc.y;
    }
    {
        const float ext3[3] = {radial, ea.x, ea.y};
        #pragma unroll
        for (int x = 0; x < 3; x++) {
            const float v = ext3[x];
            const float* w = &sExtW[x * 64 + q * 16];
            #pragma unroll
            for (int j = 0; j < 16; j++) acc16[j] += v * w[j];
        }
    }
    #pragma unroll
    for (int j = 0; j < 16; j++) acc16[j] = silu(acc16[j]);
    #pragma unroll
    for (int p = 0; p < 8; p++)
        tileh[ei * 32 + ((q * 8 + p) ^ swz)] = h2u(pkrtz(acc16[2 * p], acc16[2 * p + 1]));
    __syncthreads();

    // ---- layer 2: m16 = silu(hid64 @ W2[:, q*16..+16] + b2) ----
    float m16[16];
    #pragma unroll
    for (int j = 0; j < 16; j++) m16[j] = sB2[q * 16 + j];
    #pragma unroll 8
    for (int kp = 0; kp < 32; kp++) {
        const half2v hp = u2h(tileh[ei * 32 + (kp ^ swz)]);
        const uint4* w4 = (const uint4*)&sW2p[kp * 64 + q * 16];
        #pragma unroll
        for (int j4 = 0; j4 < 4; j4++) {
            const uint4 w = w4[j4];
            m16[4*j4+0] = dot2h(hp, w.x, m16[4*j4+0]);
            m16[4*j4+1] = dot2h(hp, w.y, m16[4*j4+1]);
            m16[4*j4+2] = dot2h(hp, w.z, m16[4*j4+2]);
            m16[4*j4+3] = dot2h(hp, w.w, m16[4*j4+3]);
        }
    }
    #pragma unroll
    for (int j = 0; j < 16; j++) m16[j] = silu(m16[j]);

    __syncthreads();
    #pragma unroll
    for (int p = 0; p < 8; p++)
        tileh[ei * 32 + ((q * 8 + p) ^ swz)] = h2u(pkrtz(m16[2 * p], m16[2 * p + 1]));
    __syncthreads();

    // ---- cw = silu(m @ cW1 + cb1) @ cW2 ----
    float ch16[16];
    #pragma unroll
    for (int j = 0; j < 16; j++) ch16[j] = sCB1[q * 16 + j];
    #pragma unroll 8
    for (int kp = 0; kp < 32; kp++) {
        const half2v hp = u2h(tileh[ei * 32 + (kp ^ swz)]);
        const uint4* w4 = (const uint4*)&sCW1p[kp * 64 + q * 16];
        #pragma unroll
        for (int j4 = 0; j4 < 4; j4++) {
            const uint4 w = w4[j4];
            ch16[4*j4+0] = dot2h(hp, w.x, ch16[4*j4+0]);
            ch16[4*j4+1] = dot2h(hp, w.y, ch16[4*j4+1]);
            ch16[4*j4+2] = dot2h(hp, w.z, ch16[4*j4+2]);
            ch16[4*j4+3] = dot2h(hp, w.w, ch16[4*j4+3]);
        }
    }
    float part = 0.f;
    #pragma unroll
    for (int j = 0; j < 16; j++) part += silu(ch16[j]) * sCW2v[q * 16 + j];
    part += __shfl_xor(part, 1);
    part += __shfl_xor(part, 2);
    const float cw = part;

    // ---- segmented reduction: magg ----
    for (int w = t; w < nseg * 64; w += 256) {
        const int lr2 = w >> 6, cc = w & 63;
        const int p0 = segstart[lr2], p1 = segstart[lr2 + 1];
        const int kp = cc >> 1, hi = cc & 1;
        float s = 0.f;
        for (int p = p0; p < p1; p++) {
            const half2v h = u2h(tileh[p * 32 + (kp ^ (p & 31))]);
            s += hi ? (float)h.y : (float)h.x;
        }
        atomicAdd(&magg[(size_t)sr[p0] * 64 + cc], s);
    }
    __syncthreads();

    // ---- segmented reduction: csum ----
    float* tf = (float*)tileh;
    if (q < 3) tf[ei * 4 + q] = (q == 0 ? dx : (q == 1 ? dy : dz)) * cw;
    __syncthreads();
    for (int w = t; w < nseg * 3; w += 256) {
        const int lr2 = w / 3, cc = w - 3 * lr2;
        const int p0 = segstart[lr2], p1 = segstart[lr2 + 1];
        float s = 0.f;
        for (int p = p0; p < p1; p++) s += tf[p * 4 + cc];
        atomicAdd(&csum[3 * sr[p0] + cc], s);
    }
}

// ---- per-layer node kernel, now with fused next-layer pre emission -----------
// Changes vs r12: NW1 GEMM uses f16-pair dot2 (LDS 32->16 KB); stages next
// layer's W1 (16 KB) and, after writing hh, exchanges o16 through the tile and
// computes preR/preC for the next layer (replaces 3 pre_kernel dispatches).
// LDS: sNW1p 16 + sW1np 16 + tile 16 + biases ~1 KB ~= 49.5 KB -> 3 blocks/CU.
__global__ __launch_bounds__(256, 3) void node_kernel(
    const float* __restrict__ gVW1, const float* __restrict__ gVB1,
    const float* __restrict__ gVW2, const float* __restrict__ gVB2,
    const float* __restrict__ gGW1, const float* __restrict__ gGB1,
    const float* __restrict__ gGW2, const float* __restrict__ gGB2,
    const float* __restrict__ gNW1, const float* __restrict__ gNB1,
    const float* __restrict__ gNW2, const float* __restrict__ gNB2,
    const float* __restrict__ gW1n, const float* __restrict__ gB1n,
    float* __restrict__ csum, const int* __restrict__ off,
    const float* __restrict__ vsrc, const float* __restrict__ field,
    float* __restrict__ magg,
    float* __restrict__ coord, float* __restrict__ hh,
    uint_t* __restrict__ preR, uint_t* __restrict__ preC, const int emit_pre)
{
    __shared__ __align__(16) uint_t sNW1p[4096];       // NW1 f16 pairs, 16 KB
    __shared__ __align__(16) uint_t sW1np[4096];       // next-layer W1 f16, 16 KB
    __shared__ __align__(16) float tile[NPB * 64];     // fp32 exchange, 16 KB
    __shared__ float sNB1[64], sNB2[64], sB1n[64];

    const int t = threadIdx.x;
    for (int i = t; i < 1024; i += 256) {
        const int kp = i >> 4, j4 = i & 15;
        const float4 w0 = ((const float4*)gNW1)[kp * 32 + j4];
        const float4 w1 = ((const float4*)gNW1)[kp * 32 + 16 + j4];
        uint4 u;
        u.x = h2u(pkrtz(w0.x, w1.x)); u.y = h2u(pkrtz(w0.y, w1.y));
        u.z = h2u(pkrtz(w0.z, w1.z)); u.w = h2u(pkrtz(w0.w, w1.w));
        ((uint4*)sNW1p)[i] = u;
    }
    for (int i = t; i < 1024; i += 256) {
        const int kp = i >> 4, j4 = i & 15;
        const float4 w0 = ((const float4*)gW1n)[kp * 32 + j4];
        const float4 w1 = ((const float4*)gW1n)[kp * 32 + 16 + j4];
        uint4 u;
        u.x = h2u(pkrtz(w0.x, w1.x)); u.y = h2u(pkrtz(w0.y, w1.y));
        u.z = h2u(pkrtz(w0.z, w1.z)); u.w = h2u(pkrtz(w0.w, w1.w));
        ((uint4*)sW1np)[i] = u;
    }
    if (t < 64) { sNB1[t] = gNB1[t]; sNB2[t] = gNB2[t]; sB1n[t] = gB1n[t]; }
    __syncthreads();

    const int ni = t >> 2;
    const int q  = t & 3;
    const int sw = ni & 7;          // fp32-tile swizzle key (float4 granules)
    int n = blockIdx.x * NPB + ni;
    const bool valid = (n < NN);
    n = valid ? n : (NN - 1);

    const float4* hh4 = (const float4*)(hh + (size_t)n * 64);
    const float4* mg4 = (const float4*)(magg + (size_t)n * 64);
    float4* tile4 = (float4*)tile;

    // ---- vw = silu(hh @ vW1 + vb1) @ vW2 + vb2 (global fp32: validated) ----
    float a16[16];
    #pragma unroll
    for (int j = 0; j < 16; j++) a16[j] = gVB1[q * 16 + j];
    #pragma unroll 2
    for (int kk = 0; kk < 16; kk++) {
        const float4 h4 = hh4[kk];
        const float hv[4] = {h4.x, h4.y, h4.z, h4.w};
        #pragma unroll
        for (int u = 0; u < 4; u++) {
            const float v = hv[u];
            const float4* w4 = (const float4*)(gVW1 + (kk * 4 + u) * 64 + q * 16);
            #pragma unroll
            for (int j4 = 0; j4 < 4; j4++) {
                const float4 w = w4[j4];
                a16[4 * j4 + 0] += v * w.x; a16[4 * j4 + 1] += v * w.y;
                a16[4 * j4 + 2] += v * w.z; a16[4 * j4 + 3] += v * w.w;
            }
        }
    }
    float part = 0.f;
    #pragma unroll
    for (int j = 0; j < 16; j++) part += silu(a16[j]) * gVW2[q * 16 + j];
    part += __shfl_xor(part, 1);
    part += __shfl_xor(part, 2);
    const float vw = part + gVB2[0];

    // ---- gw (reuses a16) ----
    #pragma unroll
    for (int j = 0; j < 16; j++) a16[j] = gGB1[q * 16 + j];
    #pragma unroll 2
    for (int kk = 0; kk < 16; kk++) {
        const float4 h4 = hh4[kk];
        const float hv[4] = {h4.x, h4.y, h4.z, h4.w};
        #pragma unroll
        for (int u = 0; u < 4; u++) {
            const float v = hv[u];
            const float4* w4 = (const float4*)(gGW1 + (kk * 4 + u) * 64 + q * 16);
            #pragma unroll
            for (int j4 = 0; j4 < 4; j4++) {
                const float4 w = w4[j4];
                a16[4 * j4 + 0] += v * w.x; a16[4 * j4 + 1] += v * w.y;
                a16[4 * j4 + 2] += v * w.z; a16[4 * j4 + 3] += v * w.w;
            }
        }
    }
    part = 0.f;
    #pragma unroll
    for (int j = 0; j < 16; j++) part += silu(a16[j]) * gGW2[q * 16 + j];
    part += __shfl_xor(part, 1);
    part += __shfl_xor(part, 2);
    const float gw = part + gGB2[0];

    // ---- coord update ----
    if (valid && q == 0) {
        const float cn = fmaxf((float)(off[n + 1] - off[n]), 1.0f);
        #pragma unroll
        for (int d = 0; d < 3; d++)
            coord[3 * n + d] += csum[3 * n + d] / cn
                              + vw * vsrc[3 * n + d]
                              + gw * field[3 * n + d];
    }

    // ---- node MLP hidden: a16 = silu([hh, magg] @ NW1 + b1), f16 dot2 ----
    #pragma unroll
    for (int j = 0; j < 16; j++) a16[j] = sNB1[q * 16 + j];
    #pragma unroll 4
    for (int kk = 0; kk < 16; kk++) {             // hh part: kp 0..31
        const float4 h4 = hh4[kk];
        const half2v p0 = pkrtz(h4.x, h4.y);
        const half2v p1 = pkrtz(h4.z, h4.w);
        const uint4* w0 = (const uint4*)&sNW1p[(2 * kk) * 64 + q * 16];
        const uint4* w1 = (const uint4*)&sNW1p[(2 * kk + 1) * 64 + q * 16];
        #pragma unroll
        for (int j4 = 0; j4 < 4; j4++) {
            const uint4 wa = w0[j4], wb = w1[j4];
            a16[4*j4+0] = dot2h(p1, wb.x, dot2h(p0, wa.x, a16[4*j4+0]));
            a16[4*j4+1] = dot2h(p1, wb.y, dot2h(p0, wa.y, a16[4*j4+1]));
            a16[4*j4+2] = dot2h(p1, wb.z, dot2h(p0, wa.z, a16[4*j4+2]));
            a16[4*j4+3] = dot2h(p1, wb.w, dot2h(p0, wa.w, a16[4*j4+3]));
        }
    }
    #pragma unroll 4
    for (int kk = 0; kk < 16; kk++) {             // magg part: kp 32..63
        const float4 m4 = mg4[kk];
        const half2v p0 = pkrtz(m4.x, m4.y);
        const half2v p1 = pkrtz(m4.z, m4.w);
        const uint4* w0 = (const uint4*)&sNW1p[(32 + 2 * kk) * 64 + q * 16];
        const uint4* w1 = (const uint4*)&sNW1p[(33 + 2 * kk) * 64 + q * 16];
        #pragma unroll
        for (int j4 = 0; j4 < 4; j4++) {
            const uint4 wa = w0[j4], wb = w1[j4];
            a16[4*j4+0] = dot2h(p1, wb.x, dot2h(p0, wa.x, a16[4*j4+0]));
            a16[4*j4+1] = dot2h(p1, wb.y, dot2h(p0, wa.y, a16[4*j4+1]));
            a16[4*j4+2] = dot2h(p1, wb.z, dot2h(p0, wa.z, a16[4*j4+2]));
            a16[4*j4+3] = dot2h(p1, wb.w, dot2h(p0, wa.w, a16[4*j4+3]));
        }
    }
    #pragma unroll
    for (int j = 0; j < 16; j++) a16[j] = silu(a16[j]);

    // ---- exchange hidden (fp32) through swizzled tile ----
    #pragma unroll
    for (int j = 0; j < 4; j++) {
        float4 v; v.x = a16[4 * j]; v.y = a16[4 * j + 1];
        v.z = a16[4 * j + 2]; v.w = a16[4 * j + 3];
        tile4[ni * 16 + ((q * 4 + j) ^ sw)] = v;
    }
    __syncthreads();

    // ---- zero magg/csum for next layer (all reads completed above) ----
    if (valid) {
        float4 z; z.x = z.y = z.z = z.w = 0.f;
        float4* mz = (float4*)(magg + (size_t)n * 64);
        #pragma unroll
        for (int j4 = 0; j4 < 4; j4++) mz[q * 4 + j4] = z;
        if (q == 0) { csum[3 * n] = 0.f; csum[3 * n + 1] = 0.f; csum[3 * n + 2] = 0.f; }
    }

    // ---- output: o16 = hid64 @ NW2[:, q*16..+16] + b2 (global fp32) ----
    float o16[16];
    #pragma unroll
    for (int j = 0; j < 16; j++) o16[j] = sNB2[q * 16 + j];
    #pragma unroll 2
    for (int kk = 0; kk < 16; kk++) {
        const float4 h4 = tile4[ni * 16 + (kk ^ sw)];
        const float hv[4] = {h4.x, h4.y, h4.z, h4.w};
        #pragma unroll
        for (int u = 0; u < 4; u++) {
            const float v = hv[u];
            const float4* w4 = (const float4*)(gNW2 + (kk * 4 + u) * 64 + q * 16);
            #pragma unroll
            for (int j4 = 0; j4 < 4; j4++) {
                const float4 w = w4[j4];
                o16[4 * j4 + 0] += v * w.x; o16[4 * j4 + 1] += v * w.y;
                o16[4 * j4 + 2] += v * w.z; o16[4 * j4 + 3] += v * w.w;
            }
        }
    }
    if (valid) {
        float4* out4 = (float4*)(hh + (size_t)n * 64 + q * 16);
        #pragma unroll
        for (int j4 = 0; j4 < 4; j4++) {
            float4 v; v.x = o16[4 * j4]; v.y = o16[4 * j4 + 1];
            v.z = o16[4 * j4 + 2]; v.w = o16[4 * j4 + 3];
            out4[j4] = v;
        }
    }

    // ---- fused pre emission for next layer (uniform branch) ----
    if (emit_pre) {
        __syncthreads();                 // all fp32-tile reads done
        uint_t* tileh = (uint_t*)tile;
        const int swz = ni & 31;
        #pragma unroll
        for (int p = 0; p < 8; p++)
            tileh[ni * 32 + ((q * 8 + p) ^ swz)] = h2u(pkrtz(o16[2 * p], o16[2 * p + 1]));
        __syncthreads();

        float aR[16], aC[16];
        #pragma unroll
        for (int j = 0; j < 16; j++) { aR[j] = sB1n[q * 16 + j]; aC[j] = 0.f; }
        #pragma unroll 8
        for (int kp = 0; kp < 32; kp++) {
            const half2v hp = u2h(tileh[ni * 32 + (kp ^ swz)]);
            const uint4* wr = (const uint4*)&sW1np[kp * 64 + q * 16];
            const uint4* wc = (const uint4*)&sW1np[(32 + kp) * 64 + q * 16];
            #pragma unroll
            for (int j4 = 0; j4 < 4; j4++) {
                const uint4 a = wr[j4], b = wc[j4];
                aR[4*j4+0] = dot2h(hp, a.x, aR[4*j4+0]);
                aR[4*j4+1] = dot2h(hp, a.y, aR[4*j4+1]);
                aR[4*j4+2] = dot2h(hp, a.z, aR[4*j4+2]);
                aR[4*j4+3] = dot2h(hp, a.w, aR[4*j4+3]);
                aC[4*j4+0] = dot2h(hp, b.x, aC[4*j4+0]);
                aC[4*j4+1] = dot2h(hp, b.y, aC[4*j4+1]);
                aC[4*j4+2] = dot2h(hp, b.z, aC[4*j4+2]);
                aC[4*j4+3] = dot2h(hp, b.w, aC[4*j4+3]);
            }
        }
        if (valid) {
            uint4 o0, o1;
            o0.x = h2u(pkrtz(aR[0],  aR[1]));  o0.y = h2u(pkrtz(aR[2],  aR[3]));
            o0.z = h2u(pkrtz(aR[4],  aR[5]));  o0.w = h2u(pkrtz(aR[6],  aR[7]));
            o1.x = h2u(pkrtz(aR[8],  aR[9]));  o1.y = h2u(pkrtz(aR[10], aR[11]));
            o1.z = h2u(pkrtz(aR[12], aR[13])); o1.w = h2u(pkrtz(aR[14], aR[15]));
            uint4* dst = (uint4*)(preR + (size_t)n * 32 + q * 8);
            dst[0] = o0; dst[1] = o1;
            o0.x = h2u(pkrtz(aC[0],  aC[1]));  o0.y = h2u(pkrtz(aC[2],  aC[3]));
            o0.z = h2u(pkrtz(aC[4],  aC[5]));  o0.w = h2u(pkrtz(aC[6],  aC[7]));
            o1.x = h2u(pkrtz(aC[8],  aC[9]));  o1.y = h2u(pkrtz(aC[10], aC[11]));
            o1.z = h2u(pkrtz(aC[12], aC[13])); o1.w = h2u(pkrtz(aC[14], aC[15]));
            dst = (uint4*)(preC + (size_t)n * 32 + q * 8);
            dst[0] = o0; dst[1] = o1;
        }
    }
}

// ---- host launch -------------------------------------------------------------
extern "C" void kernel_launch(void* const* d_in, const int* in_sizes, int n_in,
                              void* d_out, int out_size, void* d_ws, size_t ws_size,
                              hipStream_t stream) {
    float* wsf = (float*)d_ws;
    int*   wsi = (int*)(wsf + 1340000);
    uint_t* preR = (uint_t*)(wsi + IOFF_PRER);
    uint_t* preC = (uint_t*)(wsi + IOFF_PREC);
    float* coord = (float*)d_out;
    const int* edges = (const int*)d_in[4];
    const int* rows = edges;
    const int* cols = edges + NE;

    hipMemsetAsync(wsi + IOFF_CNTI, 0, NN * sizeof(int), stream);
    counti_kernel<<<(NE + 255) / 256, 256, 0, stream>>>(rows, wsi + IOFF_CNTI);
    scan_kernel<<<1, 1024, 0, stream>>>(wsi + IOFF_CNTI, wsi + IOFF_OFF, wsi + IOFF_CURSOR);
    scatter_kernel<<<(NE + 255) / 256, 256, 0, stream>>>(rows, wsi + IOFF_CURSOR,
                                                         wsi + IOFF_PERM);

    node_init<<<(NN + 255) / 256, 256, 0, stream>>>(
        (const float*)d_in[0], (const float*)d_in[1], (const float*)d_in[2],
        (const int*)d_in[5], (const float*)d_in[8],
        (const float*)d_in[9],  (const float*)d_in[10],
        (const float*)d_in[11], (const float*)d_in[12],
        (const float*)d_in[13], (const float*)d_in[14],
        (const float*)d_in[6],  (const float*)d_in[7],
        coord, wsf + OFF_FIELD, wsf + OFF_HH);

    // csum+magg zeroed once; node_kernel re-zeroes them each layer
    hipMemsetAsync(wsf + OFF_CSUM, 0, (30000 + 640000) * sizeof(float), stream);

    // layer-0 pre; layers 1..3 get pre from node_kernel's fused epilogue
    pre_kernel<<<NNODEBLK, 256, 0, stream>>>(
        wsf + OFF_HH,
        (const float*)d_in[15], (const float*)d_in[16],
        preR, preC);

    for (int l = 0; l < NL; l++) {
        const int ln = (l + 1 < NL) ? (l + 1) : 0;   // next-layer W1 (unused if last)
        edge_kernel<<<NEBLK, 256, 0, stream>>>(
            rows, cols, wsi + IOFF_PERM,
            coord, (const float*)d_in[3],
            ((const float*)d_in[15]) + l * 8384,
            ((const float*)d_in[17]) + l * 4096, ((const float*)d_in[18]) + l * 64,
            ((const float*)d_in[23]) + l * 4096, ((const float*)d_in[24]) + l * 64,
            ((const float*)d_in[25]) + l * 64,
            preR, preC,
            wsf + OFF_CSUM, wsf + OFF_MAGG);
        node_kernel<<<NNODEBLK, 256, 0, stream>>>(
            ((const float*)d_in[26]) + l * 4096, ((const float*)d_in[27]) + l * 64,
            ((const float*)d_in[28]) + l * 64,   ((const float*)d_in[29]) + l,
            ((const float*)d_in[30]) + l * 4096, ((const float*)d_in[31]) + l * 64,
            ((const float*)d_in[32]) + l * 64,   ((const float*)d_in[33]) + l,
            ((const float*)d_in[19]) + l * 8192, ((const float*)d_in[20]) + l * 64,
            ((const float*)d_in[21]) + l * 4096, ((const float*)d_in[22]) + l * 64,
            ((const float*)d_in[15]) + ln * 8384, ((const float*)d_in[16]) + ln * 64,
            wsf + OFF_CSUM, wsi + IOFF_OFF, (const float*)d_in[2],
            wsf + OFF_FIELD, wsf + OFF_MAGG, coord, wsf + OFF_HH,
            preR, preC, (l + 1 < NL) ? 1 : 0);
    }
}

// Round 14
// 669.130 us; speedup vs baseline: 4.2057x; 1.1909x over previous
//
#include <hip/hip_runtime.h>
#include <hip/hip_bf16.h>

typedef unsigned short ushort_t;
typedef unsigned int uint_t;

#define NN    10000
#define NE    320000
#define NL    4
#define EBLK  64        // edges per block (4 threads per edge)
#define NEBLK 5000      // NE / EBLK exactly
#define NPB   64        // nodes per block in pre_kernel (4 threads per node)
#define NNODEBLK 157    // ceil(NN / NPB)
#define NPB2  16        // nodes per block in node_kernel (16 threads per node)
#define NODEBLK2 625    // NN / NPB2 exactly, no tail

// ---- workspace float offsets -------------------------------------------------
#define OFF_FIELD 0        // 30000
#define OFF_HH    30000    // 640000
#define OFF_CSUM  670000   // 30000  (contiguous with MAGG for one memset)
#define OFF_MAGG  700000   // 640000 -> float end 1340000
// ---- int region (starts at float offset 1340000) ----------------------------
#define IOFF_CNTI   0        // 10000
#define IOFF_OFF    10000    // 10001
#define IOFF_CURSOR 20001    // 10000
#define IOFF_PERM   30001    // 320000
#define IOFF_PRER   350004   // 320000 uints (f16-pair preR; 16B-aligned)
#define IOFF_PREC   670004   // 320000 uints -> int end 990004
// total ws = (1340000 + 990004) * 4 = 9,320,016 B  (ws_size >= 9.4 MB verified r12)

// fast silu: v_rcp_f32 instead of IEEE divide (~1e-7 rel err, VALU-bound paths)
__device__ __forceinline__ float silu(float x) {
    return x * __builtin_amdgcn_rcpf(1.0f + __expf(-x));
}

// ---- f16 pair helpers for v_dot2_f32_f16 (clang builtins use __fp16 V2h) -----
typedef __fp16 half2v __attribute__((ext_vector_type(2)));
__device__ __forceinline__ half2v u2h(uint_t u) {
    union { uint_t u; half2v h; } x; x.u = u; return x.h;
}
__device__ __forceinline__ uint_t h2u(half2v h) {
    union { half2v h; uint_t u; } x; x.h = h; return x.u;
}
__device__ __forceinline__ half2v pkrtz(float a, float b) {
    return __builtin_amdgcn_cvt_pkrtz(a, b);
}
__device__ __forceinline__ float dot2h(half2v a, uint_t w, float c) {
#if __has_builtin(__builtin_amdgcn_fdot2)
    return __builtin_amdgcn_fdot2(a, u2h(w), c, false);
#else
    union { uint_t u; __fp16 h[2]; } x; x.u = w;
    return c + (float)a.x * (float)x.h[0] + (float)a.y * (float)x.h[1];
#endif
}

// ---- CSR build: per-row int counts ------------------------------------------
__global__ __launch_bounds__(256) void counti_kernel(const int* __restrict__ rows,
                                                     int* __restrict__ cnti) {
    const int e = blockIdx.x * 256 + threadIdx.x;
    if (e < NE) {
        int r = rows[e];
        r = ((uint_t)r < (uint_t)NN) ? r : 0;
        atomicAdd(&cnti[r], 1);
    }
}

// ---- CSR build: exclusive scan over 10000 counts (single block) --------------
__global__ __launch_bounds__(1024) void scan_kernel(const int* __restrict__ cnti,
                                                    int* __restrict__ off,
                                                    int* __restrict__ cursor) {
    __shared__ int part[1024];
    const int t = threadIdx.x;
    const int base = t * 10;
    int loc[10];
    int s = 0;
    #pragma unroll
    for (int i = 0; i < 10; i++) {
        const int idx = base + i;
        const int v = (idx < NN) ? cnti[idx] : 0;
        loc[i] = s; s += v;
    }
    part[t] = s;
    __syncthreads();
    const int own = s;
    for (int d = 1; d < 1024; d <<= 1) {
        const int v = (t >= d) ? part[t - d] : 0;
        __syncthreads();
        part[t] += v;
        __syncthreads();
    }
    const int excl = part[t] - own;
    #pragma unroll
    for (int i = 0; i < 10; i++) {
        const int idx = base + i;
        if (idx < NN) { const int o = excl + loc[i]; off[idx] = o; cursor[idx] = o; }
    }
    if (t == 0) off[NN] = NE;
}

// ---- CSR build: scatter edge ids into row-sorted order -----------------------
__global__ __launch_bounds__(256) void scatter_kernel(const int* __restrict__ rows,
                                                      int* __restrict__ cursor,
                                                      int* __restrict__ perm) {
    const int e = blockIdx.x * 256 + threadIdx.x;
    if (e < NE) {
        int r = rows[e];
        r = ((uint_t)r < (uint_t)NN) ? r : 0;
        const int pos = atomicAdd(&cursor[r], 1);
        if ((uint_t)pos < (uint_t)NE) perm[pos] = e;
    }
}

// ---- field network + node embedding + coord init (once per call) ------------
__global__ __launch_bounds__(256) void node_init(
    const float* __restrict__ hsrc, const float* __restrict__ xsrc,
    const float* __restrict__ vsrc, const int* __restrict__ charges,
    const float* __restrict__ cls,
    const float* __restrict__ fW1, const float* __restrict__ fb1,
    const float* __restrict__ fW2, const float* __restrict__ fb2,
    const float* __restrict__ fW3, const float* __restrict__ fb3,
    const float* __restrict__ embW, const float* __restrict__ embb,
    float* __restrict__ coord, float* __restrict__ field, float* __restrict__ hh)
{
    __shared__ float sFW1[704], sFW2[1024], sFW3[96];
    __shared__ float sFB1[32], sFB2[32], sFB3[3], sCLS[32], sEW[64], sEB[64];
    const int t = threadIdx.x;
    for (int i = t; i < 704; i += 256) sFW1[i] = fW1[i];
    for (int i = t; i < 1024; i += 256) sFW2[i] = fW2[i];
    if (t < 96) sFW3[t] = fW3[t];
    if (t < 32) { sFB1[t] = fb1[t]; sFB2[t] = fb2[t]; sCLS[t] = cls[t]; }
    if (t < 3)  sFB3[t] = fb3[t];
    if (t < 64) { sEW[t] = embW[t]; sEB[t] = embb[t]; }
    __syncthreads();

    const int n = blockIdx.x * 256 + t;
    if (n >= NN) return;

    float fin[22];
    #pragma unroll
    for (int d = 0; d < 3; d++) {
        fin[d]     = xsrc[3 * n + d];
        fin[3 + d] = vsrc[3 * n + d];
        coord[3 * n + d] = fin[d];
    }
    int ci = charges[n];
    ci = ((uint_t)ci < 2u) ? ci : 0;
    const int cix = ci * 16;
    #pragma unroll
    for (int k = 0; k < 16; k++) fin[6 + k] = sCLS[cix + k];

    float h1[32];
    #pragma unroll
    for (int j = 0; j < 32; j++) h1[j] = sFB1[j];
    #pragma unroll
    for (int k = 0; k < 22; k++) {
        const float v = fin[k];
        #pragma unroll
        for (int j = 0; j < 32; j++) h1[j] += v * sFW1[k * 32 + j];
    }
    #pragma unroll
    for (int j = 0; j < 32; j++) h1[j] = silu(h1[j]);

    float h2[32];
    #pragma unroll
    for (int j = 0; j < 32; j++) h2[j] = sFB2[j];
    #pragma unroll
    for (int k = 0; k < 32; k++) {
        const float v = h1[k];
        #pragma unroll
        for (int j = 0; j < 32; j++) h2[j] += v * sFW2[k * 32 + j];
    }
    #pragma unroll
    for (int j = 0; j < 32; j++) h2[j] = silu(h2[j]);

    #pragma unroll
    for (int d = 0; d < 3; d++) {
        float s = sFB3[d];
        #pragma unroll
        for (int j = 0; j < 32; j++) s += h2[j] * sFW3[j * 3 + d];
        field[3 * n + d] = s;
    }

    const float hv = hsrc[n];
    #pragma unroll
    for (int j = 0; j < 64; j++) hh[(size_t)n * 64 + j] = hv * sEW[j] + sEB[j];
}

// ---- layer-0 pre kernel: preR[n] = b1 + W1r.hh[n], preC[n] = W1c.hh[n] -------
__global__ __launch_bounds__(256, 4) void pre_kernel(
    const float* __restrict__ hh,
    const float* __restrict__ gEW1, const float* __restrict__ gEB1,
    uint_t* __restrict__ preR, uint_t* __restrict__ preC)
{
    __shared__ __align__(16) uint_t sW1p[4096];   // rows 0..127 f16-paired, 16 KB
    __shared__ float sB1[64];
    const int t = threadIdx.x;
    for (int i = t; i < 1024; i += 256) {          // 64 kp x 16 j4-groups
        const int kp = i >> 4, j4 = i & 15;
        const float4 w0 = ((const float4*)gEW1)[kp * 32 + j4];
        const float4 w1 = ((const float4*)gEW1)[kp * 32 + 16 + j4];
        uint4 u;
        u.x = h2u(pkrtz(w0.x, w1.x)); u.y = h2u(pkrtz(w0.y, w1.y));
        u.z = h2u(pkrtz(w0.z, w1.z)); u.w = h2u(pkrtz(w0.w, w1.w));
        ((uint4*)sW1p)[i] = u;
    }
    if (t < 64) sB1[t] = gEB1[t];
    __syncthreads();

    const int ni = t >> 2, q = t & 3;
    int n = blockIdx.x * NPB + ni;
    const bool valid = (n < NN);
    n = valid ? n : (NN - 1);
    const float4* h4p = (const float4*)(hh + (size_t)n * 64);

    float acc[16];
    #pragma unroll
    for (int j = 0; j < 16; j++) acc[j] = sB1[q * 16 + j];
    #pragma unroll
    for (int kk = 0; kk < 16; kk++) {
        const float4 a = h4p[kk];
        const half2v p0 = pkrtz(a.x, a.y);
        const half2v p1 = pkrtz(a.z, a.w);
        const uint4* w0 = (const uint4*)&sW1p[(2 * kk) * 64 + q * 16];
        const uint4* w1 = (const uint4*)&sW1p[(2 * kk + 1) * 64 + q * 16];
        #pragma unroll
        for (int j4 = 0; j4 < 4; j4++) {
            const uint4 wa = w0[j4], wb = w1[j4];
            acc[4*j4+0] = dot2h(p1, wb.x, dot2h(p0, wa.x, acc[4*j4+0]));
            acc[4*j4+1] = dot2h(p1, wb.y, dot2h(p0, wa.y, acc[4*j4+1]));
            acc[4*j4+2] = dot2h(p1, wb.z, dot2h(p0, wa.z, acc[4*j4+2]));
            acc[4*j4+3] = dot2h(p1, wb.w, dot2h(p0, wa.w, acc[4*j4+3]));
        }
    }
    if (valid) {
        uint4 o0, o1;
        o0.x = h2u(pkrtz(acc[0],  acc[1]));  o0.y = h2u(pkrtz(acc[2],  acc[3]));
        o0.z = h2u(pkrtz(acc[4],  acc[5]));  o0.w = h2u(pkrtz(acc[6],  acc[7]));
        o1.x = h2u(pkrtz(acc[8],  acc[9]));  o1.y = h2u(pkrtz(acc[10], acc[11]));
        o1.z = h2u(pkrtz(acc[12], acc[13])); o1.w = h2u(pkrtz(acc[14], acc[15]));
        uint4* dst = (uint4*)(preR + (size_t)n * 32 + q * 8);
        dst[0] = o0; dst[1] = o1;
    }

    #pragma unroll
    for (int j = 0; j < 16; j++) acc[j] = 0.f;
    #pragma unroll
    for (int kk = 0; kk < 16; kk++) {
        const float4 a = h4p[kk];
        const half2v p0 = pkrtz(a.x, a.y);
        const half2v p1 = pkrtz(a.z, a.w);
        const uint4* w0 = (const uint4*)&sW1p[(32 + 2 * kk) * 64 + q * 16];
        const uint4* w1 = (const uint4*)&sW1p[(33 + 2 * kk) * 64 + q * 16];
        #pragma unroll
        for (int j4 = 0; j4 < 4; j4++) {
            const uint4 wa = w0[j4], wb = w1[j4];
            acc[4*j4+0] = dot2h(p1, wb.x, dot2h(p0, wa.x, acc[4*j4+0]));
            acc[4*j4+1] = dot2h(p1, wb.y, dot2h(p0, wa.y, acc[4*j4+1]));
            acc[4*j4+2] = dot2h(p1, wb.z, dot2h(p0, wa.z, acc[4*j4+2]));
            acc[4*j4+3] = dot2h(p1, wb.w, dot2h(p0, wa.w, acc[4*j4+3]));
        }
    }
    if (valid) {
        uint4 o0, o1;
        o0.x = h2u(pkrtz(acc[0],  acc[1]));  o0.y = h2u(pkrtz(acc[2],  acc[3]));
        o0.z = h2u(pkrtz(acc[4],  acc[5]));  o0.w = h2u(pkrtz(acc[6],  acc[7]));
        o1.x = h2u(pkrtz(acc[8],  acc[9]));  o1.y = h2u(pkrtz(acc[10], acc[11]));
        o1.z = h2u(pkrtz(acc[12], acc[13])); o1.w = h2u(pkrtz(acc[14], acc[15]));
        uint4* dst = (uint4*)(preC + (size_t)n * 32 + q * 8);
        dst[0] = o0; dst[1] = o1;
    }
}

// ---- per-layer edge kernel (byte-identical to round 13: 101us validated) -----
__global__ __launch_bounds__(256, 5) void edge_kernel(
    const int* __restrict__ rows, const int* __restrict__ cols,
    const int* __restrict__ perm,
    const float* __restrict__ coord,
    const float* __restrict__ eattr,
    const float* __restrict__ gEW1,                 // only ext rows 128..130
    const float* __restrict__ gEW2, const float* __restrict__ gEB2,
    const float* __restrict__ gCW1, const float* __restrict__ gCB1,
    const float* __restrict__ gCW2,
    const uint_t* __restrict__ preR, const uint_t* __restrict__ preC,
    float* __restrict__ csum, float* __restrict__ magg)
{
    __shared__ __align__(16) uint_t tileh[EBLK * 32];  // f16-pair activations, 8 KB
    __shared__ __align__(16) uint_t sW2p[2048];        // f16-pair W2, 8 KB
    __shared__ __align__(16) uint_t sCW1p[2048];       // f16-pair cW1, 8 KB
    __shared__ float sExtW[3 * 64];                    // W1 rows 128..130 fp32
    __shared__ float sB2[64], sCB1[64], sCW2v[64];
    __shared__ int   sr[EBLK], sc[EBLK], se[EBLK];
    __shared__ int   segstart[EBLK + 1];
    __shared__ int   snseg;

    const int t = threadIdx.x;
    for (int i = t; i < 512; i += 256) {           // 32 kp x 16 j4-groups
        const int kp = i >> 4, j4 = i & 15;
        const float4 w0 = ((const float4*)gEW2)[kp * 32 + j4];
        const float4 w1 = ((const float4*)gEW2)[kp * 32 + 16 + j4];
        uint4 u;
        u.x = h2u(pkrtz(w0.x, w1.x)); u.y = h2u(pkrtz(w0.y, w1.y));
        u.z = h2u(pkrtz(w0.z, w1.z)); u.w = h2u(pkrtz(w0.w, w1.w));
        ((uint4*)sW2p)[i] = u;
    }
    for (int i = t; i < 512; i += 256) {
        const int kp = i >> 4, j4 = i & 15;
        const float4 w0 = ((const float4*)gCW1)[kp * 32 + j4];
        const float4 w1 = ((const float4*)gCW1)[kp * 32 + 16 + j4];
        uint4 u;
        u.x = h2u(pkrtz(w0.x, w1.x)); u.y = h2u(pkrtz(w0.y, w1.y));
        u.z = h2u(pkrtz(w0.z, w1.z)); u.w = h2u(pkrtz(w0.w, w1.w));
        ((uint4*)sCW1p)[i] = u;
    }
    if (t < 192) sExtW[t] = gEW1[8192 + t];        // rows 128..130
    if (t < 64) { sB2[t] = gEB2[t]; sCB1[t] = gCB1[t]; sCW2v[t] = gCW2[t]; }

    if (t < EBLK) {
        int e = perm[blockIdx.x * EBLK + t];
        e = ((uint_t)e < (uint_t)NE) ? e : 0;
        int r = rows[e], c = cols[e];
        r = ((uint_t)r < (uint_t)NN) ? r : 0;
        c = ((uint_t)c < (uint_t)NN) ? c : 0;
        se[t] = e; sr[t] = r; sc[t] = c;
    }
    __syncthreads();

    if (t < EBLK) {
        const int flag = (t == 0) ? 1 : ((sr[t] != sr[t - 1]) ? 1 : 0);
        int isc = flag;
        #pragma unroll
        for (int d = 1; d < EBLK; d <<= 1) {
            const int up = __shfl_up(isc, d);
            if (t >= d) isc += up;
        }
        if (flag) segstart[isc - 1] = t;
        if (t == EBLK - 1) { snseg = isc; segstart[isc] = EBLK; }
    }
    __syncthreads();
    const int nseg = snseg;

    const int ei = t >> 2;
    const int q  = t & 3;
    const int swz = ei & 31;
    const int r = sr[ei], c = sc[ei], e = se[ei];

    const float dx = coord[3 * r + 0] - coord[3 * c + 0];
    const float dy = coord[3 * r + 1] - coord[3 * c + 1];
    const float dz = coord[3 * r + 2] - coord[3 * c + 2];
    const float radial = dx * dx + dy * dy + dz * dz;
    const float2 ea = ((const float2*)eattr)[e];

    union { uint4 v[2]; uint_t a[8]; } R, C;
    {
        const uint4* pr = (const uint4*)(preR + (size_t)r * 32);
        const uint4* pc = (const uint4*)(preC + (size_t)c * 32);
        R.v[0] = pr[q * 2]; R.v[1] = pr[q * 2 + 1];
        C.v[0] = pc[q * 2]; C.v[1] = pc[q * 2 + 1];
    }
    float acc16[16];
    #pragma unroll
    for (int p = 0; p < 8; p++) {
        const half2v hr = u2h(R.a[p]);
        const half2v hc = u2h(C.a[p]);
        acc16[2 * p]     = (float)hr.x + (float)hc.x;
        acc16[2 * p + 1] = (float)hr.y + (float)hc.y;
    }
    {
        const float ext3[3] = {radial, ea.x, ea.y};
        #pragma unroll
        for (int x = 0; x < 3; x++) {
            const float v = ext3[x];
            const float* w = &sExtW[x * 64 + q * 16];
            #pragma unroll
            for (int j = 0; j < 16; j++) acc16[j] += v * w[j];
        }
    }
    #pragma unroll
    for (int j = 0; j < 16; j++) acc16[j] = silu(acc16[j]);
    #pragma unroll
    for (int p = 0; p < 8; p++)
        tileh[ei * 32 + ((q * 8 + p) ^ swz)] = h2u(pkrtz(acc16[2 * p], acc16[2 * p + 1]));
    __syncthreads();

    float m16[16];
    #pragma unroll
    for (int j = 0; j < 16; j++) m16[j] = sB2[q * 16 + j];
    #pragma unroll 8
    for (int kp = 0; kp < 32; kp++) {
        const half2v hp = u2h(tileh[ei * 32 + (kp ^ swz)]);
        const uint4* w4 = (const uint4*)&sW2p[kp * 64 + q * 16];
        #pragma unroll
        for (int j4 = 0; j4 < 4; j4++) {
            const uint4 w = w4[j4];
            m16[4*j4+0] = dot2h(hp, w.x, m16[4*j4+0]);
            m16[4*j4+1] = dot2h(hp, w.y, m16[4*j4+1]);
            m16[4*j4+2] = dot2h(hp, w.z, m16[4*j4+2]);
            m16[4*j4+3] = dot2h(hp, w.w, m16[4*j4+3]);
        }
    }
    #pragma unroll
    for (int j = 0; j < 16; j++) m16[j] = silu(m16[j]);

    __syncthreads();
    #pragma unroll
    for (int p = 0; p < 8; p++)
        tileh[ei * 32 + ((q * 8 + p) ^ swz)] = h2u(pkrtz(m16[2 * p], m16[2 * p + 1]));
    __syncthreads();

    float ch16[16];
    #pragma unroll
    for (int j = 0; j < 16; j++) ch16[j] = sCB1[q * 16 + j];
    #pragma unroll 8
    for (int kp = 0; kp < 32; kp++) {
        const half2v hp = u2h(tileh[ei * 32 + (kp ^ swz)]);
        const uint4* w4 = (const uint4*)&sCW1p[kp * 64 + q * 16];
        #pragma unroll
        for (int j4 = 0; j4 < 4; j4++) {
            const uint4 w = w4[j4];
            ch16[4*j4+0] = dot2h(hp, w.x, ch16[4*j4+0]);
            ch16[4*j4+1] = dot2h(hp, w.y, ch16[4*j4+1]);
            ch16[4*j4+2] = dot2h(hp, w.z, ch16[4*j4+2]);
            ch16[4*j4+3] = dot2h(hp, w.w, ch16[4*j4+3]);
        }
    }
    float part = 0.f;
    #pragma unroll
    for (int j = 0; j < 16; j++) part += silu(ch16[j]) * sCW2v[q * 16 + j];
    part += __shfl_xor(part, 1);
    part += __shfl_xor(part, 2);
    const float cw = part;

    for (int w = t; w < nseg * 64; w += 256) {
        const int lr2 = w >> 6, cc = w & 63;
        const int p0 = segstart[lr2], p1 = segstart[lr2 + 1];
        const int kp = cc >> 1, hi = cc & 1;
        float s = 0.f;
        for (int p = p0; p < p1; p++) {
            const half2v h = u2h(tileh[p * 32 + (kp ^ (p & 31))]);
            s += hi ? (float)h.y : (float)h.x;
        }
        atomicAdd(&magg[(size_t)sr[p0] * 64 + cc], s);
    }
    __syncthreads();

    float* tf = (float*)tileh;
    if (q < 3) tf[ei * 4 + q] = (q == 0 ? dx : (q == 1 ? dy : dz)) * cw;
    __syncthreads();
    for (int w = t; w < nseg * 3; w += 256) {
        const int lr2 = w / 3, cc = w - 3 * lr2;
        const int p0 = segstart[lr2], p1 = segstart[lr2 + 1];
        float s = 0.f;
        for (int p = p0; p < p1; p++) s += tf[p * 4 + cc];
        atomicAdd(&csum[3 * sr[p0] + cc], s);
    }
}

// ---- per-layer node kernel: 16 threads/node, 4 channels/thread ---------------
// Round-14: the 157-block version was grid-starved (0.6 waves/SIMD, ~87us).
// Now 16 nodes/block, grid 625 (= NN/16 exactly): 4x waves, 4x less work per
// thread. hh+magg staged per-node in LDS (stride 136 floats: node bases spread
// across banks; intra-node reads broadcast). vw/gw butterfly = 4-step shfl_xor
// within the node's 16 lanes (never crosses a node: 16 lanes = contiguous).
// LDS: sNW1p 16K + sW1np 16K + tile 8.7K + biases ~0.8K ~= 42 KB -> 3 blk/CU
// (grid-limited at ~2.4 anyway). Fused next-layer pre emission kept from r13.
__global__ __launch_bounds__(256, 3) void node_kernel(
    const float* __restrict__ gVW1, const float* __restrict__ gVB1,
    const float* __restrict__ gVW2, const float* __restrict__ gVB2,
    const float* __restrict__ gGW1, const float* __restrict__ gGB1,
    const float* __restrict__ gGW2, const float* __restrict__ gGB2,
    const float* __restrict__ gNW1, const float* __restrict__ gNB1,
    const float* __restrict__ gNW2, const float* __restrict__ gNB2,
    const float* __restrict__ gW1n, const float* __restrict__ gB1n,
    float* __restrict__ csum, const int* __restrict__ off,
    const float* __restrict__ vsrc, const float* __restrict__ field,
    float* __restrict__ magg,
    float* __restrict__ coord, float* __restrict__ hh,
    uint_t* __restrict__ preR, uint_t* __restrict__ preC, const int emit_pre)
{
    __shared__ __align__(16) uint_t sNW1p[4096];       // NW1 f16 pairs, 16 KB
    __shared__ __align__(16) uint_t sW1np[4096];       // next-layer W1 f16, 16 KB
    __shared__ __align__(16) float tile[NPB2 * 136];   // hh[0..63], magg[68..131]
    __shared__ float sNB1[64], sNB2[64], sB1n[64];

    const int t = threadIdx.x;
    for (int i = t; i < 1024; i += 256) {
        const int kp = i >> 4, j4 = i & 15;
        const float4 w0 = ((const float4*)gNW1)[kp * 32 + j4];
        const float4 w1 = ((const float4*)gNW1)[kp * 32 + 16 + j4];
        uint4 u;
        u.x = h2u(pkrtz(w0.x, w1.x)); u.y = h2u(pkrtz(w0.y, w1.y));
        u.z = h2u(pkrtz(w0.z, w1.z)); u.w = h2u(pkrtz(w0.w, w1.w));
        ((uint4*)sNW1p)[i] = u;
    }
    for (int i = t; i < 1024; i += 256) {
        const int kp = i >> 4, j4 = i & 15;
        const float4 w0 = ((const float4*)gW1n)[kp * 32 + j4];
        const float4 w1 = ((const float4*)gW1n)[kp * 32 + 16 + j4];
        uint4 u;
        u.x = h2u(pkrtz(w0.x, w1.x)); u.y = h2u(pkrtz(w0.y, w1.y));
        u.z = h2u(pkrtz(w0.z, w1.z)); u.w = h2u(pkrtz(w0.w, w1.w));
        ((uint4*)sW1np)[i] = u;
    }
    if (t < 64) { sNB1[t] = gNB1[t]; sNB2[t] = gNB2[t]; sB1n[t] = gB1n[t]; }

    const int ni = t >> 4;          // node in block (0..15)
    const int q  = t & 15;          // channel group (4 ch)
    const int n = blockIdx.x * NPB2 + ni;    // grid*NPB2 = 10000 exactly
    float* T = &tile[ni * 136];

    // stage hh + magg into tile
    ((float4*)T)[q]        = ((const float4*)(hh + (size_t)n * 64))[q];
    ((float4*)(T + 68))[q] = ((const float4*)(magg + (size_t)n * 64))[q];
    __syncthreads();

    // ---- vw = silu(hh @ vW1 + vb1) @ vW2 + vb2 ----
    float a4[4];
    {
        const float4 b = ((const float4*)gVB1)[q];
        a4[0] = b.x; a4[1] = b.y; a4[2] = b.z; a4[3] = b.w;
    }
    #pragma unroll 4
    for (int kk = 0; kk < 16; kk++) {
        const float4 h4 = ((const float4*)T)[kk];
        const float hv[4] = {h4.x, h4.y, h4.z, h4.w};
        #pragma unroll
        for (int u = 0; u < 4; u++) {
            const float v = hv[u];
            const float4 w = ((const float4*)(gVW1 + (kk * 4 + u) * 64))[q];
            a4[0] += v * w.x; a4[1] += v * w.y; a4[2] += v * w.z; a4[3] += v * w.w;
        }
    }
    float part;
    {
        const float4 w2 = ((const float4*)gVW2)[q];
        part = silu(a4[0]) * w2.x + silu(a4[1]) * w2.y
             + silu(a4[2]) * w2.z + silu(a4[3]) * w2.w;
    }
    part += __shfl_xor(part, 1);
    part += __shfl_xor(part, 2);
    part += __shfl_xor(part, 4);
    part += __shfl_xor(part, 8);
    const float vw = part + gVB2[0];

    // ---- gw (same structure) ----
    {
        const float4 b = ((const float4*)gGB1)[q];
        a4[0] = b.x; a4[1] = b.y; a4[2] = b.z; a4[3] = b.w;
    }
    #pragma unroll 4
    for (int kk = 0; kk < 16; kk++) {
        const float4 h4 = ((const float4*)T)[kk];
        const float hv[4] = {h4.x, h4.y, h4.z, h4.w};
        #pragma unroll
        for (int u = 0; u < 4; u++) {
            const float v = hv[u];
            const float4 w = ((const float4*)(gGW1 + (kk * 4 + u) * 64))[q];
            a4[0] += v * w.x; a4[1] += v * w.y; a4[2] += v * w.z; a4[3] += v * w.w;
        }
    }
    {
        const float4 w2 = ((const float4*)gGW2)[q];
        part = silu(a4[0]) * w2.x + silu(a4[1]) * w2.y
             + silu(a4[2]) * w2.z + silu(a4[3]) * w2.w;
    }
    part += __shfl_xor(part, 1);
    part += __shfl_xor(part, 2);
    part += __shfl_xor(part, 4);
    part += __shfl_xor(part, 8);
    const float gw = part + gGB2[0];

    // ---- coord update (one thread per node) ----
    if (q == 0) {
        const float cn = fmaxf((float)(off[n + 1] - off[n]), 1.0f);
        #pragma unroll
        for (int d = 0; d < 3; d++)
            coord[3 * n + d] += csum[3 * n + d] / cn
                              + vw * vsrc[3 * n + d]
                              + gw * field[3 * n + d];
    }

    // ---- node MLP hidden: a4 = silu([hh, magg] @ NW1[:, q*4..+4] + b1) ----
    {
        const float4 b = ((const float4*)sNB1)[q];
        a4[0] = b.x; a4[1] = b.y; a4[2] = b.z; a4[3] = b.w;
    }
    #pragma unroll 8
    for (int kp = 0; kp < 32; kp++) {             // hh half
        const half2v p = pkrtz(T[2 * kp], T[2 * kp + 1]);
        const uint4 w = *(const uint4*)&sNW1p[kp * 64 + q * 4];
        a4[0] = dot2h(p, w.x, a4[0]); a4[1] = dot2h(p, w.y, a4[1]);
        a4[2] = dot2h(p, w.z, a4[2]); a4[3] = dot2h(p, w.w, a4[3]);
    }
    #pragma unroll 8
    for (int kp = 0; kp < 32; kp++) {             // magg half
        const half2v p = pkrtz(T[68 + 2 * kp], T[68 + 2 * kp + 1]);
        const uint4 w = *(const uint4*)&sNW1p[(32 + kp) * 64 + q * 4];
        a4[0] = dot2h(p, w.x, a4[0]); a4[1] = dot2h(p, w.y, a4[1]);
        a4[2] = dot2h(p, w.z, a4[2]); a4[3] = dot2h(p, w.w, a4[3]);
    }
    #pragma unroll
    for (int j = 0; j < 4; j++) a4[j] = silu(a4[j]);

    // ---- exchange hidden through tile (overwrite hh slots; intra-wave) ----
    __syncthreads();
    {
        float4 v; v.x = a4[0]; v.y = a4[1]; v.z = a4[2]; v.w = a4[3];
        ((float4*)T)[q] = v;
    }
    __syncthreads();

    // ---- zero magg/csum for next layer (magg reads completed above) ----
    {
        float4 z; z.x = z.y = z.z = z.w = 0.f;
        ((float4*)(magg + (size_t)n * 64))[q] = z;
        if (q == 0) { csum[3 * n] = 0.f; csum[3 * n + 1] = 0.f; csum[3 * n + 2] = 0.f; }
    }

    // ---- output: o4 = hid64 @ NW2[:, q*4..+4] + b2 ----
    float o4[4];
    {
        const float4 b = ((const float4*)sNB2)[q];
        o4[0] = b.x; o4[1] = b.y; o4[2] = b.z; o4[3] = b.w;
    }
    #pragma unroll 4
    for (int kk = 0; kk < 16; kk++) {
        const float4 h4 = ((const float4*)T)[kk];
        const float hv[4] = {h4.x, h4.y, h4.z, h4.w};
        #pragma unroll
        for (int u = 0; u < 4; u++) {
            const float v = hv[u];
            const float4 w = ((const float4*)(gNW2 + (kk * 4 + u) * 64))[q];
            o4[0] += v * w.x; o4[1] += v * w.y; o4[2] += v * w.z; o4[3] += v * w.w;
        }
    }
    {
        float4 v; v.x = o4[0]; v.y = o4[1]; v.z = o4[2]; v.w = o4[3];
        ((float4*)(hh + (size_t)n * 64))[q] = v;
    }

    // ---- fused pre emission for next layer (uniform branch) ----
    if (emit_pre) {
        __syncthreads();                 // hidden-tile reads done
        {
            float4 v; v.x = o4[0]; v.y = o4[1]; v.z = o4[2]; v.w = o4[3];
            ((float4*)T)[q] = v;         // tile now holds new hh
        }
        __syncthreads();

        float aR[4], aC[4];
        {
            const float4 b = ((const float4*)sB1n)[q];
            aR[0] = b.x; aR[1] = b.y; aR[2] = b.z; aR[3] = b.w;
            aC[0] = aC[1] = aC[2] = aC[3] = 0.f;
        }
        #pragma unroll 8
        for (int kp = 0; kp < 32; kp++) {
            const half2v p = pkrtz(T[2 * kp], T[2 * kp + 1]);
            const uint4 wr = *(const uint4*)&sW1np[kp * 64 + q * 4];
            const uint4 wc = *(const uint4*)&sW1np[(32 + kp) * 64 + q * 4];
            aR[0] = dot2h(p, wr.x, aR[0]); aR[1] = dot2h(p, wr.y, aR[1]);
            aR[2] = dot2h(p, wr.z, aR[2]); aR[3] = dot2h(p, wr.w, aR[3]);
            aC[0] = dot2h(p, wc.x, aC[0]); aC[1] = dot2h(p, wc.y, aC[1]);
            aC[2] = dot2h(p, wc.z, aC[2]); aC[3] = dot2h(p, wc.w, aC[3]);
        }
        uint2 oR, oC;
        oR.x = h2u(pkrtz(aR[0], aR[1])); oR.y = h2u(pkrtz(aR[2], aR[3]));
        oC.x = h2u(pkrtz(aC[0], aC[1])); oC.y = h2u(pkrtz(aC[2], aC[3]));
        *(uint2*)(preR + (size_t)n * 32 + q * 2) = oR;
        *(uint2*)(preC + (size_t)n * 32 + q * 2) = oC;
    }
}

// ---- host launch -------------------------------------------------------------
extern "C" void kernel_launch(void* const* d_in, const int* in_sizes, int n_in,
                              void* d_out, int out_size, void* d_ws, size_t ws_size,
                              hipStream_t stream) {
    float* wsf = (float*)d_ws;
    int*   wsi = (int*)(wsf + 1340000);
    uint_t* preR = (uint_t*)(wsi + IOFF_PRER);
    uint_t* preC = (uint_t*)(wsi + IOFF_PREC);
    float* coord = (float*)d_out;
    const int* edges = (const int*)d_in[4];
    const int* rows = edges;
    const int* cols = edges + NE;

    hipMemsetAsync(wsi + IOFF_CNTI, 0, NN * sizeof(int), stream);
    counti_kernel<<<(NE + 255) / 256, 256, 0, stream>>>(rows, wsi + IOFF_CNTI);
    scan_kernel<<<1, 1024, 0, stream>>>(wsi + IOFF_CNTI, wsi + IOFF_OFF, wsi + IOFF_CURSOR);
    scatter_kernel<<<(NE + 255) / 256, 256, 0, stream>>>(rows, wsi + IOFF_CURSOR,
                                                         wsi + IOFF_PERM);

    node_init<<<(NN + 255) / 256, 256, 0, stream>>>(
        (const float*)d_in[0], (const float*)d_in[1], (const float*)d_in[2],
        (const int*)d_in[5], (const float*)d_in[8],
        (const float*)d_in[9],  (const float*)d_in[10],
        (const float*)d_in[11], (const float*)d_in[12],
        (const float*)d_in[13], (const float*)d_in[14],
        (const float*)d_in[6],  (const float*)d_in[7],
        coord, wsf + OFF_FIELD, wsf + OFF_HH);

    // csum+magg zeroed once; node_kernel re-zeroes them each layer
    hipMemsetAsync(wsf + OFF_CSUM, 0, (30000 + 640000) * sizeof(float), stream);

    // layer-0 pre; layers 1..3 get pre from node_kernel's fused epilogue
    pre_kernel<<<NNODEBLK, 256, 0, stream>>>(
        wsf + OFF_HH,
        (const float*)d_in[15], (const float*)d_in[16],
        preR, preC);

    for (int l = 0; l < NL; l++) {
        const int ln = (l + 1 < NL) ? (l + 1) : 0;   // next-layer W1 (unused if last)
        edge_kernel<<<NEBLK, 256, 0, stream>>>(
            rows, cols, wsi + IOFF_PERM,
            coord, (const float*)d_in[3],
            ((const float*)d_in[15]) + l * 8384,
            ((const float*)d_in[17]) + l * 4096, ((const float*)d_in[18]) + l * 64,
            ((const float*)d_in[23]) + l * 4096, ((const float*)d_in[24]) + l * 64,
            ((const float*)d_in[25]) + l * 64,
            preR, preC,
            wsf + OFF_CSUM, wsf + OFF_MAGG);
        node_kernel<<<NODEBLK2, 256, 0, stream>>>(
            ((const float*)d_in[26]) + l * 4096, ((const float*)d_in[27]) + l * 64,
            ((const float*)d_in[28]) + l * 64,   ((const float*)d_in[29]) + l,
            ((const float*)d_in[30]) + l * 4096, ((const float*)d_in[31]) + l * 64,
            ((const float*)d_in[32]) + l * 64,   ((const float*)d_in[33]) + l,
            ((const float*)d_in[19]) + l * 8192, ((const float*)d_in[20]) + l * 64,
            ((const float*)d_in[21]) + l * 4096, ((const float*)d_in[22]) + l * 64,
            ((const float*)d_in[15]) + ln * 8384, ((const float*)d_in[16]) + ln * 64,
            wsf + OFF_CSUM, wsi + IOFF_OFF, (const float*)d_in[2],
            wsf + OFF_FIELD, wsf + OFF_MAGG, coord, wsf + OFF_HH,
            preR, preC, (l + 1 < NL) ? 1 : 0);
    }
}

// Round 15
// 648.175 us; speedup vs baseline: 4.3416x; 1.0323x over previous
//
#include <hip/hip_runtime.h>
#include <hip/hip_bf16.h>

typedef unsigned short ushort_t;
typedef unsigned int uint_t;

#define NN    10000
#define NE    320000
#define NL    4
#define EBLK  64        // edges per block (4 threads per edge)
#define NEBLK 5000      // NE / EBLK exactly
#define NPB   64        // nodes per block in pre_kernel (4 threads per node)
#define NNODEBLK 157    // ceil(NN / NPB)
#define NPB2  16        // nodes per block in node_kernel (16 threads per node)
#define NODEBLK2 625    // NN / NPB2 exactly, no tail

// ---- workspace float offsets -------------------------------------------------
#define OFF_FIELD 0        // 30000
#define OFF_HH    30000    // 640000
#define OFF_CSUM  670000   // 30000  (contiguous with MAGG for one memset)
#define OFF_MAGG  700000   // 640000 -> float end 1340000
// ---- int region (starts at float offset 1340000) ----------------------------
#define IOFF_CNTI   0        // 10000
#define IOFF_OFF    10000    // 10001
#define IOFF_CURSOR 20001    // 10000
#define IOFF_PERM   30001    // 320000
#define IOFF_PRER   350004   // 320000 uints (f16-pair preR; 16B-aligned)
#define IOFF_PREC   670004   // 320000 uints -> int end 990004
// total ws = (1340000 + 990004) * 4 = 9,320,016 B  (ws_size >= 9.4 MB verified r12)

// fast silu: v_rcp_f32 instead of IEEE divide (~1e-7 rel err, VALU-bound paths)
__device__ __forceinline__ float silu(float x) {
    return x * __builtin_amdgcn_rcpf(1.0f + __expf(-x));
}

// ---- f16 pair helpers for v_dot2_f32_f16 (clang builtins use __fp16 V2h) -----
typedef __fp16 half2v __attribute__((ext_vector_type(2)));
__device__ __forceinline__ half2v u2h(uint_t u) {
    union { uint_t u; half2v h; } x; x.u = u; return x.h;
}
__device__ __forceinline__ uint_t h2u(half2v h) {
    union { half2v h; uint_t u; } x; x.h = h; return x.u;
}
__device__ __forceinline__ half2v pkrtz(float a, float b) {
    return __builtin_amdgcn_cvt_pkrtz(a, b);
}
__device__ __forceinline__ float dot2h(half2v a, uint_t w, float c) {
#if __has_builtin(__builtin_amdgcn_fdot2)
    return __builtin_amdgcn_fdot2(a, u2h(w), c, false);
#else
    union { uint_t u; __fp16 h[2]; } x; x.u = w;
    return c + (float)a.x * (float)x.h[0] + (float)a.y * (float)x.h[1];
#endif
}

// ---- CSR build: per-row int counts ------------------------------------------
__global__ __launch_bounds__(256) void counti_kernel(const int* __restrict__ rows,
                                                     int* __restrict__ cnti) {
    const int e = blockIdx.x * 256 + threadIdx.x;
    if (e < NE) {
        int r = rows[e];
        r = ((uint_t)r < (uint_t)NN) ? r : 0;
        atomicAdd(&cnti[r], 1);
    }
}

// ---- CSR build: exclusive scan over 10000 counts (single block) --------------
__global__ __launch_bounds__(1024) void scan_kernel(const int* __restrict__ cnti,
                                                    int* __restrict__ off,
                                                    int* __restrict__ cursor) {
    __shared__ int part[1024];
    const int t = threadIdx.x;
    const int base = t * 10;
    int loc[10];
    int s = 0;
    #pragma unroll
    for (int i = 0; i < 10; i++) {
        const int idx = base + i;
        const int v = (idx < NN) ? cnti[idx] : 0;
        loc[i] = s; s += v;
    }
    part[t] = s;
    __syncthreads();
    const int own = s;
    for (int d = 1; d < 1024; d <<= 1) {
        const int v = (t >= d) ? part[t - d] : 0;
        __syncthreads();
        part[t] += v;
        __syncthreads();
    }
    const int excl = part[t] - own;
    #pragma unroll
    for (int i = 0; i < 10; i++) {
        const int idx = base + i;
        if (idx < NN) { const int o = excl + loc[i]; off[idx] = o; cursor[idx] = o; }
    }
    if (t == 0) off[NN] = NE;
}

// ---- CSR build: scatter edge ids into row-sorted order -----------------------
__global__ __launch_bounds__(256) void scatter_kernel(const int* __restrict__ rows,
                                                      int* __restrict__ cursor,
                                                      int* __restrict__ perm) {
    const int e = blockIdx.x * 256 + threadIdx.x;
    if (e < NE) {
        int r = rows[e];
        r = ((uint_t)r < (uint_t)NN) ? r : 0;
        const int pos = atomicAdd(&cursor[r], 1);
        if ((uint_t)pos < (uint_t)NE) perm[pos] = e;
    }
}

// ---- field network + node embedding + coord init (once per call) ------------
__global__ __launch_bounds__(256) void node_init(
    const float* __restrict__ hsrc, const float* __restrict__ xsrc,
    const float* __restrict__ vsrc, const int* __restrict__ charges,
    const float* __restrict__ cls,
    const float* __restrict__ fW1, const float* __restrict__ fb1,
    const float* __restrict__ fW2, const float* __restrict__ fb2,
    const float* __restrict__ fW3, const float* __restrict__ fb3,
    const float* __restrict__ embW, const float* __restrict__ embb,
    float* __restrict__ coord, float* __restrict__ field, float* __restrict__ hh)
{
    __shared__ float sFW1[704], sFW2[1024], sFW3[96];
    __shared__ float sFB1[32], sFB2[32], sFB3[3], sCLS[32], sEW[64], sEB[64];
    const int t = threadIdx.x;
    for (int i = t; i < 704; i += 256) sFW1[i] = fW1[i];
    for (int i = t; i < 1024; i += 256) sFW2[i] = fW2[i];
    if (t < 96) sFW3[t] = fW3[t];
    if (t < 32) { sFB1[t] = fb1[t]; sFB2[t] = fb2[t]; sCLS[t] = cls[t]; }
    if (t < 3)  sFB3[t] = fb3[t];
    if (t < 64) { sEW[t] = embW[t]; sEB[t] = embb[t]; }
    __syncthreads();

    const int n = blockIdx.x * 256 + t;
    if (n >= NN) return;

    float fin[22];
    #pragma unroll
    for (int d = 0; d < 3; d++) {
        fin[d]     = xsrc[3 * n + d];
        fin[3 + d] = vsrc[3 * n + d];
        coord[3 * n + d] = fin[d];
    }
    int ci = charges[n];
    ci = ((uint_t)ci < 2u) ? ci : 0;
    const int cix = ci * 16;
    #pragma unroll
    for (int k = 0; k < 16; k++) fin[6 + k] = sCLS[cix + k];

    float h1[32];
    #pragma unroll
    for (int j = 0; j < 32; j++) h1[j] = sFB1[j];
    #pragma unroll
    for (int k = 0; k < 22; k++) {
        const float v = fin[k];
        #pragma unroll
        for (int j = 0; j < 32; j++) h1[j] += v * sFW1[k * 32 + j];
    }
    #pragma unroll
    for (int j = 0; j < 32; j++) h1[j] = silu(h1[j]);

    float h2[32];
    #pragma unroll
    for (int j = 0; j < 32; j++) h2[j] = sFB2[j];
    #pragma unroll
    for (int k = 0; k < 32; k++) {
        const float v = h1[k];
        #pragma unroll
        for (int j = 0; j < 32; j++) h2[j] += v * sFW2[k * 32 + j];
    }
    #pragma unroll
    for (int j = 0; j < 32; j++) h2[j] = silu(h2[j]);

    #pragma unroll
    for (int d = 0; d < 3; d++) {
        float s = sFB3[d];
        #pragma unroll
        for (int j = 0; j < 32; j++) s += h2[j] * sFW3[j * 3 + d];
        field[3 * n + d] = s;
    }

    const float hv = hsrc[n];
    #pragma unroll
    for (int j = 0; j < 64; j++) hh[(size_t)n * 64 + j] = hv * sEW[j] + sEB[j];
}

// ---- layer-0 pre kernel: preR[n] = b1 + W1r.hh[n], preC[n] = W1c.hh[n] -------
__global__ __launch_bounds__(256, 4) void pre_kernel(
    const float* __restrict__ hh,
    const float* __restrict__ gEW1, const float* __restrict__ gEB1,
    uint_t* __restrict__ preR, uint_t* __restrict__ preC)
{
    __shared__ __align__(16) uint_t sW1p[4096];   // rows 0..127 f16-paired, 16 KB
    __shared__ float sB1[64];
    const int t = threadIdx.x;
    for (int i = t; i < 1024; i += 256) {          // 64 kp x 16 j4-groups
        const int kp = i >> 4, j4 = i & 15;
        const float4 w0 = ((const float4*)gEW1)[kp * 32 + j4];
        const float4 w1 = ((const float4*)gEW1)[kp * 32 + 16 + j4];
        uint4 u;
        u.x = h2u(pkrtz(w0.x, w1.x)); u.y = h2u(pkrtz(w0.y, w1.y));
        u.z = h2u(pkrtz(w0.z, w1.z)); u.w = h2u(pkrtz(w0.w, w1.w));
        ((uint4*)sW1p)[i] = u;
    }
    if (t < 64) sB1[t] = gEB1[t];
    __syncthreads();

    const int ni = t >> 2, q = t & 3;
    int n = blockIdx.x * NPB + ni;
    const bool valid = (n < NN);
    n = valid ? n : (NN - 1);
    const float4* h4p = (const float4*)(hh + (size_t)n * 64);

    float acc[16];
    #pragma unroll
    for (int j = 0; j < 16; j++) acc[j] = sB1[q * 16 + j];
    #pragma unroll
    for (int kk = 0; kk < 16; kk++) {
        const float4 a = h4p[kk];
        const half2v p0 = pkrtz(a.x, a.y);
        const half2v p1 = pkrtz(a.z, a.w);
        const uint4* w0 = (const uint4*)&sW1p[(2 * kk) * 64 + q * 16];
        const uint4* w1 = (const uint4*)&sW1p[(2 * kk + 1) * 64 + q * 16];
        #pragma unroll
        for (int j4 = 0; j4 < 4; j4++) {
            const uint4 wa = w0[j4], wb = w1[j4];
            acc[4*j4+0] = dot2h(p1, wb.x, dot2h(p0, wa.x, acc[4*j4+0]));
            acc[4*j4+1] = dot2h(p1, wb.y, dot2h(p0, wa.y, acc[4*j4+1]));
            acc[4*j4+2] = dot2h(p1, wb.z, dot2h(p0, wa.z, acc[4*j4+2]));
            acc[4*j4+3] = dot2h(p1, wb.w, dot2h(p0, wa.w, acc[4*j4+3]));
        }
    }
    if (valid) {
        uint4 o0, o1;
        o0.x = h2u(pkrtz(acc[0],  acc[1]));  o0.y = h2u(pkrtz(acc[2],  acc[3]));
        o0.z = h2u(pkrtz(acc[4],  acc[5]));  o0.w = h2u(pkrtz(acc[6],  acc[7]));
        o1.x = h2u(pkrtz(acc[8],  acc[9]));  o1.y = h2u(pkrtz(acc[10], acc[11]));
        o1.z = h2u(pkrtz(acc[12], acc[13])); o1.w = h2u(pkrtz(acc[14], acc[15]));
        uint4* dst = (uint4*)(preR + (size_t)n * 32 + q * 8);
        dst[0] = o0; dst[1] = o1;
    }

    #pragma unroll
    for (int j = 0; j < 16; j++) acc[j] = 0.f;
    #pragma unroll
    for (int kk = 0; kk < 16; kk++) {
        const float4 a = h4p[kk];
        const half2v p0 = pkrtz(a.x, a.y);
        const half2v p1 = pkrtz(a.z, a.w);
        const uint4* w0 = (const uint4*)&sW1p[(32 + 2 * kk) * 64 + q * 16];
        const uint4* w1 = (const uint4*)&sW1p[(33 + 2 * kk) * 64 + q * 16];
        #pragma unroll
        for (int j4 = 0; j4 < 4; j4++) {
            const uint4 wa = w0[j4], wb = w1[j4];
            acc[4*j4+0] = dot2h(p1, wb.x, dot2h(p0, wa.x, acc[4*j4+0]));
            acc[4*j4+1] = dot2h(p1, wb.y, dot2h(p0, wa.y, acc[4*j4+1]));
            acc[4*j4+2] = dot2h(p1, wb.z, dot2h(p0, wa.z, acc[4*j4+2]));
            acc[4*j4+3] = dot2h(p1, wb.w, dot2h(p0, wa.w, acc[4*j4+3]));
        }
    }
    if (valid) {
        uint4 o0, o1;
        o0.x = h2u(pkrtz(acc[0],  acc[1]));  o0.y = h2u(pkrtz(acc[2],  acc[3]));
        o0.z = h2u(pkrtz(acc[4],  acc[5]));  o0.w = h2u(pkrtz(acc[6],  acc[7]));
        o1.x = h2u(pkrtz(acc[8],  acc[9]));  o1.y = h2u(pkrtz(acc[10], acc[11]));
        o1.z = h2u(pkrtz(acc[12], acc[13])); o1.w = h2u(pkrtz(acc[14], acc[15]));
        uint4* dst = (uint4*)(preC + (size_t)n * 32 + q * 8);
        dst[0] = o0; dst[1] = o1;
    }
}

// ---- per-layer edge kernel (byte-identical to rounds 13/14: 101us validated) -
__global__ __launch_bounds__(256, 5) void edge_kernel(
    const int* __restrict__ rows, const int* __restrict__ cols,
    const int* __restrict__ perm,
    const float* __restrict__ coord,
    const float* __restrict__ eattr,
    const float* __restrict__ gEW1,                 // only ext rows 128..130
    const float* __restrict__ gEW2, const float* __restrict__ gEB2,
    const float* __restrict__ gCW1, const float* __restrict__ gCB1,
    const float* __restrict__ gCW2,
    const uint_t* __restrict__ preR, const uint_t* __restrict__ preC,
    float* __restrict__ csum, float* __restrict__ magg)
{
    __shared__ __align__(16) uint_t tileh[EBLK * 32];  // f16-pair activations, 8 KB
    __shared__ __align__(16) uint_t sW2p[2048];        // f16-pair W2, 8 KB
    __shared__ __align__(16) uint_t sCW1p[2048];       // f16-pair cW1, 8 KB
    __shared__ float sExtW[3 * 64];                    // W1 rows 128..130 fp32
    __shared__ float sB2[64], sCB1[64], sCW2v[64];
    __shared__ int   sr[EBLK], sc[EBLK], se[EBLK];
    __shared__ int   segstart[EBLK + 1];
    __shared__ int   snseg;

    const int t = threadIdx.x;
    for (int i = t; i < 512; i += 256) {           // 32 kp x 16 j4-groups
        const int kp = i >> 4, j4 = i & 15;
        const float4 w0 = ((const float4*)gEW2)[kp * 32 + j4];
        const float4 w1 = ((const float4*)gEW2)[kp * 32 + 16 + j4];
        uint4 u;
        u.x = h2u(pkrtz(w0.x, w1.x)); u.y = h2u(pkrtz(w0.y, w1.y));
        u.z = h2u(pkrtz(w0.z, w1.z)); u.w = h2u(pkrtz(w0.w, w1.w));
        ((uint4*)sW2p)[i] = u;
    }
    for (int i = t; i < 512; i += 256) {
        const int kp = i >> 4, j4 = i & 15;
        const float4 w0 = ((const float4*)gCW1)[kp * 32 + j4];
        const float4 w1 = ((const float4*)gCW1)[kp * 32 + 16 + j4];
        uint4 u;
        u.x = h2u(pkrtz(w0.x, w1.x)); u.y = h2u(pkrtz(w0.y, w1.y));
        u.z = h2u(pkrtz(w0.z, w1.z)); u.w = h2u(pkrtz(w0.w, w1.w));
        ((uint4*)sCW1p)[i] = u;
    }
    if (t < 192) sExtW[t] = gEW1[8192 + t];        // rows 128..130
    if (t < 64) { sB2[t] = gEB2[t]; sCB1[t] = gCB1[t]; sCW2v[t] = gCW2[t]; }

    if (t < EBLK) {
        int e = perm[blockIdx.x * EBLK + t];
        e = ((uint_t)e < (uint_t)NE) ? e : 0;
        int r = rows[e], c = cols[e];
        r = ((uint_t)r < (uint_t)NN) ? r : 0;
        c = ((uint_t)c < (uint_t)NN) ? c : 0;
        se[t] = e; sr[t] = r; sc[t] = c;
    }
    __syncthreads();

    if (t < EBLK) {
        const int flag = (t == 0) ? 1 : ((sr[t] != sr[t - 1]) ? 1 : 0);
        int isc = flag;
        #pragma unroll
        for (int d = 1; d < EBLK; d <<= 1) {
            const int up = __shfl_up(isc, d);
            if (t >= d) isc += up;
        }
        if (flag) segstart[isc - 1] = t;
        if (t == EBLK - 1) { snseg = isc; segstart[isc] = EBLK; }
    }
    __syncthreads();
    const int nseg = snseg;

    const int ei = t >> 2;
    const int q  = t & 3;
    const int swz = ei & 31;
    const int r = sr[ei], c = sc[ei], e = se[ei];

    const float dx = coord[3 * r + 0] - coord[3 * c + 0];
    const float dy = coord[3 * r + 1] - coord[3 * c + 1];
    const float dz = coord[3 * r + 2] - coord[3 * c + 2];
    const float radial = dx * dx + dy * dy + dz * dz;
    const float2 ea = ((const float2*)eattr)[e];

    union { uint4 v[2]; uint_t a[8]; } R, C;
    {
        const uint4* pr = (const uint4*)(preR + (size_t)r * 32);
        const uint4* pc = (const uint4*)(preC + (size_t)c * 32);
        R.v[0] = pr[q * 2]; R.v[1] = pr[q * 2 + 1];
        C.v[0] = pc[q * 2]; C.v[1] = pc[q * 2 + 1];
    }
    float acc16[16];
    #pragma unroll
    for (int p = 0; p < 8; p++) {
        const half2v hr = u2h(R.a[p]);
        const half2v hc = u2h(C.a[p]);
        acc16[2 * p]     = (float)hr.x + (float)hc.x;
        acc16[2 * p + 1] = (float)hr.y + (float)hc.y;
    }
    {
        const float ext3[3] = {radial, ea.x, ea.y};
        #pragma unroll
        for (int x = 0; x < 3; x++) {
            const float v = ext3[x];
            const float* w = &sExtW[x * 64 + q * 16];
            #pragma unroll
            for (int j = 0; j < 16; j++) acc16[j] += v * w[j];
        }
    }
    #pragma unroll
    for (int j = 0; j < 16; j++) acc16[j] = silu(acc16[j]);
    #pragma unroll
    for (int p = 0; p < 8; p++)
        tileh[ei * 32 + ((q * 8 + p) ^ swz)] = h2u(pkrtz(acc16[2 * p], acc16[2 * p + 1]));
    __syncthreads();

    float m16[16];
    #pragma unroll
    for (int j = 0; j < 16; j++) m16[j] = sB2[q * 16 + j];
    #pragma unroll 8
    for (int kp = 0; kp < 32; kp++) {
        const half2v hp = u2h(tileh[ei * 32 + (kp ^ swz)]);
        const uint4* w4 = (const uint4*)&sW2p[kp * 64 + q * 16];
        #pragma unroll
        for (int j4 = 0; j4 < 4; j4++) {
            const uint4 w = w4[j4];
            m16[4*j4+0] = dot2h(hp, w.x, m16[4*j4+0]);
            m16[4*j4+1] = dot2h(hp, w.y, m16[4*j4+1]);
            m16[4*j4+2] = dot2h(hp, w.z, m16[4*j4+2]);
            m16[4*j4+3] = dot2h(hp, w.w, m16[4*j4+3]);
        }
    }
    #pragma unroll
    for (int j = 0; j < 16; j++) m16[j] = silu(m16[j]);

    __syncthreads();
    #pragma unroll
    for (int p = 0; p < 8; p++)
        tileh[ei * 32 + ((q * 8 + p) ^ swz)] = h2u(pkrtz(m16[2 * p], m16[2 * p + 1]));
    __syncthreads();

    float ch16[16];
    #pragma unroll
    for (int j = 0; j < 16; j++) ch16[j] = sCB1[q * 16 + j];
    #pragma unroll 8
    for (int kp = 0; kp < 32; kp++) {
        const half2v hp = u2h(tileh[ei * 32 + (kp ^ swz)]);
        const uint4* w4 = (const uint4*)&sCW1p[kp * 64 + q * 16];
        #pragma unroll
        for (int j4 = 0; j4 < 4; j4++) {
            const uint4 w = w4[j4];
            ch16[4*j4+0] = dot2h(hp, w.x, ch16[4*j4+0]);
            ch16[4*j4+1] = dot2h(hp, w.y, ch16[4*j4+1]);
            ch16[4*j4+2] = dot2h(hp, w.z, ch16[4*j4+2]);
            ch16[4*j4+3] = dot2h(hp, w.w, ch16[4*j4+3]);
        }
    }
    float part = 0.f;
    #pragma unroll
    for (int j = 0; j < 16; j++) part += silu(ch16[j]) * sCW2v[q * 16 + j];
    part += __shfl_xor(part, 1);
    part += __shfl_xor(part, 2);
    const float cw = part;

    for (int w = t; w < nseg * 64; w += 256) {
        const int lr2 = w >> 6, cc = w & 63;
        const int p0 = segstart[lr2], p1 = segstart[lr2 + 1];
        const int kp = cc >> 1, hi = cc & 1;
        float s = 0.f;
        for (int p = p0; p < p1; p++) {
            const half2v h = u2h(tileh[p * 32 + (kp ^ (p & 31))]);
            s += hi ? (float)h.y : (float)h.x;
        }
        atomicAdd(&magg[(size_t)sr[p0] * 64 + cc], s);
    }
    __syncthreads();

    float* tf = (float*)tileh;
    if (q < 3) tf[ei * 4 + q] = (q == 0 ? dx : (q == 1 ? dy : dz)) * cw;
    __syncthreads();
    for (int w = t; w < nseg * 3; w += 256) {
        const int lr2 = w / 3, cc = w - 3 * lr2;
        const int p0 = segstart[lr2], p1 = segstart[lr2 + 1];
        float s = 0.f;
        for (int p = p0; p < p1; p++) s += tf[p * 4 + cc];
        atomicAdd(&csum[3 * sr[p0] + cc], s);
    }
}

// ---- per-layer node kernel: 16 threads/node, all weights in LDS --------------
// Round-15: r14's node was VMEM-latency-bound (~192 per-thread global weight
// loads with only ~2.4 waves/SIMD of TLP). Now vW1/gW1 staged as f16 pairs
// (8 KB each, GEMMs use the proven dot2 form) and NW2 staged fp32 (16 KB,
// the r4-r13 proven epilogue pattern). Per-thread global loads ~192 -> ~12.
// LDS ~77 KB -> 2 blocks/CU (grid gives 2.44, minimal loss).
__global__ __launch_bounds__(256, 2) void node_kernel(
    const float* __restrict__ gVW1, const float* __restrict__ gVB1,
    const float* __restrict__ gVW2, const float* __restrict__ gVB2,
    const float* __restrict__ gGW1, const float* __restrict__ gGB1,
    const float* __restrict__ gGW2, const float* __restrict__ gGB2,
    const float* __restrict__ gNW1, const float* __restrict__ gNB1,
    const float* __restrict__ gNW2, const float* __restrict__ gNB2,
    const float* __restrict__ gW1n, const float* __restrict__ gB1n,
    float* __restrict__ csum, const int* __restrict__ off,
    const float* __restrict__ vsrc, const float* __restrict__ field,
    float* __restrict__ magg,
    float* __restrict__ coord, float* __restrict__ hh,
    uint_t* __restrict__ preR, uint_t* __restrict__ preC, const int emit_pre)
{
    __shared__ __align__(16) uint_t sNW1p[4096];       // NW1 f16 pairs, 16 KB
    __shared__ __align__(16) uint_t sW1np[4096];       // next-layer W1 f16, 16 KB
    __shared__ __align__(16) uint_t sVW1p[2048];       // vW1 f16 pairs, 8 KB
    __shared__ __align__(16) uint_t sGW1p[2048];       // gW1 f16 pairs, 8 KB
    __shared__ __align__(16) float sNW2[4096];         // NW2 fp32, 16 KB
    __shared__ __align__(16) float tile[NPB2 * 136];   // hh[0..63], magg[68..131]
    __shared__ float sNB1[64], sNB2[64], sB1n[64];

    const int t = threadIdx.x;
    for (int i = t; i < 1024; i += 256) {
        const int kp = i >> 4, j4 = i & 15;
        const float4 w0 = ((const float4*)gNW1)[kp * 32 + j4];
        const float4 w1 = ((const float4*)gNW1)[kp * 32 + 16 + j4];
        uint4 u;
        u.x = h2u(pkrtz(w0.x, w1.x)); u.y = h2u(pkrtz(w0.y, w1.y));
        u.z = h2u(pkrtz(w0.z, w1.z)); u.w = h2u(pkrtz(w0.w, w1.w));
        ((uint4*)sNW1p)[i] = u;
    }
    for (int i = t; i < 1024; i += 256) {
        const int kp = i >> 4, j4 = i & 15;
        const float4 w0 = ((const float4*)gW1n)[kp * 32 + j4];
        const float4 w1 = ((const float4*)gW1n)[kp * 32 + 16 + j4];
        uint4 u;
        u.x = h2u(pkrtz(w0.x, w1.x)); u.y = h2u(pkrtz(w0.y, w1.y));
        u.z = h2u(pkrtz(w0.z, w1.z)); u.w = h2u(pkrtz(w0.w, w1.w));
        ((uint4*)sW1np)[i] = u;
    }
    for (int i = t; i < 512; i += 256) {
        const int kp = i >> 4, j4 = i & 15;
        const float4 w0 = ((const float4*)gVW1)[kp * 32 + j4];
        const float4 w1 = ((const float4*)gVW1)[kp * 32 + 16 + j4];
        uint4 u;
        u.x = h2u(pkrtz(w0.x, w1.x)); u.y = h2u(pkrtz(w0.y, w1.y));
        u.z = h2u(pkrtz(w0.z, w1.z)); u.w = h2u(pkrtz(w0.w, w1.w));
        ((uint4*)sVW1p)[i] = u;
    }
    for (int i = t; i < 512; i += 256) {
        const int kp = i >> 4, j4 = i & 15;
        const float4 w0 = ((const float4*)gGW1)[kp * 32 + j4];
        const float4 w1 = ((const float4*)gGW1)[kp * 32 + 16 + j4];
        uint4 u;
        u.x = h2u(pkrtz(w0.x, w1.x)); u.y = h2u(pkrtz(w0.y, w1.y));
        u.z = h2u(pkrtz(w0.z, w1.z)); u.w = h2u(pkrtz(w0.w, w1.w));
        ((uint4*)sGW1p)[i] = u;
    }
    for (int i = t; i < 1024; i += 256)
        ((float4*)sNW2)[i] = ((const float4*)gNW2)[i];
    if (t < 64) { sNB1[t] = gNB1[t]; sNB2[t] = gNB2[t]; sB1n[t] = gB1n[t]; }

    const int ni = t >> 4;          // node in block (0..15)
    const int q  = t & 15;          // channel group (4 ch)
    const int n = blockIdx.x * NPB2 + ni;    // grid*NPB2 = 10000 exactly
    float* T = &tile[ni * 136];

    // stage hh + magg into tile
    ((float4*)T)[q]        = ((const float4*)(hh + (size_t)n * 64))[q];
    ((float4*)(T + 68))[q] = ((const float4*)(magg + (size_t)n * 64))[q];
    __syncthreads();

    // ---- vw = silu(hh @ vW1 + vb1) @ vW2 + vb2 (f16 dot2, LDS weights) ----
    float a4[4];
    {
        const float4 b = ((const float4*)gVB1)[q];
        a4[0] = b.x; a4[1] = b.y; a4[2] = b.z; a4[3] = b.w;
    }
    #pragma unroll 8
    for (int kp = 0; kp < 32; kp++) {
        const half2v p = pkrtz(T[2 * kp], T[2 * kp + 1]);
        const uint4 w = *(const uint4*)&sVW1p[kp * 64 + q * 4];
        a4[0] = dot2h(p, w.x, a4[0]); a4[1] = dot2h(p, w.y, a4[1]);
        a4[2] = dot2h(p, w.z, a4[2]); a4[3] = dot2h(p, w.w, a4[3]);
    }
    float part;
    {
        const float4 w2 = ((const float4*)gVW2)[q];
        part = silu(a4[0]) * w2.x + silu(a4[1]) * w2.y
             + silu(a4[2]) * w2.z + silu(a4[3]) * w2.w;
    }
    part += __shfl_xor(part, 1);
    part += __shfl_xor(part, 2);
    part += __shfl_xor(part, 4);
    part += __shfl_xor(part, 8);
    const float vw = part + gVB2[0];

    // ---- gw (same structure) ----
    {
        const float4 b = ((const float4*)gGB1)[q];
        a4[0] = b.x; a4[1] = b.y; a4[2] = b.z; a4[3] = b.w;
    }
    #pragma unroll 8
    for (int kp = 0; kp < 32; kp++) {
        const half2v p = pkrtz(T[2 * kp], T[2 * kp + 1]);
        const uint4 w = *(const uint4*)&sGW1p[kp * 64 + q * 4];
        a4[0] = dot2h(p, w.x, a4[0]); a4[1] = dot2h(p, w.y, a4[1]);
        a4[2] = dot2h(p, w.z, a4[2]); a4[3] = dot2h(p, w.w, a4[3]);
    }
    {
        const float4 w2 = ((const float4*)gGW2)[q];
        part = silu(a4[0]) * w2.x + silu(a4[1]) * w2.y
             + silu(a4[2]) * w2.z + silu(a4[3]) * w2.w;
    }
    part += __shfl_xor(part, 1);
    part += __shfl_xor(part, 2);
    part += __shfl_xor(part, 4);
    part += __shfl_xor(part, 8);
    const float gw = part + gGB2[0];

    // ---- coord update (one thread per node) ----
    if (q == 0) {
        const float cn = fmaxf((float)(off[n + 1] - off[n]), 1.0f);
        #pragma unroll
        for (int d = 0; d < 3; d++)
            coord[3 * n + d] += csum[3 * n + d] / cn
                              + vw * vsrc[3 * n + d]
                              + gw * field[3 * n + d];
    }

    // ---- node MLP hidden: a4 = silu([hh, magg] @ NW1[:, q*4..+4] + b1) ----
    {
        const float4 b = ((const float4*)sNB1)[q];
        a4[0] = b.x; a4[1] = b.y; a4[2] = b.z; a4[3] = b.w;
    }
    #pragma unroll 8
    for (int kp = 0; kp < 32; kp++) {             // hh half
        const half2v p = pkrtz(T[2 * kp], T[2 * kp + 1]);
        const uint4 w = *(const uint4*)&sNW1p[kp * 64 + q * 4];
        a4[0] = dot2h(p, w.x, a4[0]); a4[1] = dot2h(p, w.y, a4[1]);
        a4[2] = dot2h(p, w.z, a4[2]); a4[3] = dot2h(p, w.w, a4[3]);
    }
    #pragma unroll 8
    for (int kp = 0; kp < 32; kp++) {             // magg half
        const half2v p = pkrtz(T[68 + 2 * kp], T[68 + 2 * kp + 1]);
        const uint4 w = *(const uint4*)&sNW1p[(32 + kp) * 64 + q * 4];
        a4[0] = dot2h(p, w.x, a4[0]); a4[1] = dot2h(p, w.y, a4[1]);
        a4[2] = dot2h(p, w.z, a4[2]); a4[3] = dot2h(p, w.w, a4[3]);
    }
    #pragma unroll
    for (int j = 0; j < 4; j++) a4[j] = silu(a4[j]);

    // ---- exchange hidden through tile (overwrite hh slots) ----
    __syncthreads();
    {
        float4 v; v.x = a4[0]; v.y = a4[1]; v.z = a4[2]; v.w = a4[3];
        ((float4*)T)[q] = v;
    }
    __syncthreads();

    // ---- zero magg/csum for next layer (magg reads completed above) ----
    {
        float4 z; z.x = z.y = z.z = z.w = 0.f;
        ((float4*)(magg + (size_t)n * 64))[q] = z;
        if (q == 0) { csum[3 * n] = 0.f; csum[3 * n + 1] = 0.f; csum[3 * n + 2] = 0.f; }
    }

    // ---- output: o4 = hid64 @ NW2[:, q*4..+4] + b2 (LDS fp32 weights) ----
    float o4[4];
    {
        const float4 b = ((const float4*)sNB2)[q];
        o4[0] = b.x; o4[1] = b.y; o4[2] = b.z; o4[3] = b.w;
    }
    #pragma unroll 4
    for (int kk = 0; kk < 16; kk++) {
        const float4 h4 = ((const float4*)T)[kk];
        const float hv[4] = {h4.x, h4.y, h4.z, h4.w};
        #pragma unroll
        for (int u = 0; u < 4; u++) {
            const float v = hv[u];
            const float4 w = ((const float4*)(sNW2 + (kk * 4 + u) * 64))[q];
            o4[0] += v * w.x; o4[1] += v * w.y; o4[2] += v * w.z; o4[3] += v * w.w;
        }
    }
    {
        float4 v; v.x = o4[0]; v.y = o4[1]; v.z = o4[2]; v.w = o4[3];
        ((float4*)(hh + (size_t)n * 64))[q] = v;
    }

    // ---- fused pre emission for next layer (uniform branch) ----
    if (emit_pre) {
        __syncthreads();                 // hidden-tile reads done
        {
            float4 v; v.x = o4[0]; v.y = o4[1]; v.z = o4[2]; v.w = o4[3];
            ((float4*)T)[q] = v;         // tile now holds new hh
        }
        __syncthreads();

        float aR[4], aC[4];
        {
            const float4 b = ((const float4*)sB1n)[q];
            aR[0] = b.x; aR[1] = b.y; aR[2] = b.z; aR[3] = b.w;
            aC[0] = aC[1] = aC[2] = aC[3] = 0.f;
        }
        #pragma unroll 8
        for (int kp = 0; kp < 32; kp++) {
            const half2v p = pkrtz(T[2 * kp], T[2 * kp + 1]);
            const uint4 wr = *(const uint4*)&sW1np[kp * 64 + q * 4];
            const uint4 wc = *(const uint4*)&sW1np[(32 + kp) * 64 + q * 4];
            aR[0] = dot2h(p, wr.x, aR[0]); aR[1] = dot2h(p, wr.y, aR[1]);
            aR[2] = dot2h(p, wr.z, aR[2]); aR[3] = dot2h(p, wr.w, aR[3]);
            aC[0] = dot2h(p, wc.x, aC[0]); aC[1] = dot2h(p, wc.y, aC[1]);
            aC[2] = dot2h(p, wc.z, aC[2]); aC[3] = dot2h(p, wc.w, aC[3]);
        }
        uint2 oR, oC;
        oR.x = h2u(pkrtz(aR[0], aR[1])); oR.y = h2u(pkrtz(aR[2], aR[3]));
        oC.x = h2u(pkrtz(aC[0], aC[1])); oC.y = h2u(pkrtz(aC[2], aC[3]));
        *(uint2*)(preR + (size_t)n * 32 + q * 2) = oR;
        *(uint2*)(preC + (size_t)n * 32 + q * 2) = oC;
    }
}

// ---- host launch -------------------------------------------------------------
extern "C" void kernel_launch(void* const* d_in, const int* in_sizes, int n_in,
                              void* d_out, int out_size, void* d_ws, size_t ws_size,
                              hipStream_t stream) {
    float* wsf = (float*)d_ws;
    int*   wsi = (int*)(wsf + 1340000);
    uint_t* preR = (uint_t*)(wsi + IOFF_PRER);
    uint_t* preC = (uint_t*)(wsi + IOFF_PREC);
    float* coord = (float*)d_out;
    const int* edges = (const int*)d_in[4];
    const int* rows = edges;
    const int* cols = edges + NE;

    hipMemsetAsync(wsi + IOFF_CNTI, 0, NN * sizeof(int), stream);
    counti_kernel<<<(NE + 255) / 256, 256, 0, stream>>>(rows, wsi + IOFF_CNTI);
    scan_kernel<<<1, 1024, 0, stream>>>(wsi + IOFF_CNTI, wsi + IOFF_OFF, wsi + IOFF_CURSOR);
    scatter_kernel<<<(NE + 255) / 256, 256, 0, stream>>>(rows, wsi + IOFF_CURSOR,
                                                         wsi + IOFF_PERM);

    node_init<<<(NN + 255) / 256, 256, 0, stream>>>(
        (const float*)d_in[0], (const float*)d_in[1], (const float*)d_in[2],
        (const int*)d_in[5], (const float*)d_in[8],
        (const float*)d_in[9],  (const float*)d_in[10],
        (const float*)d_in[11], (const float*)d_in[12],
        (const float*)d_in[13], (const float*)d_in[14],
        (const float*)d_in[6],  (const float*)d_in[7],
        coord, wsf + OFF_FIELD, wsf + OFF_HH);

    // csum+magg zeroed once; node_kernel re-zeroes them each layer
    hipMemsetAsync(wsf + OFF_CSUM, 0, (30000 + 640000) * sizeof(float), stream);

    // layer-0 pre; layers 1..3 get pre from node_kernel's fused epilogue
    pre_kernel<<<NNODEBLK, 256, 0, stream>>>(
        wsf + OFF_HH,
        (const float*)d_in[15], (const float*)d_in[16],
        preR, preC);

    for (int l = 0; l < NL; l++) {
        const int ln = (l + 1 < NL) ? (l + 1) : 0;   // next-layer W1 (unused if last)
        edge_kernel<<<NEBLK, 256, 0, stream>>>(
            rows, cols, wsi + IOFF_PERM,
            coord, (const float*)d_in[3],
            ((const float*)d_in[15]) + l * 8384,
            ((const float*)d_in[17]) + l * 4096, ((const float*)d_in[18]) + l * 64,
            ((const float*)d_in[23]) + l * 4096, ((const float*)d_in[24]) + l * 64,
            ((const float*)d_in[25]) + l * 64,
            preR, preC,
            wsf + OFF_CSUM, wsf + OFF_MAGG);
        node_kernel<<<NODEBLK2, 256, 0, stream>>>(
            ((const float*)d_in[26]) + l * 4096, ((const float*)d_in[27]) + l * 64,
            ((const float*)d_in[28]) + l * 64,   ((const float*)d_in[29]) + l,
            ((const float*)d_in[30]) + l * 4096, ((const float*)d_in[31]) + l * 64,
            ((const float*)d_in[32]) + l * 64,   ((const float*)d_in[33]) + l,
            ((const float*)d_in[19]) + l * 8192, ((const float*)d_in[20]) + l * 64,
            ((const float*)d_in[21]) + l * 4096, ((const float*)d_in[22]) + l * 64,
            ((const float*)d_in[15]) + ln * 8384, ((const float*)d_in[16]) + ln * 64,
            wsf + OFF_CSUM, wsi + IOFF_OFF, (const float*)d_in[2],
            wsf + OFF_FIELD, wsf + OFF_MAGG, coord, wsf + OFF_HH,
            preR, preC, (l + 1 < NL) ? 1 : 0);
    }
}

// Round 16
// 625.067 us; speedup vs baseline: 4.5021x; 1.0370x over previous
//
#include <hip/hip_runtime.h>
#include <hip/hip_bf16.h>

typedef unsigned short ushort_t;
typedef unsigned int uint_t;

#define NN    10000
#define NE    320000
#define NL    4
#define EBLK  64        // edges per block (4 threads per edge)
#define NEBLK 5000      // NE / EBLK exactly
#define NPB   64        // nodes per block in pre_kernel (4 threads per node)
#define NNODEBLK 157    // ceil(NN / NPB)
#define NPB2  16        // nodes per block in node_kernel (16 threads per node)
#define NODEBLK2 625    // NN / NPB2 exactly, no tail

// ---- workspace float offsets -------------------------------------------------
#define OFF_FIELD 0        // 30000
#define OFF_HH    30000    // 640000
#define OFF_CSUM  670000   // 30000  (contiguous with MAGG for one memset)
#define OFF_MAGG  700000   // 640000 -> float end 1340000
// ---- int region (starts at float offset 1340000) ----------------------------
#define IOFF_CNTI   0        // 10000
#define IOFF_OFF    10000    // 10001
#define IOFF_CURSOR 20001    // 10000
#define IOFF_PERM   30001    // 320000
#define IOFF_PRER   350004   // 320000 uints (f16-pair preR; 16B-aligned)
#define IOFF_PREC   670004   // 320000 uints -> int end 990004
// total ws = (1340000 + 990004) * 4 = 9,320,016 B  (ws_size >= 9.4 MB verified r12)

// fast silu: v_rcp_f32 instead of IEEE divide (~1e-7 rel err, VALU-bound paths)
__device__ __forceinline__ float silu(float x) {
    return x * __builtin_amdgcn_rcpf(1.0f + __expf(-x));
}

// ---- f16 pair helpers for v_dot2_f32_f16 (clang builtins use __fp16 V2h) -----
typedef __fp16 half2v __attribute__((ext_vector_type(2)));
__device__ __forceinline__ half2v u2h(uint_t u) {
    union { uint_t u; half2v h; } x; x.u = u; return x.h;
}
__device__ __forceinline__ uint_t h2u(half2v h) {
    union { half2v h; uint_t u; } x; x.h = h; return x.u;
}
__device__ __forceinline__ half2v pkrtz(float a, float b) {
    return __builtin_amdgcn_cvt_pkrtz(a, b);
}
__device__ __forceinline__ float dot2h(half2v a, uint_t w, float c) {
#if __has_builtin(__builtin_amdgcn_fdot2)
    return __builtin_amdgcn_fdot2(a, u2h(w), c, false);
#else
    union { uint_t u; __fp16 h[2]; } x; x.u = w;
    return c + (float)a.x * (float)x.h[0] + (float)a.y * (float)x.h[1];
#endif
}

// ---- CSR build: per-row int counts ------------------------------------------
__global__ __launch_bounds__(256) void counti_kernel(const int* __restrict__ rows,
                                                     int* __restrict__ cnti) {
    const int e = blockIdx.x * 256 + threadIdx.x;
    if (e < NE) {
        int r = rows[e];
        r = ((uint_t)r < (uint_t)NN) ? r : 0;
        atomicAdd(&cnti[r], 1);
    }
}

// ---- CSR build: exclusive scan over 10000 counts (single block) --------------
__global__ __launch_bounds__(1024) void scan_kernel(const int* __restrict__ cnti,
                                                    int* __restrict__ off,
                                                    int* __restrict__ cursor) {
    __shared__ int part[1024];
    const int t = threadIdx.x;
    const int base = t * 10;
    int loc[10];
    int s = 0;
    #pragma unroll
    for (int i = 0; i < 10; i++) {
        const int idx = base + i;
        const int v = (idx < NN) ? cnti[idx] : 0;
        loc[i] = s; s += v;
    }
    part[t] = s;
    __syncthreads();
    const int own = s;
    for (int d = 1; d < 1024; d <<= 1) {
        const int v = (t >= d) ? part[t - d] : 0;
        __syncthreads();
        part[t] += v;
        __syncthreads();
    }
    const int excl = part[t] - own;
    #pragma unroll
    for (int i = 0; i < 10; i++) {
        const int idx = base + i;
        if (idx < NN) { const int o = excl + loc[i]; off[idx] = o; cursor[idx] = o; }
    }
    if (t == 0) off[NN] = NE;
}

// ---- CSR build: scatter edge ids into row-sorted order -----------------------
__global__ __launch_bounds__(256) void scatter_kernel(const int* __restrict__ rows,
                                                      int* __restrict__ cursor,
                                                      int* __restrict__ perm) {
    const int e = blockIdx.x * 256 + threadIdx.x;
    if (e < NE) {
        int r = rows[e];
        r = ((uint_t)r < (uint_t)NN) ? r : 0;
        const int pos = atomicAdd(&cursor[r], 1);
        if ((uint_t)pos < (uint_t)NE) perm[pos] = e;
    }
}

// ---- field network + node embedding + coord init (once per call) ------------
__global__ __launch_bounds__(256) void node_init(
    const float* __restrict__ hsrc, const float* __restrict__ xsrc,
    const float* __restrict__ vsrc, const int* __restrict__ charges,
    const float* __restrict__ cls,
    const float* __restrict__ fW1, const float* __restrict__ fb1,
    const float* __restrict__ fW2, const float* __restrict__ fb2,
    const float* __restrict__ fW3, const float* __restrict__ fb3,
    const float* __restrict__ embW, const float* __restrict__ embb,
    float* __restrict__ coord, float* __restrict__ field, float* __restrict__ hh)
{
    __shared__ float sFW1[704], sFW2[1024], sFW3[96];
    __shared__ float sFB1[32], sFB2[32], sFB3[3], sCLS[32], sEW[64], sEB[64];
    const int t = threadIdx.x;
    for (int i = t; i < 704; i += 256) sFW1[i] = fW1[i];
    for (int i = t; i < 1024; i += 256) sFW2[i] = fW2[i];
    if (t < 96) sFW3[t] = fW3[t];
    if (t < 32) { sFB1[t] = fb1[t]; sFB2[t] = fb2[t]; sCLS[t] = cls[t]; }
    if (t < 3)  sFB3[t] = fb3[t];
    if (t < 64) { sEW[t] = embW[t]; sEB[t] = embb[t]; }
    __syncthreads();

    const int n = blockIdx.x * 256 + t;
    if (n >= NN) return;

    float fin[22];
    #pragma unroll
    for (int d = 0; d < 3; d++) {
        fin[d]     = xsrc[3 * n + d];
        fin[3 + d] = vsrc[3 * n + d];
        coord[3 * n + d] = fin[d];
    }
    int ci = charges[n];
    ci = ((uint_t)ci < 2u) ? ci : 0;
    const int cix = ci * 16;
    #pragma unroll
    for (int k = 0; k < 16; k++) fin[6 + k] = sCLS[cix + k];

    float h1[32];
    #pragma unroll
    for (int j = 0; j < 32; j++) h1[j] = sFB1[j];
    #pragma unroll
    for (int k = 0; k < 22; k++) {
        const float v = fin[k];
        #pragma unroll
        for (int j = 0; j < 32; j++) h1[j] += v * sFW1[k * 32 + j];
    }
    #pragma unroll
    for (int j = 0; j < 32; j++) h1[j] = silu(h1[j]);

    float h2[32];
    #pragma unroll
    for (int j = 0; j < 32; j++) h2[j] = sFB2[j];
    #pragma unroll
    for (int k = 0; k < 32; k++) {
        const float v = h1[k];
        #pragma unroll
        for (int j = 0; j < 32; j++) h2[j] += v * sFW2[k * 32 + j];
    }
    #pragma unroll
    for (int j = 0; j < 32; j++) h2[j] = silu(h2[j]);

    #pragma unroll
    for (int d = 0; d < 3; d++) {
        float s = sFB3[d];
        #pragma unroll
        for (int j = 0; j < 32; j++) s += h2[j] * sFW3[j * 3 + d];
        field[3 * n + d] = s;
    }

    const float hv = hsrc[n];
    #pragma unroll
    for (int j = 0; j < 64; j++) hh[(size_t)n * 64 + j] = hv * sEW[j] + sEB[j];
}

// ---- layer-0 pre kernel: preR[n] = b1 + W1r.hh[n], preC[n] = W1c.hh[n] -------
__global__ __launch_bounds__(256, 4) void pre_kernel(
    const float* __restrict__ hh,
    const float* __restrict__ gEW1, const float* __restrict__ gEB1,
    uint_t* __restrict__ preR, uint_t* __restrict__ preC)
{
    __shared__ __align__(16) uint_t sW1p[4096];   // rows 0..127 f16-paired, 16 KB
    __shared__ float sB1[64];
    const int t = threadIdx.x;
    for (int i = t; i < 1024; i += 256) {          // 64 kp x 16 j4-groups
        const int kp = i >> 4, j4 = i & 15;
        const float4 w0 = ((const float4*)gEW1)[kp * 32 + j4];
        const float4 w1 = ((const float4*)gEW1)[kp * 32 + 16 + j4];
        uint4 u;
        u.x = h2u(pkrtz(w0.x, w1.x)); u.y = h2u(pkrtz(w0.y, w1.y));
        u.z = h2u(pkrtz(w0.z, w1.z)); u.w = h2u(pkrtz(w0.w, w1.w));
        ((uint4*)sW1p)[i] = u;
    }
    if (t < 64) sB1[t] = gEB1[t];
    __syncthreads();

    const int ni = t >> 2, q = t & 3;
    int n = blockIdx.x * NPB + ni;
    const bool valid = (n < NN);
    n = valid ? n : (NN - 1);
    const float4* h4p = (const float4*)(hh + (size_t)n * 64);

    float acc[16];
    #pragma unroll
    for (int j = 0; j < 16; j++) acc[j] = sB1[q * 16 + j];
    #pragma unroll
    for (int kk = 0; kk < 16; kk++) {
        const float4 a = h4p[kk];
        const half2v p0 = pkrtz(a.x, a.y);
        const half2v p1 = pkrtz(a.z, a.w);
        const uint4* w0 = (const uint4*)&sW1p[(2 * kk) * 64 + q * 16];
        const uint4* w1 = (const uint4*)&sW1p[(2 * kk + 1) * 64 + q * 16];
        #pragma unroll
        for (int j4 = 0; j4 < 4; j4++) {
            const uint4 wa = w0[j4], wb = w1[j4];
            acc[4*j4+0] = dot2h(p1, wb.x, dot2h(p0, wa.x, acc[4*j4+0]));
            acc[4*j4+1] = dot2h(p1, wb.y, dot2h(p0, wa.y, acc[4*j4+1]));
            acc[4*j4+2] = dot2h(p1, wb.z, dot2h(p0, wa.z, acc[4*j4+2]));
            acc[4*j4+3] = dot2h(p1, wb.w, dot2h(p0, wa.w, acc[4*j4+3]));
        }
    }
    if (valid) {
        uint4 o0, o1;
        o0.x = h2u(pkrtz(acc[0],  acc[1]));  o0.y = h2u(pkrtz(acc[2],  acc[3]));
        o0.z = h2u(pkrtz(acc[4],  acc[5]));  o0.w = h2u(pkrtz(acc[6],  acc[7]));
        o1.x = h2u(pkrtz(acc[8],  acc[9]));  o1.y = h2u(pkrtz(acc[10], acc[11]));
        o1.z = h2u(pkrtz(acc[12], acc[13])); o1.w = h2u(pkrtz(acc[14], acc[15]));
        uint4* dst = (uint4*)(preR + (size_t)n * 32 + q * 8);
        dst[0] = o0; dst[1] = o1;
    }

    #pragma unroll
    for (int j = 0; j < 16; j++) acc[j] = 0.f;
    #pragma unroll
    for (int kk = 0; kk < 16; kk++) {
        const float4 a = h4p[kk];
        const half2v p0 = pkrtz(a.x, a.y);
        const half2v p1 = pkrtz(a.z, a.w);
        const uint4* w0 = (const uint4*)&sW1p[(32 + 2 * kk) * 64 + q * 16];
        const uint4* w1 = (const uint4*)&sW1p[(33 + 2 * kk) * 64 + q * 16];
        #pragma unroll
        for (int j4 = 0; j4 < 4; j4++) {
            const uint4 wa = w0[j4], wb = w1[j4];
            acc[4*j4+0] = dot2h(p1, wb.x, dot2h(p0, wa.x, acc[4*j4+0]));
            acc[4*j4+1] = dot2h(p1, wb.y, dot2h(p0, wa.y, acc[4*j4+1]));
            acc[4*j4+2] = dot2h(p1, wb.z, dot2h(p0, wa.z, acc[4*j4+2]));
            acc[4*j4+3] = dot2h(p1, wb.w, dot2h(p0, wa.w, acc[4*j4+3]));
        }
    }
    if (valid) {
        uint4 o0, o1;
        o0.x = h2u(pkrtz(acc[0],  acc[1]));  o0.y = h2u(pkrtz(acc[2],  acc[3]));
        o0.z = h2u(pkrtz(acc[4],  acc[5]));  o0.w = h2u(pkrtz(acc[6],  acc[7]));
        o1.x = h2u(pkrtz(acc[8],  acc[9]));  o1.y = h2u(pkrtz(acc[10], acc[11]));
        o1.z = h2u(pkrtz(acc[12], acc[13])); o1.w = h2u(pkrtz(acc[14], acc[15]));
        uint4* dst = (uint4*)(preC + (size_t)n * 32 + q * 8);
        dst[0] = o0; dst[1] = o1;
    }
}

// ---- per-layer edge kernel: r13 structure + cW1/W2 LDS aliasing --------------
// Round-16: cW1 no longer has its own LDS buffer. It is held in 2 uint4 regs
// from kernel start (T14 issue-early) and ds_written into the W2 buffer at the
// existing post-W2-GEMM barrier (W2 is dead there; zero extra barriers).
// LDS 27.6 -> ~19 KB; launch_bounds(256,7) -> 7 blocks/CU (VGPR cap 73 vs ~56
// expected — no spill risk). Attacks the 44%-occupancy stall fraction.
__global__ __launch_bounds__(256, 7) void edge_kernel(
    const int* __restrict__ rows, const int* __restrict__ cols,
    const int* __restrict__ perm,
    const float* __restrict__ coord,
    const float* __restrict__ eattr,
    const float* __restrict__ gEW1,                 // only ext rows 128..130
    const float* __restrict__ gEW2, const float* __restrict__ gEB2,
    const float* __restrict__ gCW1, const float* __restrict__ gCB1,
    const float* __restrict__ gCW2,
    const uint_t* __restrict__ preR, const uint_t* __restrict__ preC,
    float* __restrict__ csum, float* __restrict__ magg)
{
    __shared__ __align__(16) uint_t tileh[EBLK * 32];  // f16-pair activations, 8 KB
    __shared__ __align__(16) uint_t sWp[2048];         // W2 then cW1 (aliased), 8 KB
    __shared__ float sExtW[3 * 64];                    // W1 rows 128..130 fp32
    __shared__ float sB2[64], sCB1[64], sCW2v[64];
    __shared__ int   sr[EBLK], sc[EBLK], se[EBLK];
    __shared__ int   segstart[EBLK + 1];
    __shared__ int   snseg;

    const int t = threadIdx.x;

    // ---- T14 issue-early: cW1 global->reg (written to sWp after W2 GEMM) ----
    uint4 cwr0, cwr1;
    {
        const int i0 = t, i1 = t + 256;            // uint4 idx: kp = i>>4, j4 = i&15
        const float4 a0 = ((const float4*)gCW1)[(i0 >> 4) * 32 + (i0 & 15)];
        const float4 b0 = ((const float4*)gCW1)[(i0 >> 4) * 32 + 16 + (i0 & 15)];
        cwr0.x = h2u(pkrtz(a0.x, b0.x)); cwr0.y = h2u(pkrtz(a0.y, b0.y));
        cwr0.z = h2u(pkrtz(a0.z, b0.z)); cwr0.w = h2u(pkrtz(a0.w, b0.w));
        const float4 a1 = ((const float4*)gCW1)[(i1 >> 4) * 32 + (i1 & 15)];
        const float4 b1 = ((const float4*)gCW1)[(i1 >> 4) * 32 + 16 + (i1 & 15)];
        cwr1.x = h2u(pkrtz(a1.x, b1.x)); cwr1.y = h2u(pkrtz(a1.y, b1.y));
        cwr1.z = h2u(pkrtz(a1.z, b1.z)); cwr1.w = h2u(pkrtz(a1.w, b1.w));
    }

    // ---- stage W2 (f16 pairs), ext rows, biases ----
    for (int i = t; i < 512; i += 256) {           // 32 kp x 16 j4-groups
        const int kp = i >> 4, j4 = i & 15;
        const float4 w0 = ((const float4*)gEW2)[kp * 32 + j4];
        const float4 w1 = ((const float4*)gEW2)[kp * 32 + 16 + j4];
        uint4 u;
        u.x = h2u(pkrtz(w0.x, w1.x)); u.y = h2u(pkrtz(w0.y, w1.y));
        u.z = h2u(pkrtz(w0.z, w1.z)); u.w = h2u(pkrtz(w0.w, w1.w));
        ((uint4*)sWp)[i] = u;
    }
    if (t < 192) sExtW[t] = gEW1[8192 + t];        // rows 128..130
    if (t < 64) { sB2[t] = gEB2[t]; sCB1[t] = gCB1[t]; sCW2v[t] = gCW2[t]; }

    if (t < EBLK) {
        int e = perm[blockIdx.x * EBLK + t];
        e = ((uint_t)e < (uint_t)NE) ? e : 0;
        int r = rows[e], c = cols[e];
        r = ((uint_t)r < (uint_t)NN) ? r : 0;
        c = ((uint_t)c < (uint_t)NN) ? c : 0;
        se[t] = e; sr[t] = r; sc[t] = c;
    }
    __syncthreads();

    if (t < EBLK) {
        const int flag = (t == 0) ? 1 : ((sr[t] != sr[t - 1]) ? 1 : 0);
        int isc = flag;
        #pragma unroll
        for (int d = 1; d < EBLK; d <<= 1) {
            const int up = __shfl_up(isc, d);
            if (t >= d) isc += up;
        }
        if (flag) segstart[isc - 1] = t;
        if (t == EBLK - 1) { snseg = isc; segstart[isc] = EBLK; }
    }
    __syncthreads();
    const int nseg = snseg;

    const int ei = t >> 2;
    const int q  = t & 3;
    const int swz = ei & 31;
    const int r = sr[ei], c = sc[ei], e = se[ei];

    const float dx = coord[3 * r + 0] - coord[3 * c + 0];
    const float dy = coord[3 * r + 1] - coord[3 * c + 1];
    const float dz = coord[3 * r + 2] - coord[3 * c + 2];
    const float radial = dx * dx + dy * dy + dz * dz;
    const float2 ea = ((const float2*)eattr)[e];

    // ---- phase 1: acc16 = preR[r] + preC[c] + ext; silu; pack to tileh ----
    union { uint4 v[2]; uint_t a[8]; } R, C;
    {
        const uint4* pr = (const uint4*)(preR + (size_t)r * 32);
        const uint4* pc = (const uint4*)(preC + (size_t)c * 32);
        R.v[0] = pr[q * 2]; R.v[1] = pr[q * 2 + 1];
        C.v[0] = pc[q * 2]; C.v[1] = pc[q * 2 + 1];
    }
    float acc16[16];
    #pragma unroll
    for (int p = 0; p < 8; p++) {
        const half2v hr = u2h(R.a[p]);
        const half2v hc = u2h(C.a[p]);
        acc16[2 * p]     = (float)hr.x + (float)hc.x;
        acc16[2 * p + 1] = (float)hr.y + (float)hc.y;
    }
    {
        const float ext3[3] = {radial, ea.x, ea.y};
        #pragma unroll
        for (int x = 0; x < 3; x++) {
            const float v = ext3[x];
            const float* w = &sExtW[x * 64 + q * 16];
            #pragma unroll
            for (int j = 0; j < 16; j++) acc16[j] += v * w[j];
        }
    }
    #pragma unroll
    for (int j = 0; j < 16; j++) acc16[j] = silu(acc16[j]);
    #pragma unroll
    for (int p = 0; p < 8; p++)
        tileh[ei * 32 + ((q * 8 + p) ^ swz)] = h2u(pkrtz(acc16[2 * p], acc16[2 * p + 1]));
    __syncthreads();

    // ---- layer 2: m16 = silu(hid64 @ W2[:, q*16..+16] + b2) ----
    float m16[16];
    #pragma unroll
    for (int j = 0; j < 16; j++) m16[j] = sB2[q * 16 + j];
    #pragma unroll 8
    for (int kp = 0; kp < 32; kp++) {
        const half2v hp = u2h(tileh[ei * 32 + (kp ^ swz)]);
        const uint4* w4 = (const uint4*)&sWp[kp * 64 + q * 16];
        #pragma unroll
        for (int j4 = 0; j4 < 4; j4++) {
            const uint4 w = w4[j4];
            m16[4*j4+0] = dot2h(hp, w.x, m16[4*j4+0]);
            m16[4*j4+1] = dot2h(hp, w.y, m16[4*j4+1]);
            m16[4*j4+2] = dot2h(hp, w.z, m16[4*j4+2]);
            m16[4*j4+3] = dot2h(hp, w.w, m16[4*j4+3]);
        }
    }
    #pragma unroll
    for (int j = 0; j < 16; j++) m16[j] = silu(m16[j]);

    __syncthreads();   // ALL W2 reads + hid reads done
    // ---- T14 write-late: cW1 reg->LDS (clobbers W2) + m16 to tileh ----
    ((uint4*)sWp)[t]       = cwr0;
    ((uint4*)sWp)[t + 256] = cwr1;
    #pragma unroll
    for (int p = 0; p < 8; p++)
        tileh[ei * 32 + ((q * 8 + p) ^ swz)] = h2u(pkrtz(m16[2 * p], m16[2 * p + 1]));
    __syncthreads();   // tileh holds m; sWp holds cW1

    // ---- cw = silu(m @ cW1 + cb1) @ cW2 ----
    float ch16[16];
    #pragma unroll
    for (int j = 0; j < 16; j++) ch16[j] = sCB1[q * 16 + j];
    #pragma unroll 8
    for (int kp = 0; kp < 32; kp++) {
        const half2v hp = u2h(tileh[ei * 32 + (kp ^ swz)]);
        const uint4* w4 = (const uint4*)&sWp[kp * 64 + q * 16];
        #pragma unroll
        for (int j4 = 0; j4 < 4; j4++) {
            const uint4 w = w4[j4];
            ch16[4*j4+0] = dot2h(hp, w.x, ch16[4*j4+0]);
            ch16[4*j4+1] = dot2h(hp, w.y, ch16[4*j4+1]);
            ch16[4*j4+2] = dot2h(hp, w.z, ch16[4*j4+2]);
            ch16[4*j4+3] = dot2h(hp, w.w, ch16[4*j4+3]);
        }
    }
    float part = 0.f;
    #pragma unroll
    for (int j = 0; j < 16; j++) part += silu(ch16[j]) * sCW2v[q * 16 + j];
    part += __shfl_xor(part, 1);
    part += __shfl_xor(part, 2);
    const float cw = part;

    // ---- segmented reduction: magg ----
    for (int w = t; w < nseg * 64; w += 256) {
        const int lr2 = w >> 6, cc = w & 63;
        const int p0 = segstart[lr2], p1 = segstart[lr2 + 1];
        const int kp = cc >> 1, hi = cc & 1;
        float s = 0.f;
        for (int p = p0; p < p1; p++) {
            const half2v h = u2h(tileh[p * 32 + (kp ^ (p & 31))]);
            s += hi ? (float)h.y : (float)h.x;
        }
        atomicAdd(&magg[(size_t)sr[p0] * 64 + cc], s);
    }
    __syncthreads();

    // ---- segmented reduction: csum ----
    float* tf = (float*)tileh;
    if (q < 3) tf[ei * 4 + q] = (q == 0 ? dx : (q == 1 ? dy : dz)) * cw;
    __syncthreads();
    for (int w = t; w < nseg * 3; w += 256) {
        const int lr2 = w / 3, cc = w - 3 * lr2;
        const int p0 = segstart[lr2], p1 = segstart[lr2 + 1];
        float s = 0.f;
        for (int p = p0; p < p1; p++) s += tf[p * 4 + cc];
        atomicAdd(&csum[3 * sr[p0] + cc], s);
    }
}

// ---- per-layer node kernel (byte-identical to round 15) ----------------------
__global__ __launch_bounds__(256, 2) void node_kernel(
    const float* __restrict__ gVW1, const float* __restrict__ gVB1,
    const float* __restrict__ gVW2, const float* __restrict__ gVB2,
    const float* __restrict__ gGW1, const float* __restrict__ gGB1,
    const float* __restrict__ gGW2, const float* __restrict__ gGB2,
    const float* __restrict__ gNW1, const float* __restrict__ gNB1,
    const float* __restrict__ gNW2, const float* __restrict__ gNB2,
    const float* __restrict__ gW1n, const float* __restrict__ gB1n,
    float* __restrict__ csum, const int* __restrict__ off,
    const float* __restrict__ vsrc, const float* __restrict__ field,
    float* __restrict__ magg,
    float* __restrict__ coord, float* __restrict__ hh,
    uint_t* __restrict__ preR, uint_t* __restrict__ preC, const int emit_pre)
{
    __shared__ __align__(16) uint_t sNW1p[4096];       // NW1 f16 pairs, 16 KB
    __shared__ __align__(16) uint_t sW1np[4096];       // next-layer W1 f16, 16 KB
    __shared__ __align__(16) uint_t sVW1p[2048];       // vW1 f16 pairs, 8 KB
    __shared__ __align__(16) uint_t sGW1p[2048];       // gW1 f16 pairs, 8 KB
    __shared__ __align__(16) float sNW2[4096];         // NW2 fp32, 16 KB
    __shared__ __align__(16) float tile[NPB2 * 136];   // hh[0..63], magg[68..131]
    __shared__ float sNB1[64], sNB2[64], sB1n[64];

    const int t = threadIdx.x;
    for (int i = t; i < 1024; i += 256) {
        const int kp = i >> 4, j4 = i & 15;
        const float4 w0 = ((const float4*)gNW1)[kp * 32 + j4];
        const float4 w1 = ((const float4*)gNW1)[kp * 32 + 16 + j4];
        uint4 u;
        u.x = h2u(pkrtz(w0.x, w1.x)); u.y = h2u(pkrtz(w0.y, w1.y));
        u.z = h2u(pkrtz(w0.z, w1.z)); u.w = h2u(pkrtz(w0.w, w1.w));
        ((uint4*)sNW1p)[i] = u;
    }
    for (int i = t; i < 1024; i += 256) {
        const int kp = i >> 4, j4 = i & 15;
        const float4 w0 = ((const float4*)gW1n)[kp * 32 + j4];
        const float4 w1 = ((const float4*)gW1n)[kp * 32 + 16 + j4];
        uint4 u;
        u.x = h2u(pkrtz(w0.x, w1.x)); u.y = h2u(pkrtz(w0.y, w1.y));
        u.z = h2u(pkrtz(w0.z, w1.z)); u.w = h2u(pkrtz(w0.w, w1.w));
        ((uint4*)sW1np)[i] = u;
    }
    for (int i = t; i < 512; i += 256) {
        const int kp = i >> 4, j4 = i & 15;
        const float4 w0 = ((const float4*)gVW1)[kp * 32 + j4];
        const float4 w1 = ((const float4*)gVW1)[kp * 32 + 16 + j4];
        uint4 u;
        u.x = h2u(pkrtz(w0.x, w1.x)); u.y = h2u(pkrtz(w0.y, w1.y));
        u.z = h2u(pkrtz(w0.z, w1.z)); u.w = h2u(pkrtz(w0.w, w1.w));
        ((uint4*)sVW1p)[i] = u;
    }
    for (int i = t; i < 512; i += 256) {
        const int kp = i >> 4, j4 = i & 15;
        const float4 w0 = ((const float4*)gGW1)[kp * 32 + j4];
        const float4 w1 = ((const float4*)gGW1)[kp * 32 + 16 + j4];
        uint4 u;
        u.x = h2u(pkrtz(w0.x, w1.x)); u.y = h2u(pkrtz(w0.y, w1.y));
        u.z = h2u(pkrtz(w0.z, w1.z)); u.w = h2u(pkrtz(w0.w, w1.w));
        ((uint4*)sGW1p)[i] = u;
    }
    for (int i = t; i < 1024; i += 256)
        ((float4*)sNW2)[i] = ((const float4*)gNW2)[i];
    if (t < 64) { sNB1[t] = gNB1[t]; sNB2[t] = gNB2[t]; sB1n[t] = gB1n[t]; }

    const int ni = t >> 4;          // node in block (0..15)
    const int q  = t & 15;          // channel group (4 ch)
    const int n = blockIdx.x * NPB2 + ni;    // grid*NPB2 = 10000 exactly
    float* T = &tile[ni * 136];

    ((float4*)T)[q]        = ((const float4*)(hh + (size_t)n * 64))[q];
    ((float4*)(T + 68))[q] = ((const float4*)(magg + (size_t)n * 64))[q];
    __syncthreads();

    // ---- vw ----
    float a4[4];
    {
        const float4 b = ((const float4*)gVB1)[q];
        a4[0] = b.x; a4[1] = b.y; a4[2] = b.z; a4[3] = b.w;
    }
    #pragma unroll 8
    for (int kp = 0; kp < 32; kp++) {
        const half2v p = pkrtz(T[2 * kp], T[2 * kp + 1]);
        const uint4 w = *(const uint4*)&sVW1p[kp * 64 + q * 4];
        a4[0] = dot2h(p, w.x, a4[0]); a4[1] = dot2h(p, w.y, a4[1]);
        a4[2] = dot2h(p, w.z, a4[2]); a4[3] = dot2h(p, w.w, a4[3]);
    }
    float part;
    {
        const float4 w2 = ((const float4*)gVW2)[q];
        part = silu(a4[0]) * w2.x + silu(a4[1]) * w2.y
             + silu(a4[2]) * w2.z + silu(a4[3]) * w2.w;
    }
    part += __shfl_xor(part, 1);
    part += __shfl_xor(part, 2);
    part += __shfl_xor(part, 4);
    part += __shfl_xor(part, 8);
    const float vw = part + gVB2[0];

    // ---- gw ----
    {
        const float4 b = ((const float4*)gGB1)[q];
        a4[0] = b.x; a4[1] = b.y; a4[2] = b.z; a4[3] = b.w;
    }
    #pragma unroll 8
    for (int kp = 0; kp < 32; kp++) {
        const half2v p = pkrtz(T[2 * kp], T[2 * kp + 1]);
        const uint4 w = *(const uint4*)&sGW1p[kp * 64 + q * 4];
        a4[0] = dot2h(p, w.x, a4[0]); a4[1] = dot2h(p, w.y, a4[1]);
        a4[2] = dot2h(p, w.z, a4[2]); a4[3] = dot2h(p, w.w, a4[3]);
    }
    {
        const float4 w2 = ((const float4*)gGW2)[q];
        part = silu(a4[0]) * w2.x + silu(a4[1]) * w2.y
             + silu(a4[2]) * w2.z + silu(a4[3]) * w2.w;
    }
    part += __shfl_xor(part, 1);
    part += __shfl_xor(part, 2);
    part += __shfl_xor(part, 4);
    part += __shfl_xor(part, 8);
    const float gw = part + gGB2[0];

    // ---- coord update ----
    if (q == 0) {
        const float cn = fmaxf((float)(off[n + 1] - off[n]), 1.0f);
        #pragma unroll
        for (int d = 0; d < 3; d++)
            coord[3 * n + d] += csum[3 * n + d] / cn
                              + vw * vsrc[3 * n + d]
                              + gw * field[3 * n + d];
    }

    // ---- node MLP hidden ----
    {
        const float4 b = ((const float4*)sNB1)[q];
        a4[0] = b.x; a4[1] = b.y; a4[2] = b.z; a4[3] = b.w;
    }
    #pragma unroll 8
    for (int kp = 0; kp < 32; kp++) {
        const half2v p = pkrtz(T[2 * kp], T[2 * kp + 1]);
        const uint4 w = *(const uint4*)&sNW1p[kp * 64 + q * 4];
        a4[0] = dot2h(p, w.x, a4[0]); a4[1] = dot2h(p, w.y, a4[1]);
        a4[2] = dot2h(p, w.z, a4[2]); a4[3] = dot2h(p, w.w, a4[3]);
    }
    #pragma unroll 8
    for (int kp = 0; kp < 32; kp++) {
        const half2v p = pkrtz(T[68 + 2 * kp], T[68 + 2 * kp + 1]);
        const uint4 w = *(const uint4*)&sNW1p[(32 + kp) * 64 + q * 4];
        a4[0] = dot2h(p, w.x, a4[0]); a4[1] = dot2h(p, w.y, a4[1]);
        a4[2] = dot2h(p, w.z, a4[2]); a4[3] = dot2h(p, w.w, a4[3]);
    }
    #pragma unroll
    for (int j = 0; j < 4; j++) a4[j] = silu(a4[j]);

    __syncthreads();
    {
        float4 v; v.x = a4[0]; v.y = a4[1]; v.z = a4[2]; v.w = a4[3];
        ((float4*)T)[q] = v;
    }
    __syncthreads();

    {
        float4 z; z.x = z.y = z.z = z.w = 0.f;
        ((float4*)(magg + (size_t)n * 64))[q] = z;
        if (q == 0) { csum[3 * n] = 0.f; csum[3 * n + 1] = 0.f; csum[3 * n + 2] = 0.f; }
    }

    // ---- output GEMM (LDS fp32 NW2) ----
    float o4[4];
    {
        const float4 b = ((const float4*)sNB2)[q];
        o4[0] = b.x; o4[1] = b.y; o4[2] = b.z; o4[3] = b.w;
    }
    #pragma unroll 4
    for (int kk = 0; kk < 16; kk++) {
        const float4 h4 = ((const float4*)T)[kk];
        const float hv[4] = {h4.x, h4.y, h4.z, h4.w};
        #pragma unroll
        for (int u = 0; u < 4; u++) {
            const float v = hv[u];
            const float4 w = ((const float4*)(sNW2 + (kk * 4 + u) * 64))[q];
            o4[0] += v * w.x; o4[1] += v * w.y; o4[2] += v * w.z; o4[3] += v * w.w;
        }
    }
    {
        float4 v; v.x = o4[0]; v.y = o4[1]; v.z = o4[2]; v.w = o4[3];
        ((float4*)(hh + (size_t)n * 64))[q] = v;
    }

    // ---- fused pre emission for next layer ----
    if (emit_pre) {
        __syncthreads();
        {
            float4 v; v.x = o4[0]; v.y = o4[1]; v.z = o4[2]; v.w = o4[3];
            ((float4*)T)[q] = v;
        }
        __syncthreads();

        float aR[4], aC[4];
        {
            const float4 b = ((const float4*)sB1n)[q];
            aR[0] = b.x; aR[1] = b.y; aR[2] = b.z; aR[3] = b.w;
            aC[0] = aC[1] = aC[2] = aC[3] = 0.f;
        }
        #pragma unroll 8
        for (int kp = 0; kp < 32; kp++) {
            const half2v p = pkrtz(T[2 * kp], T[2 * kp + 1]);
            const uint4 wr = *(const uint4*)&sW1np[kp * 64 + q * 4];
            const uint4 wc = *(const uint4*)&sW1np[(32 + kp) * 64 + q * 4];
            aR[0] = dot2h(p, wr.x, aR[0]); aR[1] = dot2h(p, wr.y, aR[1]);
            aR[2] = dot2h(p, wr.z, aR[2]); aR[3] = dot2h(p, wr.w, aR[3]);
            aC[0] = dot2h(p, wc.x, aC[0]); aC[1] = dot2h(p, wc.y, aC[1]);
            aC[2] = dot2h(p, wc.z, aC[2]); aC[3] = dot2h(p, wc.w, aC[3]);
        }
        uint2 oR, oC;
        oR.x = h2u(pkrtz(aR[0], aR[1])); oR.y = h2u(pkrtz(aR[2], aR[3]));
        oC.x = h2u(pkrtz(aC[0], aC[1])); oC.y = h2u(pkrtz(aC[2], aC[3]));
        *(uint2*)(preR + (size_t)n * 32 + q * 2) = oR;
        *(uint2*)(preC + (size_t)n * 32 + q * 2) = oC;
    }
}

// ---- host launch -------------------------------------------------------------
extern "C" void kernel_launch(void* const* d_in, const int* in_sizes, int n_in,
                              void* d_out, int out_size, void* d_ws, size_t ws_size,
                              hipStream_t stream) {
    float* wsf = (float*)d_ws;
    int*   wsi = (int*)(wsf + 1340000);
    uint_t* preR = (uint_t*)(wsi + IOFF_PRER);
    uint_t* preC = (uint_t*)(wsi + IOFF_PREC);
    float* coord = (float*)d_out;
    const int* edges = (const int*)d_in[4];
    const int* rows = edges;
    const int* cols = edges + NE;

    hipMemsetAsync(wsi + IOFF_CNTI, 0, NN * sizeof(int), stream);
    counti_kernel<<<(NE + 255) / 256, 256, 0, stream>>>(rows, wsi + IOFF_CNTI);
    scan_kernel<<<1, 1024, 0, stream>>>(wsi + IOFF_CNTI, wsi + IOFF_OFF, wsi + IOFF_CURSOR);
    scatter_kernel<<<(NE + 255) / 256, 256, 0, stream>>>(rows, wsi + IOFF_CURSOR,
                                                         wsi + IOFF_PERM);

    node_init<<<(NN + 255) / 256, 256, 0, stream>>>(
        (const float*)d_in[0], (const float*)d_in[1], (const float*)d_in[2],
        (const int*)d_in[5], (const float*)d_in[8],
        (const float*)d_in[9],  (const float*)d_in[10],
        (const float*)d_in[11], (const float*)d_in[12],
        (const float*)d_in[13], (const float*)d_in[14],
        (const float*)d_in[6],  (const float*)d_in[7],
        coord, wsf + OFF_FIELD, wsf + OFF_HH);

    // csum+magg zeroed once; node_kernel re-zeroes them each layer
    hipMemsetAsync(wsf + OFF_CSUM, 0, (30000 + 640000) * sizeof(float), stream);

    // layer-0 pre; layers 1..3 get pre from node_kernel's fused epilogue
    pre_kernel<<<NNODEBLK, 256, 0, stream>>>(
        wsf + OFF_HH,
        (const float*)d_in[15], (const float*)d_in[16],
        preR, preC);

    for (int l = 0; l < NL; l++) {
        const int ln = (l + 1 < NL) ? (l + 1) : 0;   // next-layer W1 (unused if last)
        edge_kernel<<<NEBLK, 256, 0, stream>>>(
            rows, cols, wsi + IOFF_PERM,
            coord, (const float*)d_in[3],
            ((const float*)d_in[15]) + l * 8384,
            ((const float*)d_in[17]) + l * 4096, ((const float*)d_in[18]) + l * 64,
            ((const float*)d_in[23]) + l * 4096, ((const float*)d_in[24]) + l * 64,
            ((const float*)d_in[25]) + l * 64,
            preR, preC,
            wsf + OFF_CSUM, wsf + OFF_MAGG);
        node_kernel<<<NODEBLK2, 256, 0, stream>>>(
            ((const float*)d_in[26]) + l * 4096, ((const float*)d_in[27]) + l * 64,
            ((const float*)d_in[28]) + l * 64,   ((const float*)d_in[29]) + l,
            ((const float*)d_in[30]) + l * 4096, ((const float*)d_in[31]) + l * 64,
            ((const float*)d_in[32]) + l * 64,   ((const float*)d_in[33]) + l,
            ((const float*)d_in[19]) + l * 8192, ((const float*)d_in[20]) + l * 64,
            ((const float*)d_in[21]) + l * 4096, ((const float*)d_in[22]) + l * 64,
            ((const float*)d_in[15]) + ln * 8384, ((const float*)d_in[16]) + ln * 64,
            wsf + OFF_CSUM, wsi + IOFF_OFF, (const float*)d_in[2],
            wsf + OFF_FIELD, wsf + OFF_MAGG, coord, wsf + OFF_HH,
            preR, preC, (l + 1 < NL) ? 1 : 0);
    }
}